// Round 6
// baseline (1216.720 us; speedup 1.0000x reference)
//
#include <hip/hip_runtime.h>
#include <hip/hip_bf16.h>
#include <hip/hip_fp16.h>

// TemporalGNN: GRU's H stays zero => R dead, timesteps independent.
// out[b,n,:] = relu( sum_t p_t*(1-Z_t)*Ht_t ) @ W_out + b_out
//   Z  = sigmoid(Y_t @ Wz + bz),  Ht = tanh(Y_t @ Wh + bh)
//   Y_t = sym-normalized aggregation of X[...,t] in F=32 space.
// R6: gather from an fp16 copy of X (halves L2-miss fabric traffic, the
// measured invariant limiter). Structure otherwise identical to R5.

#define FDIM 32
#define TDIM 12
#define ODIM 64
#define BDIM 4

__global__ void k_count(const int* __restrict__ dst, int* __restrict__ counts, int E) {
    int e = blockIdx.x * 256 + threadIdx.x;
    if (e < E) atomicAdd(&counts[dst[e]], 1);
}

__global__ __launch_bounds__(1024) void k_scan(const int* __restrict__ counts,
                                               int* __restrict__ offsets,
                                               float* __restrict__ dis, int N) {
    __shared__ int wsum[16];
    __shared__ int sCarry;
    const int tid = threadIdx.x;
    const int lane = tid & 63;
    const int wv = tid >> 6;
    if (tid == 0) sCarry = 0;
    __syncthreads();
    for (int base = 0; base < N; base += 1024) {
        int i = base + tid;
        int v = (i < N) ? counts[i] : 0;
        int s = v;
        for (int off = 1; off < 64; off <<= 1) {
            int t = __shfl_up(s, off, 64);
            if (lane >= off) s += t;
        }
        if (lane == 63) wsum[wv] = s;
        __syncthreads();
        if (wv == 0 && lane < 16) {
            int ws = wsum[lane];
            for (int off = 1; off < 16; off <<= 1) {
                int t = __shfl_up(ws, off, 64);
                if (lane >= off) ws += t;
            }
            wsum[lane] = ws;
        }
        __syncthreads();
        int carry = sCarry;
        int wpre = (wv > 0) ? wsum[wv - 1] : 0;
        if (i < N) {
            offsets[i] = carry + wpre + s - v;
            dis[i] = 1.0f / sqrtf((float)(v + 1));
        }
        __syncthreads();
        if (tid == 0) sCarry = carry + wsum[15];
        __syncthreads();
    }
    if (tid == 0) offsets[N] = sCarry;
}

__global__ void k_scatter(const int* __restrict__ src, const int* __restrict__ dst,
                          const int* __restrict__ offsets, int* __restrict__ fill,
                          const float* __restrict__ dis,
                          int2* __restrict__ csr, int E) {
    int e = blockIdx.x * 256 + threadIdx.x;
    if (e < E) {
        int s = src[e], d = dst[e];
        int pos = offsets[d] + atomicAdd(&fill[d], 1);
        csr[pos] = make_int2(s, __float_as_int(dis[s] * dis[d]));
    }
}

__global__ void k_prep(const float* __restrict__ Wg_z, const float* __restrict__ bg_z,
                       const float* __restrict__ Wl_z, const float* __restrict__ bl_z,
                       const float* __restrict__ Wg_h, const float* __restrict__ bg_h,
                       const float* __restrict__ Wl_h, const float* __restrict__ bl_h,
                       const float* __restrict__ att,
                       float* __restrict__ Wz, float* __restrict__ bz,
                       float* __restrict__ Wh, float* __restrict__ bh,
                       float* __restrict__ probs) {
    int tid = threadIdx.x;
    for (int i = tid; i < FDIM * ODIM; i += 256) {
        int f = i >> 6, o = i & 63;
        float az = 0.f, ah = 0.f;
        for (int k = 0; k < ODIM; k++) {
            az += Wg_z[f * ODIM + k] * Wl_z[k * ODIM + o];
            ah += Wg_h[f * ODIM + k] * Wl_h[k * ODIM + o];
        }
        Wz[i] = az;
        Wh[i] = ah;
    }
    if (tid < ODIM) {
        float az = bl_z[tid], ah = bl_h[tid];
        for (int k = 0; k < ODIM; k++) {
            az += bg_z[k] * Wl_z[k * ODIM + tid];
            ah += bg_h[k] * Wl_h[k * ODIM + tid];
        }
        bz[tid] = az;
        bh[tid] = ah;
    }
    if (tid == 0) {
        float m = -1e30f;
        for (int t = 0; t < TDIM; t++) m = fmaxf(m, att[t]);
        float e[TDIM], s = 0.f;
        for (int t = 0; t < TDIM; t++) { e[t] = expf(att[t] - m); s += e[t]; }
        for (int t = 0; t < TDIM; t++) probs[t] = e[t] / s;
    }
}

// fp32 -> fp16 copy of X (4 elems/thread, grid-stride).
__global__ __launch_bounds__(256) void k_cvt(const float4* __restrict__ in,
                                             uint2* __restrict__ out, int n4) {
    int i = blockIdx.x * 256 + threadIdx.x;
    const int stride = gridDim.x * 256;
    for (; i < n4; i += stride) {
        const float4 v = in[i];
        __half2 h0 = __floats2half2_rn(v.x, v.y);
        __half2 h1 = __floats2half2_rn(v.z, v.w);
        uint2 u;
        u.x = *reinterpret_cast<unsigned*>(&h0);
        u.y = *reinterpret_cast<unsigned*>(&h1);
        out[i] = u;
    }
}

__device__ __forceinline__ float sigm(float x) { return 1.f / (1.f + expf(-x)); }

// Block-per-node grid-stride, 384 threads = 6 waves. fp16 gather variant.
// Phase 1: thread owns (b = tid/96, half4-chunk q = tid%96) of the 384-half row.
// Phase 2: thread (o=tid&63, w=tid>>6) computes gates for t=w, w+6.
// Phase 3: tid<48 does ReLU + 64->12 readout.
__global__ __launch_bounds__(384) void k_main_h(
    const uint2* __restrict__ Xh, const int* __restrict__ offsets,
    const int2* __restrict__ csr, const float* __restrict__ dis,
    const float* __restrict__ Wz, const float* __restrict__ bz,
    const float* __restrict__ Wh, const float* __restrict__ bh,
    const float* __restrict__ probs, const float* __restrict__ Wout,
    const float* __restrict__ bout, float* __restrict__ out, int N) {
    const int tid = threadIdx.x;
    const int lane = tid & 63;

    __shared__ float4 sY4[BDIM][96];
    __shared__ float sAcc[BDIM][ODIM];
    __shared__ float sWout[ODIM * TDIM];
    __shared__ float sBout[TDIM];

    for (int i = tid; i < ODIM * TDIM; i += 384) sWout[i] = Wout[i];
    if (tid < TDIM) sBout[tid] = bout[tid];

    const int o = tid & 63;
    const int w = tid >> 6;
    float wzr[FDIM], whr[FDIM];
#pragma unroll
    for (int f = 0; f < FDIM; f++) {
        wzr[f] = Wz[f * ODIM + o];
        whr[f] = Wh[f * ODIM + o];
    }
    const float bzo = bz[o], bho = bh[o];
    const int t0 = w, t1 = w + 6;
    const float p0 = probs[t0], p1 = probs[t1];

    const int b = tid / 96;
    const int q = tid - b * 96;
    const unsigned rowBase = (unsigned)b * (unsigned)N;

#define H4ACC(acc, u, m)                                                      \
    {                                                                         \
        __half2 h0_ = *reinterpret_cast<__half2*>(&(u).x);                    \
        __half2 h1_ = *reinterpret_cast<__half2*>(&(u).y);                    \
        float2 f0_ = __half22float2(h0_);                                     \
        float2 f1_ = __half22float2(h1_);                                     \
        acc.x += (m) * f0_.x; acc.y += (m) * f0_.y;                           \
        acc.z += (m) * f1_.x; acc.w += (m) * f1_.y;                           \
    }

    for (int n = blockIdx.x; n < N; n += gridDim.x) {
        if (tid < BDIM * ODIM) ((float*)sAcc)[tid] = 0.f;

        const int beg = offsets[n], end = offsets[n + 1];
        const float dn = dis[n];
        const float snorm = dn * dn;

        // ---- Phase 1: gather (fp16 rows, 8 B/lane, 8-deep) ----
        float4 a0 = make_float4(0.f, 0.f, 0.f, 0.f);
        float4 a1 = a0, a2 = a0, a3 = a0;
        {
            uint2 us = Xh[(rowBase + n) * 96u + q];
            H4ACC(a0, us, snorm);
        }

        for (int ebase = beg; ebase < end; ebase += 64) {
            const int cnt = min(64, end - ebase);
            int esrc = 0;
            float enm = 0.f;
            if (ebase + lane < end) {
                const int2 e = csr[ebase + lane];
                esrc = e.x;
                enm = __int_as_float(e.y);
            }
            int j = 0;
            for (; j + 8 <= cnt; j += 8) {
                const int s0 = __shfl(esrc, j + 0, 64), s1 = __shfl(esrc, j + 1, 64);
                const int s2 = __shfl(esrc, j + 2, 64), s3 = __shfl(esrc, j + 3, 64);
                const int s4 = __shfl(esrc, j + 4, 64), s5 = __shfl(esrc, j + 5, 64);
                const int s6 = __shfl(esrc, j + 6, 64), s7 = __shfl(esrc, j + 7, 64);
                const float m0 = __shfl(enm, j + 0, 64), m1 = __shfl(enm, j + 1, 64);
                const float m2 = __shfl(enm, j + 2, 64), m3 = __shfl(enm, j + 3, 64);
                const float m4 = __shfl(enm, j + 4, 64), m5 = __shfl(enm, j + 5, 64);
                const float m6 = __shfl(enm, j + 6, 64), m7 = __shfl(enm, j + 7, 64);
                uint2 v0 = Xh[(rowBase + s0) * 96u + q];
                uint2 v1 = Xh[(rowBase + s1) * 96u + q];
                uint2 v2 = Xh[(rowBase + s2) * 96u + q];
                uint2 v3 = Xh[(rowBase + s3) * 96u + q];
                uint2 v4 = Xh[(rowBase + s4) * 96u + q];
                uint2 v5 = Xh[(rowBase + s5) * 96u + q];
                uint2 v6 = Xh[(rowBase + s6) * 96u + q];
                uint2 v7 = Xh[(rowBase + s7) * 96u + q];
                H4ACC(a0, v0, m0); H4ACC(a1, v1, m1);
                H4ACC(a2, v2, m2); H4ACC(a3, v3, m3);
                H4ACC(a0, v4, m4); H4ACC(a1, v5, m5);
                H4ACC(a2, v6, m6); H4ACC(a3, v7, m7);
            }
            for (; j < cnt; j++) {
                const int s = __shfl(esrc, j, 64);
                const float m = __shfl(enm, j, 64);
                uint2 v = Xh[(rowBase + s) * 96u + q];
                H4ACC(a0, v, m);
            }
        }
        a0.x += (a1.x + a2.x) + a3.x;
        a0.y += (a1.y + a2.y) + a3.y;
        a0.z += (a1.z + a2.z) + a3.z;
        a0.w += (a1.w + a2.w) + a3.w;
        sY4[b][q] = a0;
        __syncthreads();

        // ---- Phase 2: gates ----
#pragma unroll
        for (int bb = 0; bb < BDIM; bb++) {
            const float* yb = (const float*)sY4[bb];
            float z0 = bzo, z1 = bzo, h0 = bho, h1 = bho;
#pragma unroll
            for (int f = 0; f < FDIM; f++) {
                float ya = yb[f * TDIM + t0];
                float yc = yb[f * TDIM + t1];
                z0 += ya * wzr[f]; h0 += ya * whr[f];
                z1 += yc * wzr[f]; h1 += yc * whr[f];
            }
            float contrib = p0 * (1.f - sigm(z0)) * tanhf(h0)
                          + p1 * (1.f - sigm(z1)) * tanhf(h1);
            atomicAdd(&sAcc[bb][o], contrib);
        }
        __syncthreads();

        // ---- Phase 3: readout ----
        if (tid < BDIM * TDIM) {
            int ob = tid / TDIM, jj = tid - ob * TDIM;
            float v = sBout[jj];
#pragma unroll
            for (int o2 = 0; o2 < ODIM; o2++) {
                v += fmaxf(sAcc[ob][o2], 0.f) * sWout[o2 * TDIM + jj];
            }
            out[(unsigned)(ob * N + n) * TDIM + jj] = v;
        }
        __syncthreads();
    }
#undef H4ACC
}

// fp32 fallback (R5 kernel) if workspace can't hold the fp16 copy.
__global__ __launch_bounds__(384) void k_main_f(
    const float* __restrict__ X, const int* __restrict__ offsets,
    const int2* __restrict__ csr, const float* __restrict__ dis,
    const float* __restrict__ Wz, const float* __restrict__ bz,
    const float* __restrict__ Wh, const float* __restrict__ bh,
    const float* __restrict__ probs, const float* __restrict__ Wout,
    const float* __restrict__ bout, float* __restrict__ out, int N) {
    const int tid = threadIdx.x;
    const int lane = tid & 63;

    __shared__ float4 sY4[BDIM][96];
    __shared__ float sAcc[BDIM][ODIM];
    __shared__ float sWout[ODIM * TDIM];
    __shared__ float sBout[TDIM];

    for (int i = tid; i < ODIM * TDIM; i += 384) sWout[i] = Wout[i];
    if (tid < TDIM) sBout[tid] = bout[tid];

    const int o = tid & 63;
    const int w = tid >> 6;
    float wzr[FDIM], whr[FDIM];
#pragma unroll
    for (int f = 0; f < FDIM; f++) {
        wzr[f] = Wz[f * ODIM + o];
        whr[f] = Wh[f * ODIM + o];
    }
    const float bzo = bz[o], bho = bh[o];
    const int t0 = w, t1 = w + 6;
    const float p0 = probs[t0], p1 = probs[t1];

    const int b = tid / 96;
    const int q = tid - b * 96;
    const float4* __restrict__ Xq = (const float4*)X;
    const unsigned rowBase = (unsigned)b * (unsigned)N;

    for (int n = blockIdx.x; n < N; n += gridDim.x) {
        if (tid < BDIM * ODIM) ((float*)sAcc)[tid] = 0.f;

        const int beg = offsets[n], end = offsets[n + 1];
        const float dn = dis[n];
        const float snorm = dn * dn;

        float4 a0 = Xq[(rowBase + n) * 96u + q];
        a0.x *= snorm; a0.y *= snorm; a0.z *= snorm; a0.w *= snorm;
        float4 a1 = make_float4(0.f, 0.f, 0.f, 0.f);
        float4 a2 = a1, a3 = a1;

        for (int ebase = beg; ebase < end; ebase += 64) {
            const int cnt = min(64, end - ebase);
            int esrc = 0;
            float enm = 0.f;
            if (ebase + lane < end) {
                const int2 e = csr[ebase + lane];
                esrc = e.x;
                enm = __int_as_float(e.y);
            }
            int j = 0;
            for (; j + 4 <= cnt; j += 4) {
                const int s0 = __shfl(esrc, j + 0, 64), s1 = __shfl(esrc, j + 1, 64);
                const int s2 = __shfl(esrc, j + 2, 64), s3 = __shfl(esrc, j + 3, 64);
                const float m0 = __shfl(enm, j + 0, 64), m1 = __shfl(enm, j + 1, 64);
                const float m2 = __shfl(enm, j + 2, 64), m3 = __shfl(enm, j + 3, 64);
                const float4 v0 = Xq[(rowBase + s0) * 96u + q];
                const float4 v1 = Xq[(rowBase + s1) * 96u + q];
                const float4 v2 = Xq[(rowBase + s2) * 96u + q];
                const float4 v3 = Xq[(rowBase + s3) * 96u + q];
                a0.x += m0 * v0.x; a0.y += m0 * v0.y; a0.z += m0 * v0.z; a0.w += m0 * v0.w;
                a1.x += m1 * v1.x; a1.y += m1 * v1.y; a1.z += m1 * v1.z; a1.w += m1 * v1.w;
                a2.x += m2 * v2.x; a2.y += m2 * v2.y; a2.z += m2 * v2.z; a2.w += m2 * v2.w;
                a3.x += m3 * v3.x; a3.y += m3 * v3.y; a3.z += m3 * v3.z; a3.w += m3 * v3.w;
            }
            for (; j < cnt; j++) {
                const int s = __shfl(esrc, j, 64);
                const float m = __shfl(enm, j, 64);
                const float4 v = Xq[(rowBase + s) * 96u + q];
                a0.x += m * v.x; a0.y += m * v.y; a0.z += m * v.z; a0.w += m * v.w;
            }
        }
        a0.x += (a1.x + a2.x) + a3.x;
        a0.y += (a1.y + a2.y) + a3.y;
        a0.z += (a1.z + a2.z) + a3.z;
        a0.w += (a1.w + a2.w) + a3.w;
        sY4[b][q] = a0;
        __syncthreads();

#pragma unroll
        for (int bb = 0; bb < BDIM; bb++) {
            const float* yb = (const float*)sY4[bb];
            float z0 = bzo, z1 = bzo, h0 = bho, h1 = bho;
#pragma unroll
            for (int f = 0; f < FDIM; f++) {
                float ya = yb[f * TDIM + t0];
                float yc = yb[f * TDIM + t1];
                z0 += ya * wzr[f]; h0 += ya * whr[f];
                z1 += yc * wzr[f]; h1 += yc * whr[f];
            }
            float contrib = p0 * (1.f - sigm(z0)) * tanhf(h0)
                          + p1 * (1.f - sigm(z1)) * tanhf(h1);
            atomicAdd(&sAcc[bb][o], contrib);
        }
        __syncthreads();

        if (tid < BDIM * TDIM) {
            int ob = tid / TDIM, jj = tid - ob * TDIM;
            float v = sBout[jj];
#pragma unroll
            for (int o2 = 0; o2 < ODIM; o2++) {
                v += fmaxf(sAcc[ob][o2], 0.f) * sWout[o2 * TDIM + jj];
            }
            out[(unsigned)(ob * N + n) * TDIM + jj] = v;
        }
        __syncthreads();
    }
}

extern "C" void kernel_launch(void* const* d_in, const int* in_sizes, int n_in,
                              void* d_out, int out_size, void* d_ws, size_t ws_size,
                              hipStream_t stream) {
    const float* X    = (const float*)d_in[0];
    const int*   ei   = (const int*)d_in[1];
    const float* Wg_z = (const float*)d_in[2];
    const float* bg_z = (const float*)d_in[3];
    const float* Wg_h = (const float*)d_in[6];
    const float* bg_h = (const float*)d_in[7];
    const float* Wl_z = (const float*)d_in[8];
    const float* bl_z = (const float*)d_in[9];
    const float* Wl_h = (const float*)d_in[12];
    const float* bl_h = (const float*)d_in[13];
    const float* att  = (const float*)d_in[14];
    const float* Wout = (const float*)d_in[15];
    const float* bout = (const float*)d_in[16];
    float* out = (float*)d_out;

    const int E = in_sizes[1] / 2;
    const int N = in_sizes[0] / (BDIM * FDIM * TDIM);
    const size_t xElems = (size_t)BDIM * N * FDIM * TDIM;
    const size_t xhBytes = xElems * 2;          // fp16 copy
    const size_t restBytes = (size_t)N * 4 * 4 + 64 + (size_t)E * 8 + 20000;
    const bool useH = ws_size >= xhBytes + restBytes;

    char* wp = (char*)d_ws;
    uint2* Xh = nullptr;
    if (useH) { Xh = (uint2*)wp; wp += xhBytes; }
    int* counts   = (int*)wp;   wp += (size_t)N * 4;
    int* fill     = (int*)wp;   wp += (size_t)N * 4;
    int* offs     = (int*)wp;   wp += (size_t)(N + 4) * 4;
    float* dis    = (float*)wp; wp += (size_t)N * 4;
    int2* csr     = (int2*)wp;  wp += (size_t)E * 8;
    float* Wz     = (float*)wp; wp += FDIM * ODIM * 4;
    float* Wh     = (float*)wp; wp += FDIM * ODIM * 4;
    float* bz     = (float*)wp; wp += ODIM * 4;
    float* bh     = (float*)wp; wp += ODIM * 4;
    float* probs  = (float*)wp; wp += 16 * 4;

    hipMemsetAsync(counts, 0, (size_t)2 * N * 4, stream);

    k_prep<<<1, 256, 0, stream>>>(Wg_z, bg_z, Wl_z, bl_z, Wg_h, bg_h, Wl_h, bl_h,
                                  att, Wz, bz, Wh, bh, probs);
    if (useH) {
        const int n4 = (int)(xElems / 4);
        k_cvt<<<2048, 256, 0, stream>>>((const float4*)X, Xh, n4);
    }
    k_count<<<(E + 255) / 256, 256, 0, stream>>>(ei + E, counts, E);
    k_scan<<<1, 1024, 0, stream>>>(counts, offs, dis, N);
    k_scatter<<<(E + 255) / 256, 256, 0, stream>>>(ei, ei + E, offs, fill, dis, csr, E);

    int nBlocks = N < 2048 ? N : 2048;
    if (useH) {
        k_main_h<<<nBlocks, 384, 0, stream>>>(Xh, offs, csr, dis, Wz, bz, Wh, bh,
                                              probs, Wout, bout, out, N);
    } else {
        k_main_f<<<nBlocks, 384, 0, stream>>>(X, offs, csr, dis, Wz, bz, Wh, bh,
                                              probs, Wout, bout, out, N);
    }
}

// Round 8
// 990.010 us; speedup vs baseline: 1.2290x; 1.2290x over previous
//
#include <hip/hip_runtime.h>
#include <hip/hip_bf16.h>
#include <hip/hip_fp16.h>

// TemporalGNN: GRU's H stays zero => R dead, timesteps independent.
// out[b,n,:] = relu( sum_t p_t*(1-Z_t)*Ht_t ) @ W_out + b_out
//   Z  = sigmoid(Y_t @ Wz + bz),  Ht = tanh(Y_t @ Wh + bh)
//   Y_t = sym-normalized aggregation (self-loop included in CSR) in F=32 space.
// R8 = R7 with the sAcc init bug fixed (512 slots zeroed by 384 threads).

#define FDIM 32
#define TDIM 12
#define ODIM 64
#define BDIM 4

__global__ void k_count(const int* __restrict__ dst, int* __restrict__ counts, int E) {
    int e = blockIdx.x * 256 + threadIdx.x;
    if (e < E) atomicAdd(&counts[dst[e]], 1);
}

// exclusive scan of (counts[i]+1)  (self-loop slot included); dis = rsqrt(deg+1)
__global__ __launch_bounds__(1024) void k_scan(const int* __restrict__ counts,
                                               int* __restrict__ offsets,
                                               float* __restrict__ dis, int N) {
    __shared__ int wsum[16];
    __shared__ int sCarry;
    const int tid = threadIdx.x;
    const int lane = tid & 63;
    const int wv = tid >> 6;
    if (tid == 0) sCarry = 0;
    __syncthreads();
    for (int base = 0; base < N; base += 1024) {
        int i = base + tid;
        int v = (i < N) ? (counts[i] + 1) : 0;
        int s = v;
        for (int off = 1; off < 64; off <<= 1) {
            int t = __shfl_up(s, off, 64);
            if (lane >= off) s += t;
        }
        if (lane == 63) wsum[wv] = s;
        __syncthreads();
        if (wv == 0 && lane < 16) {
            int ws = wsum[lane];
            for (int off = 1; off < 16; off <<= 1) {
                int t = __shfl_up(ws, off, 64);
                if (lane >= off) ws += t;
            }
            wsum[lane] = ws;
        }
        __syncthreads();
        int carry = sCarry;
        int wpre = (wv > 0) ? wsum[wv - 1] : 0;
        if (i < N) {
            offsets[i] = carry + wpre + s - v;
            dis[i] = 1.0f / sqrtf((float)v);
        }
        __syncthreads();
        if (tid == 0) sCarry = carry + wsum[15];
        __syncthreads();
    }
    if (tid == 0) offsets[N] = sCarry;
}

// write self-edge at slot 0 of each node's range; fill starts at 1
__global__ void k_self(const int* __restrict__ offsets, const float* __restrict__ dis,
                       int* __restrict__ fill, int2* __restrict__ csr, int N) {
    int n = blockIdx.x * 256 + threadIdx.x;
    if (n < N) {
        float d = dis[n];
        csr[offsets[n]] = make_int2(n, __float_as_int(d * d));
        fill[n] = 1;
    }
}

__global__ void k_scatter(const int* __restrict__ src, const int* __restrict__ dst,
                          const int* __restrict__ offsets, int* __restrict__ fill,
                          const float* __restrict__ dis,
                          int2* __restrict__ csr, int E) {
    int e = blockIdx.x * 256 + threadIdx.x;
    if (e < E) {
        int s = src[e], d = dst[e];
        int pos = offsets[d] + atomicAdd(&fill[d], 1);
        csr[pos] = make_int2(s, __float_as_int(dis[s] * dis[d]));
    }
}

__global__ void k_prep(const float* __restrict__ Wg_z, const float* __restrict__ bg_z,
                       const float* __restrict__ Wl_z, const float* __restrict__ bl_z,
                       const float* __restrict__ Wg_h, const float* __restrict__ bg_h,
                       const float* __restrict__ Wl_h, const float* __restrict__ bl_h,
                       const float* __restrict__ att,
                       float* __restrict__ Wz, float* __restrict__ bz,
                       float* __restrict__ Wh, float* __restrict__ bh,
                       float* __restrict__ probs) {
    int tid = threadIdx.x;
    for (int i = tid; i < FDIM * ODIM; i += 256) {
        int f = i >> 6, o = i & 63;
        float az = 0.f, ah = 0.f;
        for (int k = 0; k < ODIM; k++) {
            az += Wg_z[f * ODIM + k] * Wl_z[k * ODIM + o];
            ah += Wg_h[f * ODIM + k] * Wl_h[k * ODIM + o];
        }
        Wz[i] = az;
        Wh[i] = ah;
    }
    if (tid < ODIM) {
        float az = bl_z[tid], ah = bl_h[tid];
        for (int k = 0; k < ODIM; k++) {
            az += bg_z[k] * Wl_z[k * ODIM + tid];
            ah += bg_h[k] * Wl_h[k * ODIM + tid];
        }
        bz[tid] = az;
        bh[tid] = ah;
    }
    if (tid == 0) {
        float m = -1e30f;
        for (int t = 0; t < TDIM; t++) m = fmaxf(m, att[t]);
        float e[TDIM], s = 0.f;
        for (int t = 0; t < TDIM; t++) { e[t] = expf(att[t] - m); s += e[t]; }
        for (int t = 0; t < TDIM; t++) probs[t] = e[t] / s;
    }
}

// fp32 -> fp16 copy of X
__global__ __launch_bounds__(256) void k_cvt(const float4* __restrict__ in,
                                             uint2* __restrict__ out, int n4) {
    int i = blockIdx.x * 256 + threadIdx.x;
    const int stride = gridDim.x * 256;
    for (; i < n4; i += stride) {
        const float4 v = in[i];
        __half2 h0 = __floats2half2_rn(v.x, v.y);
        __half2 h1 = __floats2half2_rn(v.z, v.w);
        uint2 u;
        u.x = *reinterpret_cast<unsigned*>(&h0);
        u.y = *reinterpret_cast<unsigned*>(&h1);
        out[i] = u;
    }
}

__device__ __forceinline__ float sigm(float x) { return 1.f / (1.f + __expf(-x)); }
__device__ __forceinline__ float tanhfast(float x) { return 1.f - 2.f / (1.f + __expf(2.f * x)); }

// accumulate 8 halves of uint4 v scaled by m into a0..a7
#define H8ACC(m, v)                                                            \
    {                                                                          \
        float2 f0_ = __half22float2(*(__half2*)&(v).x);                        \
        float2 f1_ = __half22float2(*(__half2*)&(v).y);                        \
        float2 f2_ = __half22float2(*(__half2*)&(v).z);                        \
        float2 f3_ = __half22float2(*(__half2*)&(v).w);                        \
        a0 += (m) * f0_.x; a1 += (m) * f0_.y;                                  \
        a2 += (m) * f1_.x; a3 += (m) * f1_.y;                                  \
        a4 += (m) * f2_.x; a5 += (m) * f2_.y;                                  \
        a6 += (m) * f3_.x; a7 += (m) * f3_.y;                                  \
    }

// gate chunk for batch index bb (phase 2 of node i-1)
#define P2CHUNK(bb)                                                            \
    if (doP2) {                                                                \
        const float2* y2_ = (const float2*)&sYA[prv][bb][0];                   \
        float zz0 = bzo, zz1 = bzo, hh0 = bho, hh1 = bho;                      \
        _Pragma("unroll") for (int f = 0; f < FDIM; f++) {                     \
            float2 y_ = y2_[f * 6 + w];                                        \
            zz0 += y_.x * wzr[f]; hh0 += y_.x * whr[f];                        \
            zz1 += y_.y * wzr[f]; hh1 += y_.y * whr[f];                        \
        }                                                                      \
        float c0_ = p0 * (1.f - sigm(zz0)) * tanhfast(hh0);                    \
        float c1_ = p1 * (1.f - sigm(zz1)) * tanhfast(hh1);                    \
        atomicAdd(&sAcc[prv][bb][o], c0_ + c1_);                               \
    }

// Persistent pipelined kernel. 384 threads = 6 waves = 2 gather teams of 3.
__global__ __launch_bounds__(384, 3) void k_main_p(
    const uint4* __restrict__ Xh, const int* __restrict__ offs,
    const int2* __restrict__ csr, const float* __restrict__ dis,
    const float* __restrict__ Wz, const float* __restrict__ bz,
    const float* __restrict__ Wh, const float* __restrict__ bh,
    const float* __restrict__ probs, const float* __restrict__ Wout,
    const float* __restrict__ bout, float* __restrict__ out, int N) {
    __shared__ float sYA[2][BDIM][FDIM * TDIM];  // team-0 partial Y, dbuf (12 KiB)
    __shared__ float sYB[2][BDIM][FDIM * TDIM];  // team-1 partial Y, dbuf (12 KiB)
    __shared__ float sAcc[2][BDIM][ODIM];        // gate accum, dbuf (2 KiB)
    __shared__ float sWout[ODIM * TDIM];         // 3 KiB
    __shared__ float sBout[TDIM];

    const int tid = threadIdx.x;
    const int lane = tid & 63;
    const int o = lane;
    const int w = tid >> 6;
    const int team = tid / 192;            // 0/1: edge parity
    const int tl = tid - team * 192;
    const int gb = tl / 48;                // gather batch (b)
    const int gc = tl - gb * 48;           // 16B chunk within 768B row

    for (int i = tid; i < ODIM * TDIM; i += 384) sWout[i] = Wout[i];
    if (tid < TDIM) sBout[tid] = bout[tid];
    for (int k = tid; k < 2 * BDIM * ODIM; k += 384) ((float*)sAcc)[k] = 0.f;  // FIX: all 512 slots

    float wzr[FDIM], whr[FDIM];
#pragma unroll
    for (int f = 0; f < FDIM; f++) {
        wzr[f] = Wz[f * ODIM + o];
        whr[f] = Wh[f * ODIM + o];
    }
    const float bzo = bz[o], bho = bh[o];
    const int t0 = 2 * w, t1 = 2 * w + 1;
    const float p0 = probs[t0], p1 = probs[t1];

    const int n0 = blockIdx.x;
    const int stride = gridDim.x;
    const int cnt = (n0 < N) ? ((N - 1 - n0) / stride + 1) : 0;

    int begC = 0, endC = 0;
    if (cnt > 0) { begC = offs[n0]; endC = offs[n0 + 1]; }

    for (int i = 0; i < cnt + 2; ++i) {
        const bool doG = (i < cnt);
        const bool doP2 = (i >= 1) && (i - 1 < cnt);
        const bool doP3 = (i >= 2);
        const int cur = i & 1;
        const int prv = cur ^ 1;

        // (a) csr window prefetch for gather node (uses begC/endC prefetched last iter)
        int esrc = 0;
        float enm = 0.f;
        int wcnt0 = 0;
        const int begN = begC, endN = endC;
        if (doG) {
            wcnt0 = min(64, endN - begN);
            if (lane < endN - begN) {
                int2 e = csr[begN + lane];
                esrc = e.x;
                enm = __int_as_float(e.y);
            }
        }
        // (b) merge node i-1's Y: sYA[prv] += sYB[prv]
        if (doP2) {
            float4* A4 = (float4*)&sYA[prv][0][0];
            const float4* B4 = (const float4*)&sYB[prv][0][0];
            float4 a = A4[tid];
            const float4 b2 = B4[tid];
            a.x += b2.x; a.y += b2.y; a.z += b2.z; a.w += b2.w;
            A4[tid] = a;
        }
        // (c) phase3 for node i-2 (wave 0 only) + zero its sAcc buffer
        if (doP3 && tid < BDIM * TDIM) {
            const int n3 = n0 + (i - 2) * stride;
            const int ob = tid / TDIM, jj = tid - ob * TDIM;
            float v = sBout[jj];
#pragma unroll
            for (int o2 = 0; o2 < ODIM; o2++)
                v += fmaxf(sAcc[cur][ob][o2], 0.f) * sWout[o2 * TDIM + jj];
            out[(unsigned)(ob * N + n3) * TDIM + jj] = v;
            for (int k = tid; k < BDIM * ODIM; k += BDIM * TDIM)
                ((float*)sAcc[cur])[k] = 0.f;  // same wave: reads complete first
        }
        __syncthreads();

        // (e) gather batches interleaved with gate chunks
        float a0 = 0.f, a1 = 0.f, a2 = 0.f, a3 = 0.f,
              a4 = 0.f, a5 = 0.f, a6 = 0.f, a7 = 0.f;
        const unsigned gRow = (unsigned)(gb * N);

        uint4 v0, v1, v2, v3, v4, v5;
        float m0, m1, m2, m3, m4, m5;
        if (doG) {  // batch A: team edges 0..5 (window slots team+2s), masked
            const int s0 = __shfl(esrc, team + 0, 64), s1 = __shfl(esrc, team + 2, 64);
            const int s2 = __shfl(esrc, team + 4, 64), s3 = __shfl(esrc, team + 6, 64);
            const int s4 = __shfl(esrc, team + 8, 64), s5 = __shfl(esrc, team + 10, 64);
            m0 = __shfl(enm, team + 0, 64); m1 = __shfl(enm, team + 2, 64);
            m2 = __shfl(enm, team + 4, 64); m3 = __shfl(enm, team + 6, 64);
            m4 = __shfl(enm, team + 8, 64); m5 = __shfl(enm, team + 10, 64);
            v0 = Xh[(gRow + s0) * 48u + gc]; v1 = Xh[(gRow + s1) * 48u + gc];
            v2 = Xh[(gRow + s2) * 48u + gc]; v3 = Xh[(gRow + s3) * 48u + gc];
            v4 = Xh[(gRow + s4) * 48u + gc]; v5 = Xh[(gRow + s5) * 48u + gc];
        }
        P2CHUNK(0)
        P2CHUNK(1)
        if (doG) {  // consume A
            H8ACC(m0, v0); H8ACC(m1, v1); H8ACC(m2, v2);
            H8ACC(m3, v3); H8ACC(m4, v4); H8ACC(m5, v5);
            // batch B: team edges 6..11 (slots team+12..team+22), masked
            const int s0b = __shfl(esrc, team + 12, 64), s1b = __shfl(esrc, team + 14, 64);
            const int s2b = __shfl(esrc, team + 16, 64), s3b = __shfl(esrc, team + 18, 64);
            const int s4b = __shfl(esrc, team + 20, 64), s5b = __shfl(esrc, team + 22, 64);
            m0 = __shfl(enm, team + 12, 64); m1 = __shfl(enm, team + 14, 64);
            m2 = __shfl(enm, team + 16, 64); m3 = __shfl(enm, team + 18, 64);
            m4 = __shfl(enm, team + 20, 64); m5 = __shfl(enm, team + 22, 64);
            v0 = Xh[(gRow + s0b) * 48u + gc]; v1 = Xh[(gRow + s1b) * 48u + gc];
            v2 = Xh[(gRow + s2b) * 48u + gc]; v3 = Xh[(gRow + s3b) * 48u + gc];
            v4 = Xh[(gRow + s4b) * 48u + gc]; v5 = Xh[(gRow + s5b) * 48u + gc];
        }
        P2CHUNK(2)
        P2CHUNK(3)
        if (doG) {  // consume B
            H8ACC(m0, v0); H8ACC(m1, v1); H8ACC(m2, v2);
            H8ACC(m3, v3); H8ACC(m4, v4); H8ACC(m5, v5);
            // tail: window-0 edges beyond 24, then rare extra windows
            for (int j = 24 + team; j < wcnt0; j += 2) {
                const int s = __shfl(esrc, j, 64);
                const float m = __shfl(enm, j, 64);
                uint4 v = Xh[(gRow + s) * 48u + gc];
                H8ACC(m, v);
            }
            for (int wb = begN + 64; wb < endN; wb += 64) {
                int es2 = 0;
                float em2 = 0.f;
                const int wc = min(64, endN - wb);
                if (lane < endN - wb) {
                    int2 e = csr[wb + lane];
                    es2 = e.x;
                    em2 = __int_as_float(e.y);
                }
                for (int j = team; j < wc; j += 2) {
                    const int s = __shfl(es2, j, 64);
                    const float m = __shfl(em2, j, 64);
                    uint4 v = Xh[(gRow + s) * 48u + gc];
                    H8ACC(m, v);
                }
            }
            // deposit team partial Y
            float* dst = (team == 0 ? &sYA[cur][gb][gc * 8] : &sYB[cur][gb][gc * 8]);
            ((float4*)dst)[0] = make_float4(a0, a1, a2, a3);
            ((float4*)dst)[1] = make_float4(a4, a5, a6, a7);
        }
        // prefetch offsets for next gather node
        if (i + 1 < cnt) {
            const int nn = n0 + (i + 1) * stride;
            begC = offs[nn];
            endC = offs[nn + 1];
        }
        __syncthreads();
    }
}

// fp32 fallback (no fp16 workspace): consumes self-inclusive csr.
__global__ __launch_bounds__(384) void k_main_f(
    const float* __restrict__ X, const int* __restrict__ offsets,
    const int2* __restrict__ csr, const float* __restrict__ dis,
    const float* __restrict__ Wz, const float* __restrict__ bz,
    const float* __restrict__ Wh, const float* __restrict__ bh,
    const float* __restrict__ probs, const float* __restrict__ Wout,
    const float* __restrict__ bout, float* __restrict__ out, int N) {
    const int tid = threadIdx.x;
    const int lane = tid & 63;

    __shared__ float4 sY4[BDIM][96];
    __shared__ float sAcc[BDIM][ODIM];
    __shared__ float sWout[ODIM * TDIM];
    __shared__ float sBout[TDIM];

    for (int i = tid; i < ODIM * TDIM; i += 384) sWout[i] = Wout[i];
    if (tid < TDIM) sBout[tid] = bout[tid];

    const int o = tid & 63;
    const int w = tid >> 6;
    float wzr[FDIM], whr[FDIM];
#pragma unroll
    for (int f = 0; f < FDIM; f++) {
        wzr[f] = Wz[f * ODIM + o];
        whr[f] = Wh[f * ODIM + o];
    }
    const float bzo = bz[o], bho = bh[o];
    const int t0 = w, t1 = w + 6;
    const float p0 = probs[t0], p1 = probs[t1];

    const int b = tid / 96;
    const int q = tid - b * 96;
    const float4* __restrict__ Xq = (const float4*)X;
    const unsigned rowBase = (unsigned)b * (unsigned)N;

    for (int n = blockIdx.x; n < N; n += gridDim.x) {
        if (tid < BDIM * ODIM) ((float*)sAcc)[tid] = 0.f;

        const int beg = offsets[n], end = offsets[n + 1];
        float4 A0 = make_float4(0.f, 0.f, 0.f, 0.f);
        float4 A1 = A0, A2 = A0, A3 = A0;

        for (int ebase = beg; ebase < end; ebase += 64) {
            const int cnt2 = min(64, end - ebase);
            int esrc = 0;
            float enm = 0.f;
            if (ebase + lane < end) {
                const int2 e = csr[ebase + lane];
                esrc = e.x;
                enm = __int_as_float(e.y);
            }
            int j = 0;
            for (; j + 4 <= cnt2; j += 4) {
                const int s0 = __shfl(esrc, j + 0, 64), s1 = __shfl(esrc, j + 1, 64);
                const int s2 = __shfl(esrc, j + 2, 64), s3 = __shfl(esrc, j + 3, 64);
                const float m0 = __shfl(enm, j + 0, 64), m1 = __shfl(enm, j + 1, 64);
                const float m2 = __shfl(enm, j + 2, 64), m3 = __shfl(enm, j + 3, 64);
                const float4 u0 = Xq[(rowBase + s0) * 96u + q];
                const float4 u1 = Xq[(rowBase + s1) * 96u + q];
                const float4 u2 = Xq[(rowBase + s2) * 96u + q];
                const float4 u3 = Xq[(rowBase + s3) * 96u + q];
                A0.x += m0 * u0.x; A0.y += m0 * u0.y; A0.z += m0 * u0.z; A0.w += m0 * u0.w;
                A1.x += m1 * u1.x; A1.y += m1 * u1.y; A1.z += m1 * u1.z; A1.w += m1 * u1.w;
                A2.x += m2 * u2.x; A2.y += m2 * u2.y; A2.z += m2 * u2.z; A2.w += m2 * u2.w;
                A3.x += m3 * u3.x; A3.y += m3 * u3.y; A3.z += m3 * u3.z; A3.w += m3 * u3.w;
            }
            for (; j < cnt2; j++) {
                const int s = __shfl(esrc, j, 64);
                const float m = __shfl(enm, j, 64);
                const float4 u = Xq[(rowBase + s) * 96u + q];
                A0.x += m * u.x; A0.y += m * u.y; A0.z += m * u.z; A0.w += m * u.w;
            }
        }
        A0.x += (A1.x + A2.x) + A3.x;
        A0.y += (A1.y + A2.y) + A3.y;
        A0.z += (A1.z + A2.z) + A3.z;
        A0.w += (A1.w + A2.w) + A3.w;
        sY4[b][q] = A0;
        __syncthreads();

#pragma unroll
        for (int bb = 0; bb < BDIM; bb++) {
            const float* yb = (const float*)sY4[bb];
            float z0 = bzo, z1 = bzo, h0 = bho, h1 = bho;
#pragma unroll
            for (int f = 0; f < FDIM; f++) {
                float ya = yb[f * TDIM + t0];
                float yc = yb[f * TDIM + t1];
                z0 += ya * wzr[f]; h0 += ya * whr[f];
                z1 += yc * wzr[f]; h1 += yc * whr[f];
            }
            float contrib = p0 * (1.f - sigm(z0)) * tanhfast(h0)
                          + p1 * (1.f - sigm(z1)) * tanhfast(h1);
            atomicAdd(&sAcc[bb][o], contrib);
        }
        __syncthreads();

        if (tid < BDIM * TDIM) {
            int ob = tid / TDIM, jj = tid - ob * TDIM;
            float v = sBout[jj];
#pragma unroll
            for (int o2 = 0; o2 < ODIM; o2++) {
                v += fmaxf(sAcc[ob][o2], 0.f) * sWout[o2 * TDIM + jj];
            }
            out[(unsigned)(ob * N + n) * TDIM + jj] = v;
        }
        __syncthreads();
    }
}

extern "C" void kernel_launch(void* const* d_in, const int* in_sizes, int n_in,
                              void* d_out, int out_size, void* d_ws, size_t ws_size,
                              hipStream_t stream) {
    const float* X    = (const float*)d_in[0];
    const int*   ei   = (const int*)d_in[1];
    const float* Wg_z = (const float*)d_in[2];
    const float* bg_z = (const float*)d_in[3];
    const float* Wg_h = (const float*)d_in[6];
    const float* bg_h = (const float*)d_in[7];
    const float* Wl_z = (const float*)d_in[8];
    const float* bl_z = (const float*)d_in[9];
    const float* Wl_h = (const float*)d_in[12];
    const float* bl_h = (const float*)d_in[13];
    const float* att  = (const float*)d_in[14];
    const float* Wout = (const float*)d_in[15];
    const float* bout = (const float*)d_in[16];
    float* out = (float*)d_out;

    const int E = in_sizes[1] / 2;
    const int N = in_sizes[0] / (BDIM * FDIM * TDIM);
    const size_t xElems = (size_t)BDIM * N * FDIM * TDIM;
    const size_t xhBytes = xElems * 2;
    const size_t csrBytes = (size_t)(E + N) * 8;
    const size_t restBytes = (size_t)N * 4 * 4 + 64 + csrBytes + 20000;
    const bool useH = ws_size >= xhBytes + restBytes;

    char* wp = (char*)d_ws;
    uint2* Xh = nullptr;
    if (useH) { Xh = (uint2*)wp; wp += xhBytes; }
    int* counts   = (int*)wp;   wp += (size_t)N * 4;
    int* fill     = (int*)wp;   wp += (size_t)N * 4;
    int* offs     = (int*)wp;   wp += (size_t)(N + 4) * 4;
    float* dis    = (float*)wp; wp += (size_t)N * 4;
    int2* csr     = (int2*)wp;  wp += csrBytes;
    float* Wz     = (float*)wp; wp += FDIM * ODIM * 4;
    float* Wh     = (float*)wp; wp += FDIM * ODIM * 4;
    float* bz     = (float*)wp; wp += ODIM * 4;
    float* bh     = (float*)wp; wp += ODIM * 4;
    float* probs  = (float*)wp; wp += 16 * 4;

    hipMemsetAsync(counts, 0, (size_t)N * 4, stream);

    k_prep<<<1, 256, 0, stream>>>(Wg_z, bg_z, Wl_z, bl_z, Wg_h, bg_h, Wl_h, bl_h,
                                  att, Wz, bz, Wh, bh, probs);
    if (useH) {
        const int n4 = (int)(xElems / 4);
        k_cvt<<<2048, 256, 0, stream>>>((const float4*)X, Xh, n4);
    }
    k_count<<<(E + 255) / 256, 256, 0, stream>>>(ei + E, counts, E);
    k_scan<<<1, 1024, 0, stream>>>(counts, offs, dis, N);
    k_self<<<(N + 255) / 256, 256, 0, stream>>>(offs, dis, fill, csr, N);
    k_scatter<<<(E + 255) / 256, 256, 0, stream>>>(ei, ei + E, offs, fill, dis, csr, E);

    if (useH) {
        int nB = N < 512 ? N : 512;
        k_main_p<<<nB, 384, 0, stream>>>((const uint4*)Xh, offs, csr, dis,
                                         Wz, bz, Wh, bh, probs, Wout, bout, out, N);
    } else {
        int nB = N < 2048 ? N : 2048;
        k_main_f<<<nB, 384, 0, stream>>>(X, offs, csr, dis, Wz, bz, Wh, bh,
                                         probs, Wout, bout, out, N);
    }
}

// Round 9
// 917.968 us; speedup vs baseline: 1.3254x; 1.0785x over previous
//
#include <hip/hip_runtime.h>
#include <hip/hip_bf16.h>
#include <hip/hip_fp16.h>

// TemporalGNN: GRU's H stays zero => R dead, timesteps independent.
// out[b,n,:] = relu( sum_t p_t*(1-Z_t)*Ht_t ) @ W_out + b_out
//   Z  = sigmoid(Y_t @ Wz + bz),  Ht = tanh(Y_t @ Wh + bh)
//   Y_t = sym-normalized aggregation (self-loop included in CSR) in F=32 space.
// R9 = R8 pipeline with deep-MLP scheduling: 8 staged gathers covered by gate
// chunks, 4 more into chunks 2/3, csr window prefetched a full iter ahead,
// 4-deep high-degree tail.

#define FDIM 32
#define TDIM 12
#define ODIM 64
#define BDIM 4

__global__ void k_count(const int* __restrict__ dst, int* __restrict__ counts, int E) {
    int e = blockIdx.x * 256 + threadIdx.x;
    if (e < E) atomicAdd(&counts[dst[e]], 1);
}

// exclusive scan of (counts[i]+1)  (self-loop slot included); dis = rsqrt(deg+1)
__global__ __launch_bounds__(1024) void k_scan(const int* __restrict__ counts,
                                               int* __restrict__ offsets,
                                               float* __restrict__ dis, int N) {
    __shared__ int wsum[16];
    __shared__ int sCarry;
    const int tid = threadIdx.x;
    const int lane = tid & 63;
    const int wv = tid >> 6;
    if (tid == 0) sCarry = 0;
    __syncthreads();
    for (int base = 0; base < N; base += 1024) {
        int i = base + tid;
        int v = (i < N) ? (counts[i] + 1) : 0;
        int s = v;
        for (int off = 1; off < 64; off <<= 1) {
            int t = __shfl_up(s, off, 64);
            if (lane >= off) s += t;
        }
        if (lane == 63) wsum[wv] = s;
        __syncthreads();
        if (wv == 0 && lane < 16) {
            int ws = wsum[lane];
            for (int off = 1; off < 16; off <<= 1) {
                int t = __shfl_up(ws, off, 64);
                if (lane >= off) ws += t;
            }
            wsum[lane] = ws;
        }
        __syncthreads();
        int carry = sCarry;
        int wpre = (wv > 0) ? wsum[wv - 1] : 0;
        if (i < N) {
            offsets[i] = carry + wpre + s - v;
            dis[i] = 1.0f / sqrtf((float)v);
        }
        __syncthreads();
        if (tid == 0) sCarry = carry + wsum[15];
        __syncthreads();
    }
    if (tid == 0) offsets[N] = sCarry;
}

// write self-edge at slot 0 of each node's range; fill starts at 1
__global__ void k_self(const int* __restrict__ offsets, const float* __restrict__ dis,
                       int* __restrict__ fill, int2* __restrict__ csr, int N) {
    int n = blockIdx.x * 256 + threadIdx.x;
    if (n < N) {
        float d = dis[n];
        csr[offsets[n]] = make_int2(n, __float_as_int(d * d));
        fill[n] = 1;
    }
}

__global__ void k_scatter(const int* __restrict__ src, const int* __restrict__ dst,
                          const int* __restrict__ offsets, int* __restrict__ fill,
                          const float* __restrict__ dis,
                          int2* __restrict__ csr, int E) {
    int e = blockIdx.x * 256 + threadIdx.x;
    if (e < E) {
        int s = src[e], d = dst[e];
        int pos = offsets[d] + atomicAdd(&fill[d], 1);
        csr[pos] = make_int2(s, __float_as_int(dis[s] * dis[d]));
    }
}

__global__ void k_prep(const float* __restrict__ Wg_z, const float* __restrict__ bg_z,
                       const float* __restrict__ Wl_z, const float* __restrict__ bl_z,
                       const float* __restrict__ Wg_h, const float* __restrict__ bg_h,
                       const float* __restrict__ Wl_h, const float* __restrict__ bl_h,
                       const float* __restrict__ att,
                       float* __restrict__ Wz, float* __restrict__ bz,
                       float* __restrict__ Wh, float* __restrict__ bh,
                       float* __restrict__ probs) {
    int tid = threadIdx.x;
    for (int i = tid; i < FDIM * ODIM; i += 256) {
        int f = i >> 6, o = i & 63;
        float az = 0.f, ah = 0.f;
        for (int k = 0; k < ODIM; k++) {
            az += Wg_z[f * ODIM + k] * Wl_z[k * ODIM + o];
            ah += Wg_h[f * ODIM + k] * Wl_h[k * ODIM + o];
        }
        Wz[i] = az;
        Wh[i] = ah;
    }
    if (tid < ODIM) {
        float az = bl_z[tid], ah = bl_h[tid];
        for (int k = 0; k < ODIM; k++) {
            az += bg_z[k] * Wl_z[k * ODIM + tid];
            ah += bg_h[k] * Wl_h[k * ODIM + tid];
        }
        bz[tid] = az;
        bh[tid] = ah;
    }
    if (tid == 0) {
        float m = -1e30f;
        for (int t = 0; t < TDIM; t++) m = fmaxf(m, att[t]);
        float e[TDIM], s = 0.f;
        for (int t = 0; t < TDIM; t++) { e[t] = expf(att[t] - m); s += e[t]; }
        for (int t = 0; t < TDIM; t++) probs[t] = e[t] / s;
    }
}

// fp32 -> fp16 copy of X
__global__ __launch_bounds__(256) void k_cvt(const float4* __restrict__ in,
                                             uint2* __restrict__ out, int n4) {
    int i = blockIdx.x * 256 + threadIdx.x;
    const int stride = gridDim.x * 256;
    for (; i < n4; i += stride) {
        const float4 v = in[i];
        __half2 h0 = __floats2half2_rn(v.x, v.y);
        __half2 h1 = __floats2half2_rn(v.z, v.w);
        uint2 u;
        u.x = *reinterpret_cast<unsigned*>(&h0);
        u.y = *reinterpret_cast<unsigned*>(&h1);
        out[i] = u;
    }
}

__device__ __forceinline__ float sigm(float x) { return 1.f / (1.f + __expf(-x)); }
__device__ __forceinline__ float tanhfast(float x) { return 1.f - 2.f / (1.f + __expf(2.f * x)); }

// accumulate 8 halves of uint4 v scaled by m into a0..a7
#define H8ACC(m, v)                                                            \
    {                                                                          \
        float2 f0_ = __half22float2(*(__half2*)&(v).x);                        \
        float2 f1_ = __half22float2(*(__half2*)&(v).y);                        \
        float2 f2_ = __half22float2(*(__half2*)&(v).z);                        \
        float2 f3_ = __half22float2(*(__half2*)&(v).w);                        \
        a0 += (m) * f0_.x; a1 += (m) * f0_.y;                                  \
        a2 += (m) * f1_.x; a3 += (m) * f1_.y;                                  \
        a4 += (m) * f2_.x; a5 += (m) * f2_.y;                                  \
        a6 += (m) * f3_.x; a7 += (m) * f3_.y;                                  \
    }

// issue one gather: slot = window lane, dst = uint4 register
#define GISSUE(dst, slot)                                                      \
    {                                                                          \
        int s_ = __shfl(esrcC, (slot), 64);                                    \
        (dst) = Xh[(gRow + s_) * 48u + gc];                                    \
    }

// gate chunk for batch index bb (phase 2 of node i-1)
#define P2CHUNK(bb)                                                            \
    if (doP2) {                                                                \
        const float2* y2_ = (const float2*)&sYA[prv][bb][0];                   \
        float zz0 = bzo, zz1 = bzo, hh0 = bho, hh1 = bho;                      \
        _Pragma("unroll") for (int f = 0; f < FDIM; f++) {                     \
            float2 y_ = y2_[f * 6 + w];                                        \
            zz0 += y_.x * wzr[f]; hh0 += y_.x * whr[f];                        \
            zz1 += y_.y * wzr[f]; hh1 += y_.y * whr[f];                        \
        }                                                                      \
        float c0_ = p0 * (1.f - sigm(zz0)) * tanhfast(hh0);                    \
        float c1_ = p1 * (1.f - sigm(zz1)) * tanhfast(hh1);                    \
        atomicAdd(&sAcc[prv][bb][o], c0_ + c1_);                               \
    }

// Persistent pipelined kernel. 384 threads = 6 waves = 2 gather teams of 3.
__global__ __launch_bounds__(384, 3) void k_main_p(
    const uint4* __restrict__ Xh, const int* __restrict__ offs,
    const int2* __restrict__ csr, const float* __restrict__ dis,
    const float* __restrict__ Wz, const float* __restrict__ bz,
    const float* __restrict__ Wh, const float* __restrict__ bh,
    const float* __restrict__ probs, const float* __restrict__ Wout,
    const float* __restrict__ bout, float* __restrict__ out, int N) {
    __shared__ float sYA[2][BDIM][FDIM * TDIM];  // team-0 partial Y, dbuf (12 KiB)
    __shared__ float sYB[2][BDIM][FDIM * TDIM];  // team-1 partial Y, dbuf (12 KiB)
    __shared__ float sAcc[2][BDIM][ODIM];        // gate accum, dbuf (2 KiB)
    __shared__ float sWout[ODIM * TDIM];         // 3 KiB
    __shared__ float sBout[TDIM];

    const int tid = threadIdx.x;
    const int lane = tid & 63;
    const int o = lane;
    const int w = tid >> 6;
    const int team = tid / 192;            // 0/1: edge parity
    const int tl = tid - team * 192;
    const int gb = tl / 48;                // gather batch (b)
    const int gc = tl - gb * 48;           // 16B chunk within 768B row

    for (int i = tid; i < ODIM * TDIM; i += 384) sWout[i] = Wout[i];
    if (tid < TDIM) sBout[tid] = bout[tid];
    for (int k = tid; k < 2 * BDIM * ODIM; k += 384) ((float*)sAcc)[k] = 0.f;

    float wzr[FDIM], whr[FDIM];
#pragma unroll
    for (int f = 0; f < FDIM; f++) {
        wzr[f] = Wz[f * ODIM + o];
        whr[f] = Wh[f * ODIM + o];
    }
    const float bzo = bz[o], bho = bh[o];
    const int t0 = 2 * w, t1 = 2 * w + 1;
    const float p0 = probs[t0], p1 = probs[t1];

    const int n0 = blockIdx.x;
    const int stride = gridDim.x;
    const int cnt = (n0 < N) ? ((N - 1 - n0) / stride + 1) : 0;

    // pipeline state: current node's window (regs), next node's bounds
    int begCur = 0, endCur = 0, begNxt = 0, endNxt = 0;
    int esrcC = 0;
    float enmC = 0.f;
    if (cnt > 0) {
        begCur = offs[n0];
        endCur = offs[n0 + 1];
        if (lane < endCur - begCur) {
            int2 e = csr[begCur + lane];
            esrcC = e.x;
            enmC = __int_as_float(e.y);
        }
        if (cnt > 1) {
            begNxt = offs[n0 + stride];
            endNxt = offs[n0 + stride + 1];
        }
    }

    for (int i = 0; i < cnt + 2; ++i) {
        const bool doG = (i < cnt);
        const bool doP2 = (i >= 1) && (i - 1 < cnt);
        const bool doP3 = (i >= 2);
        const int cur = i & 1;
        const int prv = cur ^ 1;

        // (a) prefetch NEXT node's csr window (consumed next iteration)
        int esrcN = 0;
        float enmN = 0.f;
        if (i + 1 < cnt) {
            if (lane < endNxt - begNxt) {
                int2 e = csr[begNxt + lane];
                esrcN = e.x;
                enmN = __int_as_float(e.y);
            }
        }
        // (b) merge node i-1's Y: sYA[prv] += sYB[prv]
        if (doP2) {
            float4* A4 = (float4*)&sYA[prv][0][0];
            const float4* B4 = (const float4*)&sYB[prv][0][0];
            float4 a = A4[tid];
            const float4 b2 = B4[tid];
            a.x += b2.x; a.y += b2.y; a.z += b2.z; a.w += b2.w;
            A4[tid] = a;
        }
        // (c) phase3 for node i-2 + zero its sAcc buffer
        if (doP3 && tid < BDIM * TDIM) {
            const int n3 = n0 + (i - 2) * stride;
            const int ob = tid / TDIM, jj = tid - ob * TDIM;
            float v = sBout[jj];
#pragma unroll
            for (int o2 = 0; o2 < ODIM; o2++)
                v += fmaxf(sAcc[cur][ob][o2], 0.f) * sWout[o2 * TDIM + jj];
            out[(unsigned)(ob * N + n3) * TDIM + jj] = v;
            for (int k = tid; k < BDIM * ODIM; k += BDIM * TDIM)
                ((float*)sAcc[cur])[k] = 0.f;
        }
        __syncthreads();

        // (e) deep-staged gather interleaved with gate chunks
        float a0 = 0.f, a1 = 0.f, a2 = 0.f, a3 = 0.f,
              a4 = 0.f, a5 = 0.f, a6 = 0.f, a7 = 0.f;
        const unsigned gRow = (unsigned)(gb * N);
        const int wcnt0 = doG ? min(64, endCur - begCur) : 0;

        uint4 x0, x1, x2, x3, x4, x5, x6, x7;
        float c0, c1, c2, c3, c4, c5, c6, c7, c8, c9, c10, c11;
        if (doG) {  // norms for all 12 primary slots + issue loads 0..7
            c0 = __shfl(enmC, team + 0, 64);  c1 = __shfl(enmC, team + 2, 64);
            c2 = __shfl(enmC, team + 4, 64);  c3 = __shfl(enmC, team + 6, 64);
            c4 = __shfl(enmC, team + 8, 64);  c5 = __shfl(enmC, team + 10, 64);
            c6 = __shfl(enmC, team + 12, 64); c7 = __shfl(enmC, team + 14, 64);
            c8 = __shfl(enmC, team + 16, 64); c9 = __shfl(enmC, team + 18, 64);
            c10 = __shfl(enmC, team + 20, 64); c11 = __shfl(enmC, team + 22, 64);
            GISSUE(x0, team + 0);  GISSUE(x1, team + 2);
            GISSUE(x2, team + 4);  GISSUE(x3, team + 6);
            GISSUE(x4, team + 8);  GISSUE(x5, team + 10);
            GISSUE(x6, team + 12); GISSUE(x7, team + 14);
        }
        P2CHUNK(0)
        P2CHUNK(1)
        if (doG) {  // consume 0..3, reuse regs to issue 8..11
            H8ACC(c0, x0); H8ACC(c1, x1); H8ACC(c2, x2); H8ACC(c3, x3);
            GISSUE(x0, team + 16); GISSUE(x1, team + 18);
            GISSUE(x2, team + 20); GISSUE(x3, team + 22);
        }
        P2CHUNK(2)
        P2CHUNK(3)
        if (doG) {  // consume 4..11
            H8ACC(c4, x4); H8ACC(c5, x5); H8ACC(c6, x6); H8ACC(c7, x7);
            H8ACC(c8, x0); H8ACC(c9, x1); H8ACC(c10, x2); H8ACC(c11, x3);
            // tail: window-0 slots >= 24, 4-deep
            int j = 24 + team;
            for (; j + 6 < wcnt0; j += 8) {
                float ca = __shfl(enmC, j, 64), cb = __shfl(enmC, j + 2, 64);
                float cc = __shfl(enmC, j + 4, 64), cd = __shfl(enmC, j + 6, 64);
                uint4 ya, yb, yc, yd;
                GISSUE(ya, j); GISSUE(yb, j + 2); GISSUE(yc, j + 4); GISSUE(yd, j + 6);
                H8ACC(ca, ya); H8ACC(cb, yb); H8ACC(cc, yc); H8ACC(cd, yd);
            }
            for (; j < wcnt0; j += 2) {
                const float cm = __shfl(enmC, j, 64);
                uint4 yv;
                GISSUE(yv, j);
                H8ACC(cm, yv);
            }
            // rare extra windows (deg > 64)
            for (int wb = begCur + 64; wb < endCur; wb += 64) {
                int es2 = 0;
                float em2 = 0.f;
                const int wc = min(64, endCur - wb);
                if (lane < endCur - wb) {
                    int2 e = csr[wb + lane];
                    es2 = e.x;
                    em2 = __int_as_float(e.y);
                }
                for (int jj2 = team; jj2 < wc; jj2 += 2) {
                    const int s = __shfl(es2, jj2, 64);
                    const float m = __shfl(em2, jj2, 64);
                    uint4 v = Xh[(gRow + s) * 48u + gc];
                    H8ACC(m, v);
                }
            }
            // deposit team partial Y
            float* dst = (team == 0 ? &sYA[cur][gb][gc * 8] : &sYB[cur][gb][gc * 8]);
            ((float4*)dst)[0] = make_float4(a0, a1, a2, a3);
            ((float4*)dst)[1] = make_float4(a4, a5, a6, a7);
        }
        // (f) shift pipeline state; prefetch bounds for node i+2
        begCur = begNxt; endCur = endNxt;
        esrcC = esrcN; enmC = enmN;
        if (i + 2 < cnt) {
            const int nn = n0 + (i + 2) * stride;
            begNxt = offs[nn];
            endNxt = offs[nn + 1];
        }
        __syncthreads();
    }
}

// fp32 fallback (no fp16 workspace): consumes self-inclusive csr.
__global__ __launch_bounds__(384) void k_main_f(
    const float* __restrict__ X, const int* __restrict__ offsets,
    const int2* __restrict__ csr, const float* __restrict__ dis,
    const float* __restrict__ Wz, const float* __restrict__ bz,
    const float* __restrict__ Wh, const float* __restrict__ bh,
    const float* __restrict__ probs, const float* __restrict__ Wout,
    const float* __restrict__ bout, float* __restrict__ out, int N) {
    const int tid = threadIdx.x;
    const int lane = tid & 63;

    __shared__ float4 sY4[BDIM][96];
    __shared__ float sAcc[BDIM][ODIM];
    __shared__ float sWout[ODIM * TDIM];
    __shared__ float sBout[TDIM];

    for (int i = tid; i < ODIM * TDIM; i += 384) sWout[i] = Wout[i];
    if (tid < TDIM) sBout[tid] = bout[tid];

    const int o = tid & 63;
    const int w = tid >> 6;
    float wzr[FDIM], whr[FDIM];
#pragma unroll
    for (int f = 0; f < FDIM; f++) {
        wzr[f] = Wz[f * ODIM + o];
        whr[f] = Wh[f * ODIM + o];
    }
    const float bzo = bz[o], bho = bh[o];
    const int t0 = w, t1 = w + 6;
    const float p0 = probs[t0], p1 = probs[t1];

    const int b = tid / 96;
    const int q = tid - b * 96;
    const float4* __restrict__ Xq = (const float4*)X;
    const unsigned rowBase = (unsigned)b * (unsigned)N;

    for (int n = blockIdx.x; n < N; n += gridDim.x) {
        if (tid < BDIM * ODIM) ((float*)sAcc)[tid] = 0.f;

        const int beg = offsets[n], end = offsets[n + 1];
        float4 A0 = make_float4(0.f, 0.f, 0.f, 0.f);
        float4 A1 = A0, A2 = A0, A3 = A0;

        for (int ebase = beg; ebase < end; ebase += 64) {
            const int cnt2 = min(64, end - ebase);
            int esrc = 0;
            float enm = 0.f;
            if (ebase + lane < end) {
                const int2 e = csr[ebase + lane];
                esrc = e.x;
                enm = __int_as_float(e.y);
            }
            int j = 0;
            for (; j + 4 <= cnt2; j += 4) {
                const int s0 = __shfl(esrc, j + 0, 64), s1 = __shfl(esrc, j + 1, 64);
                const int s2 = __shfl(esrc, j + 2, 64), s3 = __shfl(esrc, j + 3, 64);
                const float m0 = __shfl(enm, j + 0, 64), m1 = __shfl(enm, j + 1, 64);
                const float m2 = __shfl(enm, j + 2, 64), m3 = __shfl(enm, j + 3, 64);
                const float4 u0 = Xq[(rowBase + s0) * 96u + q];
                const float4 u1 = Xq[(rowBase + s1) * 96u + q];
                const float4 u2 = Xq[(rowBase + s2) * 96u + q];
                const float4 u3 = Xq[(rowBase + s3) * 96u + q];
                A0.x += m0 * u0.x; A0.y += m0 * u0.y; A0.z += m0 * u0.z; A0.w += m0 * u0.w;
                A1.x += m1 * u1.x; A1.y += m1 * u1.y; A1.z += m1 * u1.z; A1.w += m1 * u1.w;
                A2.x += m2 * u2.x; A2.y += m2 * u2.y; A2.z += m2 * u2.z; A2.w += m2 * u2.w;
                A3.x += m3 * u3.x; A3.y += m3 * u3.y; A3.z += m3 * u3.z; A3.w += m3 * u3.w;
            }
            for (; j < cnt2; j++) {
                const int s = __shfl(esrc, j, 64);
                const float m = __shfl(enm, j, 64);
                const float4 u = Xq[(rowBase + s) * 96u + q];
                A0.x += m * u.x; A0.y += m * u.y; A0.z += m * u.z; A0.w += m * u.w;
            }
        }
        A0.x += (A1.x + A2.x) + A3.x;
        A0.y += (A1.y + A2.y) + A3.y;
        A0.z += (A1.z + A2.z) + A3.z;
        A0.w += (A1.w + A2.w) + A3.w;
        sY4[b][q] = A0;
        __syncthreads();

#pragma unroll
        for (int bb = 0; bb < BDIM; bb++) {
            const float* yb = (const float*)sY4[bb];
            float z0 = bzo, z1 = bzo, h0 = bho, h1 = bho;
#pragma unroll
            for (int f = 0; f < FDIM; f++) {
                float ya = yb[f * TDIM + t0];
                float yc = yb[f * TDIM + t1];
                z0 += ya * wzr[f]; h0 += ya * whr[f];
                z1 += yc * wzr[f]; h1 += yc * whr[f];
            }
            float contrib = p0 * (1.f - sigm(z0)) * tanhfast(h0)
                          + p1 * (1.f - sigm(z1)) * tanhfast(h1);
            atomicAdd(&sAcc[bb][o], contrib);
        }
        __syncthreads();

        if (tid < BDIM * TDIM) {
            int ob = tid / TDIM, jj = tid - ob * TDIM;
            float v = sBout[jj];
#pragma unroll
            for (int o2 = 0; o2 < ODIM; o2++) {
                v += fmaxf(sAcc[ob][o2], 0.f) * sWout[o2 * TDIM + jj];
            }
            out[(unsigned)(ob * N + n) * TDIM + jj] = v;
        }
        __syncthreads();
    }
}

extern "C" void kernel_launch(void* const* d_in, const int* in_sizes, int n_in,
                              void* d_out, int out_size, void* d_ws, size_t ws_size,
                              hipStream_t stream) {
    const float* X    = (const float*)d_in[0];
    const int*   ei   = (const int*)d_in[1];
    const float* Wg_z = (const float*)d_in[2];
    const float* bg_z = (const float*)d_in[3];
    const float* Wg_h = (const float*)d_in[6];
    const float* bg_h = (const float*)d_in[7];
    const float* Wl_z = (const float*)d_in[8];
    const float* bl_z = (const float*)d_in[9];
    const float* Wl_h = (const float*)d_in[12];
    const float* bl_h = (const float*)d_in[13];
    const float* att  = (const float*)d_in[14];
    const float* Wout = (const float*)d_in[15];
    const float* bout = (const float*)d_in[16];
    float* out = (float*)d_out;

    const int E = in_sizes[1] / 2;
    const int N = in_sizes[0] / (BDIM * FDIM * TDIM);
    const size_t xElems = (size_t)BDIM * N * FDIM * TDIM;
    const size_t xhBytes = xElems * 2;
    const size_t csrBytes = (size_t)(E + N) * 8;
    const size_t restBytes = (size_t)N * 4 * 4 + 64 + csrBytes + 20000;
    const bool useH = ws_size >= xhBytes + restBytes;

    char* wp = (char*)d_ws;
    uint2* Xh = nullptr;
    if (useH) { Xh = (uint2*)wp; wp += xhBytes; }
    int* counts   = (int*)wp;   wp += (size_t)N * 4;
    int* fill     = (int*)wp;   wp += (size_t)N * 4;
    int* offs     = (int*)wp;   wp += (size_t)(N + 4) * 4;
    float* dis    = (float*)wp; wp += (size_t)N * 4;
    int2* csr     = (int2*)wp;  wp += csrBytes;
    float* Wz     = (float*)wp; wp += FDIM * ODIM * 4;
    float* Wh     = (float*)wp; wp += FDIM * ODIM * 4;
    float* bz     = (float*)wp; wp += ODIM * 4;
    float* bh     = (float*)wp; wp += ODIM * 4;
    float* probs  = (float*)wp; wp += 16 * 4;

    hipMemsetAsync(counts, 0, (size_t)N * 4, stream);

    k_prep<<<1, 256, 0, stream>>>(Wg_z, bg_z, Wl_z, bl_z, Wg_h, bg_h, Wl_h, bl_h,
                                  att, Wz, bz, Wh, bh, probs);
    if (useH) {
        const int n4 = (int)(xElems / 4);
        k_cvt<<<2048, 256, 0, stream>>>((const float4*)X, Xh, n4);
    }
    k_count<<<(E + 255) / 256, 256, 0, stream>>>(ei + E, counts, E);
    k_scan<<<1, 1024, 0, stream>>>(counts, offs, dis, N);
    k_self<<<(N + 255) / 256, 256, 0, stream>>>(offs, dis, fill, csr, N);
    k_scatter<<<(E + 255) / 256, 256, 0, stream>>>(ei, ei + E, offs, fill, dis, csr, E);

    if (useH) {
        int nB = N < 1024 ? N : 1024;
        k_main_p<<<nB, 384, 0, stream>>>((const uint4*)Xh, offs, csr, dis,
                                         Wz, bz, Wh, bh, probs, Wout, bout, out, N);
    } else {
        int nB = N < 2048 ? N : 2048;
        k_main_f<<<nB, 384, 0, stream>>>(X, offs, csr, dis, Wz, bz, Wh, bh,
                                         probs, Wout, bout, out, N);
    }
}

// Round 10
// 504.769 us; speedup vs baseline: 2.4104x; 1.8186x over previous
//
#include <hip/hip_runtime.h>
#include <hip/hip_bf16.h>
#include <hip/hip_fp16.h>

// TemporalGNN: GRU's H stays zero => R dead, timesteps independent.
// out[b,n,:] = relu( sum_t p_t*(1-Z_t)*Ht_t ) @ W_out + b_out
//   Z  = sigmoid(Y_t @ Wz + bz),  Ht = tanh(Y_t @ Wh + bh)
//   Y_t = sym-normalized aggregation (self-loop in CSR) in F=32 space.
// R10: wave-independent tasks. Each wave owns one (node,batch): gathers the
// 768B fp16 row per edge (one uint4 wave-load), wave-private LDS Y slice,
// all-12-t gates in-wave, butterfly readout. NO block barriers in main loop
// -> 4-5 independent waves/SIMD hide gather latency (vs 1.5 before).

#define FDIM 32
#define TDIM 12
#define ODIM 64
#define BDIM 4

__global__ void k_count(const int* __restrict__ dst, int* __restrict__ counts, int E) {
    int e = blockIdx.x * 256 + threadIdx.x;
    if (e < E) atomicAdd(&counts[dst[e]], 1);
}

// exclusive scan of (counts[i]+1) (self-loop slot); dis = rsqrt(deg+1)
__global__ __launch_bounds__(1024) void k_scan(const int* __restrict__ counts,
                                               int* __restrict__ offsets,
                                               float* __restrict__ dis, int N) {
    __shared__ int wsum[16];
    __shared__ int sCarry;
    const int tid = threadIdx.x;
    const int lane = tid & 63;
    const int wv = tid >> 6;
    if (tid == 0) sCarry = 0;
    __syncthreads();
    for (int base = 0; base < N; base += 1024) {
        int i = base + tid;
        int v = (i < N) ? (counts[i] + 1) : 0;
        int s = v;
        for (int off = 1; off < 64; off <<= 1) {
            int t = __shfl_up(s, off, 64);
            if (lane >= off) s += t;
        }
        if (lane == 63) wsum[wv] = s;
        __syncthreads();
        if (wv == 0 && lane < 16) {
            int ws = wsum[lane];
            for (int off = 1; off < 16; off <<= 1) {
                int t = __shfl_up(ws, off, 64);
                if (lane >= off) ws += t;
            }
            wsum[lane] = ws;
        }
        __syncthreads();
        int carry = sCarry;
        int wpre = (wv > 0) ? wsum[wv - 1] : 0;
        if (i < N) {
            offsets[i] = carry + wpre + s - v;
            dis[i] = 1.0f / sqrtf((float)v);
        }
        __syncthreads();
        if (tid == 0) sCarry = carry + wsum[15];
        __syncthreads();
    }
    if (tid == 0) offsets[N] = sCarry;
}

__global__ void k_self(const int* __restrict__ offsets, const float* __restrict__ dis,
                       int* __restrict__ fill, int2* __restrict__ csr, int N) {
    int n = blockIdx.x * 256 + threadIdx.x;
    if (n < N) {
        float d = dis[n];
        csr[offsets[n]] = make_int2(n, __float_as_int(d * d));
        fill[n] = 1;
    }
}

__global__ void k_scatter(const int* __restrict__ src, const int* __restrict__ dst,
                          const int* __restrict__ offsets, int* __restrict__ fill,
                          const float* __restrict__ dis,
                          int2* __restrict__ csr, int E) {
    int e = blockIdx.x * 256 + threadIdx.x;
    if (e < E) {
        int s = src[e], d = dst[e];
        int pos = offsets[d] + atomicAdd(&fill[d], 1);
        csr[pos] = make_int2(s, __float_as_int(dis[s] * dis[d]));
    }
}

__global__ void k_prep(const float* __restrict__ Wg_z, const float* __restrict__ bg_z,
                       const float* __restrict__ Wl_z, const float* __restrict__ bl_z,
                       const float* __restrict__ Wg_h, const float* __restrict__ bg_h,
                       const float* __restrict__ Wl_h, const float* __restrict__ bl_h,
                       const float* __restrict__ att,
                       float* __restrict__ Wz, float* __restrict__ bz,
                       float* __restrict__ Wh, float* __restrict__ bh,
                       float* __restrict__ probs) {
    int tid = threadIdx.x;
    for (int i = tid; i < FDIM * ODIM; i += 256) {
        int f = i >> 6, o = i & 63;
        float az = 0.f, ah = 0.f;
        for (int k = 0; k < ODIM; k++) {
            az += Wg_z[f * ODIM + k] * Wl_z[k * ODIM + o];
            ah += Wg_h[f * ODIM + k] * Wl_h[k * ODIM + o];
        }
        Wz[i] = az;
        Wh[i] = ah;
    }
    if (tid < ODIM) {
        float az = bl_z[tid], ah = bl_h[tid];
        for (int k = 0; k < ODIM; k++) {
            az += bg_z[k] * Wl_z[k * ODIM + tid];
            ah += bg_h[k] * Wl_h[k * ODIM + tid];
        }
        bz[tid] = az;
        bh[tid] = ah;
    }
    if (tid == 0) {
        float m = -1e30f;
        for (int t = 0; t < TDIM; t++) m = fmaxf(m, att[t]);
        float e[TDIM], s = 0.f;
        for (int t = 0; t < TDIM; t++) { e[t] = expf(att[t] - m); s += e[t]; }
        for (int t = 0; t < TDIM; t++) probs[t] = e[t] / s;
    }
}

// fp32 -> fp16 copy of X
__global__ __launch_bounds__(256) void k_cvt(const float4* __restrict__ in,
                                             uint2* __restrict__ out, int n4) {
    int i = blockIdx.x * 256 + threadIdx.x;
    const int stride = gridDim.x * 256;
    for (; i < n4; i += stride) {
        const float4 v = in[i];
        __half2 h0 = __floats2half2_rn(v.x, v.y);
        __half2 h1 = __floats2half2_rn(v.z, v.w);
        uint2 u;
        u.x = *reinterpret_cast<unsigned*>(&h0);
        u.y = *reinterpret_cast<unsigned*>(&h1);
        out[i] = u;
    }
}

__device__ __forceinline__ float sigm(float x) { return 1.f / (1.f + __expf(-x)); }
__device__ __forceinline__ float tanhfast(float x) { return 1.f - 2.f / (1.f + __expf(2.f * x)); }

// accumulate 8 halves of uint4 v scaled by m into a0..a7
#define H8ACC(m, v)                                                            \
    {                                                                          \
        float2 f0_ = __half22float2(*(__half2*)&(v).x);                        \
        float2 f1_ = __half22float2(*(__half2*)&(v).y);                        \
        float2 f2_ = __half22float2(*(__half2*)&(v).z);                        \
        float2 f3_ = __half22float2(*(__half2*)&(v).w);                        \
        a0 += (m) * f0_.x; a1 += (m) * f0_.y;                                  \
        a2 += (m) * f1_.x; a3 += (m) * f1_.y;                                  \
        a4 += (m) * f2_.x; a5 += (m) * f2_.y;                                  \
        a6 += (m) * f3_.x; a7 += (m) * f3_.y;                                  \
    }

#define GLOAD(dst, mvar, slot)                                                 \
    {                                                                          \
        int s_ = __shfl(esrc, (slot), 64);                                     \
        (mvar) = __shfl(enm, (slot), 64);                                      \
        (dst) = Xh[(rowB + (unsigned)s_) * 48u + lanec];                       \
    }

// Wave-independent main kernel. 256 threads = 4 independent waves.
// Wave task = (batch b, node n), b-major. No __syncthreads in main loop.
__global__ __launch_bounds__(256, 4) void k_main_w(
    const uint4* __restrict__ Xh, const int* __restrict__ offs,
    const int2* __restrict__ csr,
    const float* __restrict__ Wz, const float* __restrict__ bz,
    const float* __restrict__ Wh, const float* __restrict__ bh,
    const float* __restrict__ probs, const float* __restrict__ Wout,
    const float* __restrict__ bout, float* __restrict__ out, int N) {
    __shared__ float sWz[FDIM * ODIM];   // 8 KiB
    __shared__ float sWh[FDIM * ODIM];   // 8 KiB
    __shared__ float sY[4][FDIM * TDIM]; // 6 KiB, wave-private slices
    __shared__ float sProbs[TDIM];
    __shared__ float sBout[TDIM];

    const int tid = threadIdx.x;
    const int wv = tid >> 6;
    const int lane = tid & 63;
    const int lanec = lane < 47 ? lane : 47;  // clamp for row-load address

    for (int i = tid; i < FDIM * ODIM; i += 256) { sWz[i] = Wz[i]; sWh[i] = Wh[i]; }
    if (tid < TDIM) { sProbs[tid] = probs[tid]; sBout[tid] = bout[tid]; }
    __syncthreads();  // the only block barrier

    const float bzo = bz[lane], bho = bh[lane];
    float wout_r[TDIM];
#pragma unroll
    for (int j = 0; j < TDIM; j++) wout_r[j] = Wout[lane * TDIM + j];

    float* __restrict__ sy = sY[wv];
    const int totalWaves = gridDim.x * 4;
    const int totalTasks = N * BDIM;

    for (int task = blockIdx.x * 4 + wv; task < totalTasks; task += totalWaves) {
        const int b = task / N;          // b-major: concurrent waves share batch
        const int n = task - b * N;
        const unsigned rowB = (unsigned)b * (unsigned)N;
        const int beg = offs[n], end = offs[n + 1];

        // ---- gather: one uint4 wave-load per edge (48 active lanes) ----
        float a0 = 0.f, a1 = 0.f, a2 = 0.f, a3 = 0.f,
              a4 = 0.f, a5 = 0.f, a6 = 0.f, a7 = 0.f;
        for (int ebase = beg; ebase < end; ebase += 64) {
            const int wcnt = min(64, end - ebase);
            int esrc = 0;
            float enm = 0.f;
            if (ebase + lane < end) {
                const int2 e = csr[ebase + lane];
                esrc = e.x;
                enm = __int_as_float(e.y);
            }
            int j = 0;
            for (; j + 8 <= wcnt; j += 8) {
                uint4 x0, x1, x2, x3, x4, x5, x6, x7;
                float m0, m1, m2, m3, m4, m5, m6, m7;
                GLOAD(x0, m0, j + 0); GLOAD(x1, m1, j + 1);
                GLOAD(x2, m2, j + 2); GLOAD(x3, m3, j + 3);
                GLOAD(x4, m4, j + 4); GLOAD(x5, m5, j + 5);
                GLOAD(x6, m6, j + 6); GLOAD(x7, m7, j + 7);
                H8ACC(m0, x0); H8ACC(m1, x1); H8ACC(m2, x2); H8ACC(m3, x3);
                H8ACC(m4, x4); H8ACC(m5, x5); H8ACC(m6, x6); H8ACC(m7, x7);
            }
            for (; j < wcnt; j++) {
                uint4 xv;
                float mv;
                GLOAD(xv, mv, j);
                H8ACC(mv, xv);
            }
        }
        // deposit Y (f-major flat: idx = f*12+t = lane*8+k), wave-private
        if (lane < 48) {
            float4* d4 = (float4*)&sy[lane * 8];
            d4[0] = make_float4(a0, a1, a2, a3);
            d4[1] = make_float4(a4, a5, a6, a7);
        }
        // same-wave LDS write->read: compiler inserts lgkmcnt wait; no barrier

        // ---- gates: all 12 t, z/h in registers, weights from LDS ----
        float z[TDIM], h[TDIM];
#pragma unroll
        for (int t = 0; t < TDIM; t++) { z[t] = bzo; h[t] = bho; }
#pragma unroll
        for (int f = 0; f < FDIM; f++) {
            const float wzf = sWz[f * ODIM + lane];
            const float whf = sWh[f * ODIM + lane];
            const float4 y0 = *(const float4*)&sy[f * TDIM + 0];
            const float4 y1 = *(const float4*)&sy[f * TDIM + 4];
            const float4 y2 = *(const float4*)&sy[f * TDIM + 8];
            z[0] += y0.x * wzf; h[0] += y0.x * whf;
            z[1] += y0.y * wzf; h[1] += y0.y * whf;
            z[2] += y0.z * wzf; h[2] += y0.z * whf;
            z[3] += y0.w * wzf; h[3] += y0.w * whf;
            z[4] += y1.x * wzf; h[4] += y1.x * whf;
            z[5] += y1.y * wzf; h[5] += y1.y * whf;
            z[6] += y1.z * wzf; h[6] += y1.z * whf;
            z[7] += y1.w * wzf; h[7] += y1.w * whf;
            z[8] += y2.x * wzf; h[8] += y2.x * whf;
            z[9] += y2.y * wzf; h[9] += y2.y * whf;
            z[10] += y2.z * wzf; h[10] += y2.z * whf;
            z[11] += y2.w * wzf; h[11] += y2.w * whf;
        }
        float acc = 0.f;
#pragma unroll
        for (int t = 0; t < TDIM; t++) {
            const float Zt = sigm(z[t]);
            const float Ht = tanhfast(h[t]);
            acc += sProbs[t] * (1.f - Zt) * Ht;
        }

        // ---- readout: butterfly-reduce relu(acc)*Wout over o ----
        const float r = fmaxf(acc, 0.f);
        float v[TDIM];
#pragma unroll
        for (int j = 0; j < TDIM; j++) v[j] = r * wout_r[j];
#pragma unroll
        for (int m = 1; m < 64; m <<= 1) {
#pragma unroll
            for (int j = 0; j < TDIM; j++) v[j] += __shfl_xor(v[j], m, 64);
        }
        float vout = 0.f;
#pragma unroll
        for (int j = 0; j < TDIM; j++) vout = (lane == j) ? v[j] : vout;
        if (lane < TDIM)
            out[(rowB + (unsigned)n) * TDIM + lane] = vout + sBout[lane];
    }
}

// fp32 fallback (no fp16 workspace): consumes self-inclusive csr. (R9 kernel)
__global__ __launch_bounds__(384) void k_main_f(
    const float* __restrict__ X, const int* __restrict__ offsets,
    const int2* __restrict__ csr, const float* __restrict__ dis,
    const float* __restrict__ Wz, const float* __restrict__ bz,
    const float* __restrict__ Wh, const float* __restrict__ bh,
    const float* __restrict__ probs, const float* __restrict__ Wout,
    const float* __restrict__ bout, float* __restrict__ out, int N) {
    const int tid = threadIdx.x;
    const int lane = tid & 63;

    __shared__ float4 sY4[BDIM][96];
    __shared__ float sAcc[BDIM][ODIM];
    __shared__ float sWout[ODIM * TDIM];
    __shared__ float sBout[TDIM];

    for (int i = tid; i < ODIM * TDIM; i += 384) sWout[i] = Wout[i];
    if (tid < TDIM) sBout[tid] = bout[tid];

    const int o = tid & 63;
    const int w = tid >> 6;
    float wzr[FDIM], whr[FDIM];
#pragma unroll
    for (int f = 0; f < FDIM; f++) {
        wzr[f] = Wz[f * ODIM + o];
        whr[f] = Wh[f * ODIM + o];
    }
    const float bzo = bz[o], bho = bh[o];
    const int t0 = w, t1 = w + 6;
    const float p0 = probs[t0], p1 = probs[t1];

    const int b = tid / 96;
    const int q = tid - b * 96;
    const float4* __restrict__ Xq = (const float4*)X;
    const unsigned rowBase = (unsigned)b * (unsigned)N;

    for (int n = blockIdx.x; n < N; n += gridDim.x) {
        if (tid < BDIM * ODIM) ((float*)sAcc)[tid] = 0.f;

        const int beg = offsets[n], end = offsets[n + 1];
        float4 A0 = make_float4(0.f, 0.f, 0.f, 0.f);
        float4 A1 = A0, A2 = A0, A3 = A0;

        for (int ebase = beg; ebase < end; ebase += 64) {
            const int cnt2 = min(64, end - ebase);
            int esrc = 0;
            float enm = 0.f;
            if (ebase + lane < end) {
                const int2 e = csr[ebase + lane];
                esrc = e.x;
                enm = __int_as_float(e.y);
            }
            int j = 0;
            for (; j + 4 <= cnt2; j += 4) {
                const int s0 = __shfl(esrc, j + 0, 64), s1 = __shfl(esrc, j + 1, 64);
                const int s2 = __shfl(esrc, j + 2, 64), s3 = __shfl(esrc, j + 3, 64);
                const float m0 = __shfl(enm, j + 0, 64), m1 = __shfl(enm, j + 1, 64);
                const float m2 = __shfl(enm, j + 2, 64), m3 = __shfl(enm, j + 3, 64);
                const float4 u0 = Xq[(rowBase + s0) * 96u + q];
                const float4 u1 = Xq[(rowBase + s1) * 96u + q];
                const float4 u2 = Xq[(rowBase + s2) * 96u + q];
                const float4 u3 = Xq[(rowBase + s3) * 96u + q];
                A0.x += m0 * u0.x; A0.y += m0 * u0.y; A0.z += m0 * u0.z; A0.w += m0 * u0.w;
                A1.x += m1 * u1.x; A1.y += m1 * u1.y; A1.z += m1 * u1.z; A1.w += m1 * u1.w;
                A2.x += m2 * u2.x; A2.y += m2 * u2.y; A2.z += m2 * u2.z; A2.w += m2 * u2.w;
                A3.x += m3 * u3.x; A3.y += m3 * u3.y; A3.z += m3 * u3.z; A3.w += m3 * u3.w;
            }
            for (; j < cnt2; j++) {
                const int s = __shfl(esrc, j, 64);
                const float m = __shfl(enm, j, 64);
                const float4 u = Xq[(rowBase + s) * 96u + q];
                A0.x += m * u.x; A0.y += m * u.y; A0.z += m * u.z; A0.w += m * u.w;
            }
        }
        A0.x += (A1.x + A2.x) + A3.x;
        A0.y += (A1.y + A2.y) + A3.y;
        A0.z += (A1.z + A2.z) + A3.z;
        A0.w += (A1.w + A2.w) + A3.w;
        sY4[b][q] = A0;
        __syncthreads();

#pragma unroll
        for (int bb = 0; bb < BDIM; bb++) {
            const float* yb = (const float*)sY4[bb];
            float z0 = bzo, z1 = bzo, h0 = bho, h1 = bho;
#pragma unroll
            for (int f = 0; f < FDIM; f++) {
                float ya = yb[f * TDIM + t0];
                float yc = yb[f * TDIM + t1];
                z0 += ya * wzr[f]; h0 += ya * whr[f];
                z1 += yc * wzr[f]; h1 += yc * whr[f];
            }
            float contrib = p0 * (1.f - sigm(z0)) * tanhfast(h0)
                          + p1 * (1.f - sigm(z1)) * tanhfast(h1);
            atomicAdd(&sAcc[bb][o], contrib);
        }
        __syncthreads();

        if (tid < BDIM * TDIM) {
            int ob = tid / TDIM, jj = tid - ob * TDIM;
            float v = sBout[jj];
#pragma unroll
            for (int o2 = 0; o2 < ODIM; o2++) {
                v += fmaxf(sAcc[ob][o2], 0.f) * sWout[o2 * TDIM + jj];
            }
            out[(unsigned)(ob * N + n) * TDIM + jj] = v;
        }
        __syncthreads();
    }
}

extern "C" void kernel_launch(void* const* d_in, const int* in_sizes, int n_in,
                              void* d_out, int out_size, void* d_ws, size_t ws_size,
                              hipStream_t stream) {
    const float* X    = (const float*)d_in[0];
    const int*   ei   = (const int*)d_in[1];
    const float* Wg_z = (const float*)d_in[2];
    const float* bg_z = (const float*)d_in[3];
    const float* Wg_h = (const float*)d_in[6];
    const float* bg_h = (const float*)d_in[7];
    const float* Wl_z = (const float*)d_in[8];
    const float* bl_z = (const float*)d_in[9];
    const float* Wl_h = (const float*)d_in[12];
    const float* bl_h = (const float*)d_in[13];
    const float* att  = (const float*)d_in[14];
    const float* Wout = (const float*)d_in[15];
    const float* bout = (const float*)d_in[16];
    float* out = (float*)d_out;

    const int E = in_sizes[1] / 2;
    const int N = in_sizes[0] / (BDIM * FDIM * TDIM);
    const size_t xElems = (size_t)BDIM * N * FDIM * TDIM;
    const size_t xhBytes = xElems * 2;
    const size_t csrBytes = (size_t)(E + N) * 8;
    const size_t restBytes = (size_t)N * 4 * 4 + 64 + csrBytes + 20000;
    const bool useH = ws_size >= xhBytes + restBytes;

    char* wp = (char*)d_ws;
    uint2* Xh = nullptr;
    if (useH) { Xh = (uint2*)wp; wp += xhBytes; }
    int* counts   = (int*)wp;   wp += (size_t)N * 4;
    int* fill     = (int*)wp;   wp += (size_t)N * 4;
    int* offs     = (int*)wp;   wp += (size_t)(N + 4) * 4;
    float* dis    = (float*)wp; wp += (size_t)N * 4;
    int2* csr     = (int2*)wp;  wp += csrBytes;
    float* Wz     = (float*)wp; wp += FDIM * ODIM * 4;
    float* Wh     = (float*)wp; wp += FDIM * ODIM * 4;
    float* bz     = (float*)wp; wp += ODIM * 4;
    float* bh     = (float*)wp; wp += ODIM * 4;
    float* probs  = (float*)wp; wp += 16 * 4;

    hipMemsetAsync(counts, 0, (size_t)N * 4, stream);

    k_prep<<<1, 256, 0, stream>>>(Wg_z, bg_z, Wl_z, bl_z, Wg_h, bg_h, Wl_h, bl_h,
                                  att, Wz, bz, Wh, bh, probs);
    if (useH) {
        const int n4 = (int)(xElems / 4);
        k_cvt<<<2048, 256, 0, stream>>>((const float4*)X, Xh, n4);
    }
    k_count<<<(E + 255) / 256, 256, 0, stream>>>(ei + E, counts, E);
    k_scan<<<1, 1024, 0, stream>>>(counts, offs, dis, N);
    k_self<<<(N + 255) / 256, 256, 0, stream>>>(offs, dis, fill, csr, N);
    k_scatter<<<(E + 255) / 256, 256, 0, stream>>>(ei, ei + E, offs, fill, dis, csr, E);

    if (useH) {
        k_main_w<<<2048, 256, 0, stream>>>((const uint4*)Xh, offs, csr,
                                           Wz, bz, Wh, bh, probs, Wout, bout, out, N);
    } else {
        int nB = N < 2048 ? N : 2048;
        k_main_f<<<nB, 384, 0, stream>>>(X, offs, csr, dis, Wz, bz, Wh, bh,
                                         probs, Wout, bout, out, N);
    }
}

// Round 11
// 449.638 us; speedup vs baseline: 2.7060x; 1.1226x over previous
//
#include <hip/hip_runtime.h>
#include <hip/hip_bf16.h>
#include <hip/hip_fp16.h>

// TemporalGNN: GRU's H stays zero => R dead, timesteps independent.
// out[b,n,:] = relu( sum_t p_t*(1-Z_t)*Ht_t ) @ W_out + b_out
//   Z  = sigmoid(Y_t @ Wz + bz),  Ht = tanh(Y_t @ Wh + bh)
//   Y_t = sym-normalized aggregation (self-loop in CSR) in F=32 space.
// R11 = R10 wave-independent structure + MFMA gates: the 768-FMA gate GEMV per
// task becomes 8x mfma_f32_16x16x32_f16 (K=32=F in one shot) on the idle
// matrix pipe. Weights as persistent fp16 B-frags in registers; Y transposed
// through padded LDS [t][f] (stride 36) to form the A-frag.

#define FDIM 32
#define TDIM 12
#define ODIM 64
#define BDIM 4

typedef _Float16 half8v __attribute__((ext_vector_type(8)));
typedef float float4v __attribute__((ext_vector_type(4)));

__global__ void k_count(const int* __restrict__ dst, int* __restrict__ counts, int E) {
    int e = blockIdx.x * 256 + threadIdx.x;
    if (e < E) atomicAdd(&counts[dst[e]], 1);
}

// exclusive scan of (counts[i]+1) (self-loop slot); dis = rsqrt(deg+1)
__global__ __launch_bounds__(1024) void k_scan(const int* __restrict__ counts,
                                               int* __restrict__ offsets,
                                               float* __restrict__ dis, int N) {
    __shared__ int wsum[16];
    __shared__ int sCarry;
    const int tid = threadIdx.x;
    const int lane = tid & 63;
    const int wv = tid >> 6;
    if (tid == 0) sCarry = 0;
    __syncthreads();
    for (int base = 0; base < N; base += 1024) {
        int i = base + tid;
        int v = (i < N) ? (counts[i] + 1) : 0;
        int s = v;
        for (int off = 1; off < 64; off <<= 1) {
            int t = __shfl_up(s, off, 64);
            if (lane >= off) s += t;
        }
        if (lane == 63) wsum[wv] = s;
        __syncthreads();
        if (wv == 0 && lane < 16) {
            int ws = wsum[lane];
            for (int off = 1; off < 16; off <<= 1) {
                int t = __shfl_up(ws, off, 64);
                if (lane >= off) ws += t;
            }
            wsum[lane] = ws;
        }
        __syncthreads();
        int carry = sCarry;
        int wpre = (wv > 0) ? wsum[wv - 1] : 0;
        if (i < N) {
            offsets[i] = carry + wpre + s - v;
            dis[i] = 1.0f / sqrtf((float)v);
        }
        __syncthreads();
        if (tid == 0) sCarry = carry + wsum[15];
        __syncthreads();
    }
    if (tid == 0) offsets[N] = sCarry;
}

__global__ void k_self(const int* __restrict__ offsets, const float* __restrict__ dis,
                       int* __restrict__ fill, int2* __restrict__ csr, int N) {
    int n = blockIdx.x * 256 + threadIdx.x;
    if (n < N) {
        float d = dis[n];
        csr[offsets[n]] = make_int2(n, __float_as_int(d * d));
        fill[n] = 1;
    }
}

__global__ void k_scatter(const int* __restrict__ src, const int* __restrict__ dst,
                          const int* __restrict__ offsets, int* __restrict__ fill,
                          const float* __restrict__ dis,
                          int2* __restrict__ csr, int E) {
    int e = blockIdx.x * 256 + threadIdx.x;
    if (e < E) {
        int s = src[e], d = dst[e];
        int pos = offsets[d] + atomicAdd(&fill[d], 1);
        csr[pos] = make_int2(s, __float_as_int(dis[s] * dis[d]));
    }
}

__global__ void k_prep(const float* __restrict__ Wg_z, const float* __restrict__ bg_z,
                       const float* __restrict__ Wl_z, const float* __restrict__ bl_z,
                       const float* __restrict__ Wg_h, const float* __restrict__ bg_h,
                       const float* __restrict__ Wl_h, const float* __restrict__ bl_h,
                       const float* __restrict__ att,
                       float* __restrict__ Wz, float* __restrict__ bz,
                       float* __restrict__ Wh, float* __restrict__ bh,
                       float* __restrict__ probs) {
    int tid = threadIdx.x;
    for (int i = tid; i < FDIM * ODIM; i += 256) {
        int f = i >> 6, o = i & 63;
        float az = 0.f, ah = 0.f;
        for (int k = 0; k < ODIM; k++) {
            az += Wg_z[f * ODIM + k] * Wl_z[k * ODIM + o];
            ah += Wg_h[f * ODIM + k] * Wl_h[k * ODIM + o];
        }
        Wz[i] = az;
        Wh[i] = ah;
    }
    if (tid < ODIM) {
        float az = bl_z[tid], ah = bl_h[tid];
        for (int k = 0; k < ODIM; k++) {
            az += bg_z[k] * Wl_z[k * ODIM + tid];
            ah += bg_h[k] * Wl_h[k * ODIM + tid];
        }
        bz[tid] = az;
        bh[tid] = ah;
    }
    if (tid == 0) {
        float m = -1e30f;
        for (int t = 0; t < TDIM; t++) m = fmaxf(m, att[t]);
        float e[TDIM], s = 0.f;
        for (int t = 0; t < TDIM; t++) { e[t] = expf(att[t] - m); s += e[t]; }
        for (int t = 0; t < TDIM; t++) probs[t] = e[t] / s;
    }
}

// fp32 -> fp16 copy of X
__global__ __launch_bounds__(256) void k_cvt(const float4* __restrict__ in,
                                             uint2* __restrict__ out, int n4) {
    int i = blockIdx.x * 256 + threadIdx.x;
    const int stride = gridDim.x * 256;
    for (; i < n4; i += stride) {
        const float4 v = in[i];
        __half2 h0 = __floats2half2_rn(v.x, v.y);
        __half2 h1 = __floats2half2_rn(v.z, v.w);
        uint2 u;
        u.x = *reinterpret_cast<unsigned*>(&h0);
        u.y = *reinterpret_cast<unsigned*>(&h1);
        out[i] = u;
    }
}

__device__ __forceinline__ float sigm(float x) { return 1.f / (1.f + __expf(-x)); }
__device__ __forceinline__ float tanhfast(float x) { return 1.f - 2.f / (1.f + __expf(2.f * x)); }

// accumulate 8 halves of uint4 v scaled by m into a0..a7
#define H8ACC(m, v)                                                            \
    {                                                                          \
        float2 f0_ = __half22float2(*(__half2*)&(v).x);                        \
        float2 f1_ = __half22float2(*(__half2*)&(v).y);                        \
        float2 f2_ = __half22float2(*(__half2*)&(v).z);                        \
        float2 f3_ = __half22float2(*(__half2*)&(v).w);                        \
        a0 += (m) * f0_.x; a1 += (m) * f0_.y;                                  \
        a2 += (m) * f1_.x; a3 += (m) * f1_.y;                                  \
        a4 += (m) * f2_.x; a5 += (m) * f2_.y;                                  \
        a6 += (m) * f3_.x; a7 += (m) * f3_.y;                                  \
    }

#define GLOAD(dst, mvar, slot)                                                 \
    {                                                                          \
        int s_ = __shfl(esrc, (slot), 64);                                     \
        (mvar) = __shfl(enm, (slot), 64);                                      \
        (dst) = Xh[(rowB + (unsigned)s_) * 48u + lanec];                       \
    }

// B-frag (weights) preload: B[k][col]: col=lane&15, k=(lane>>4)*8+r
#define LOADB(dst, Wsrc, jt)                                                   \
    {                                                                          \
        _Pragma("unroll") for (int r_ = 0; r_ < 8; r_++)                       \
            dst[r_] = (_Float16)Wsrc[(kg * 8 + r_) * ODIM + (jt) * 16 + c];    \
    }

// epilogue for one column tile jt: q = reduced acc[jt*16 + c]
#define EPI(qv, dzv, dhv, bzv, bhv)                                            \
    {                                                                          \
        float s_ = 0.f;                                                        \
        {  float zf_ = dzv[0] + bzv, hf_ = dhv[0] + bhv;                       \
           s_ += pr0 * (1.f - sigm(zf_)) * tanhfast(hf_); }                    \
        {  float zf_ = dzv[1] + bzv, hf_ = dhv[1] + bhv;                       \
           s_ += pr1 * (1.f - sigm(zf_)) * tanhfast(hf_); }                    \
        {  float zf_ = dzv[2] + bzv, hf_ = dhv[2] + bhv;                       \
           s_ += pr2 * (1.f - sigm(zf_)) * tanhfast(hf_); }                    \
        {  float zf_ = dzv[3] + bzv, hf_ = dhv[3] + bhv;                       \
           s_ += pr3 * (1.f - sigm(zf_)) * tanhfast(hf_); }                    \
        s_ += __shfl_xor(s_, 16, 64);                                          \
        s_ += __shfl_xor(s_, 32, 64);                                          \
        qv = s_;                                                               \
    }

// Wave-independent main kernel + MFMA gates. 256 threads = 4 independent waves.
__global__ __launch_bounds__(256, 4) void k_main_w(
    const uint4* __restrict__ Xh, const int* __restrict__ offs,
    const int2* __restrict__ csr,
    const float* __restrict__ Wz, const float* __restrict__ bz,
    const float* __restrict__ Wh, const float* __restrict__ bh,
    const float* __restrict__ probs, const float* __restrict__ Wout,
    const float* __restrict__ bout, float* __restrict__ out, int N) {
    __shared__ float sY[4][16 * 36 + 4];   // [t][f] padded stride 36; ~9.3 KiB

    const int tid = threadIdx.x;
    const int wv = tid >> 6;
    const int lane = tid & 63;
    const int lanec = lane < 47 ? lane : 47;
    const int c = lane & 15;         // MFMA col (A-row / D-col)
    const int kg = lane >> 4;        // MFMA k-group (and D row-group)

    // persistent per-wave state
    half8v wzf0, wzf1, wzf2, wzf3, whf0, whf1, whf2, whf3;
    LOADB(wzf0, Wz, 0) LOADB(wzf1, Wz, 1) LOADB(wzf2, Wz, 2) LOADB(wzf3, Wz, 3)
    LOADB(whf0, Wh, 0) LOADB(whf1, Wh, 1) LOADB(whf2, Wh, 2) LOADB(whf3, Wh, 3)
    const float bz0 = bz[c], bz1 = bz[16 + c], bz2 = bz[32 + c], bz3 = bz[48 + c];
    const float bh0 = bh[c], bh1 = bh[16 + c], bh2 = bh[32 + c], bh3 = bh[48 + c];
    const float pr0 = (kg * 4 + 0 < TDIM) ? probs[kg * 4 + 0] : 0.f;
    const float pr1 = (kg * 4 + 1 < TDIM) ? probs[kg * 4 + 1] : 0.f;
    const float pr2 = (kg * 4 + 2 < TDIM) ? probs[kg * 4 + 2] : 0.f;
    const float pr3 = (kg * 4 + 3 < TDIM) ? probs[kg * 4 + 3] : 0.f;
    float wout_r[TDIM];
#pragma unroll
    for (int j = 0; j < TDIM; j++) wout_r[j] = Wout[lane * TDIM + j];
    const float bo = (lane < TDIM) ? bout[lane] : 0.f;

    float* __restrict__ sy = sY[wv];
    const int totalWaves = gridDim.x * 4;
    const int totalTasks = N * BDIM;

    for (int task = blockIdx.x * 4 + wv; task < totalTasks; task += totalWaves) {
        const int b = task / N;
        const int n = task - b * N;
        const unsigned rowB = (unsigned)b * (unsigned)N;
        const int beg = offs[n], end = offs[n + 1];

        // ---- gather: one uint4 wave-load per edge (48 active lanes) ----
        float a0 = 0.f, a1 = 0.f, a2 = 0.f, a3 = 0.f,
              a4 = 0.f, a5 = 0.f, a6 = 0.f, a7 = 0.f;
        for (int ebase = beg; ebase < end; ebase += 64) {
            const int wcnt = min(64, end - ebase);
            int esrc = 0;
            float enm = 0.f;
            if (ebase + lane < end) {
                const int2 e = csr[ebase + lane];
                esrc = e.x;
                enm = __int_as_float(e.y);
            }
            int j = 0;
            for (; j + 8 <= wcnt; j += 8) {
                uint4 x0, x1, x2, x3, x4, x5, x6, x7;
                float m0, m1, m2, m3, m4, m5, m6, m7;
                GLOAD(x0, m0, j + 0); GLOAD(x1, m1, j + 1);
                GLOAD(x2, m2, j + 2); GLOAD(x3, m3, j + 3);
                GLOAD(x4, m4, j + 4); GLOAD(x5, m5, j + 5);
                GLOAD(x6, m6, j + 6); GLOAD(x7, m7, j + 7);
                H8ACC(m0, x0); H8ACC(m1, x1); H8ACC(m2, x2); H8ACC(m3, x3);
                H8ACC(m4, x4); H8ACC(m5, x5); H8ACC(m6, x6); H8ACC(m7, x7);
            }
            for (; j < wcnt; j++) {
                uint4 xv;
                float mv;
                GLOAD(xv, mv, j);
                H8ACC(mv, xv);
            }
        }

        // ---- deposit Y to LDS transposed [t][f] (stride 36) ----
        if (lane < 48) {
            int flat = lane * 8;               // = f*12 + t
            int f = flat / 12;
            int t = flat - f * 12;
#pragma unroll
            for (int k = 0; k < 8; k++) {
                float av = (k == 0) ? a0 : (k == 1) ? a1 : (k == 2) ? a2 :
                           (k == 3) ? a3 : (k == 4) ? a4 : (k == 5) ? a5 :
                           (k == 6) ? a6 : a7;
                sy[t * 36 + f] = av;
                t++;
                if (t == TDIM) { t = 0; f++; }
            }
        }
        // same-wave LDS write->read (compiler inserts lgkmcnt); no barrier

        // ---- A-frag: row=c (t), k=kg*8+j (f) ----
        half8v af;
        if (c < TDIM) {
            const float4* yp = (const float4*)&sy[c * 36 + kg * 8];
            const float4 y0 = yp[0];
            const float4 y1 = yp[1];
            af[0] = (_Float16)y0.x; af[1] = (_Float16)y0.y;
            af[2] = (_Float16)y0.z; af[3] = (_Float16)y0.w;
            af[4] = (_Float16)y1.x; af[5] = (_Float16)y1.y;
            af[6] = (_Float16)y1.z; af[7] = (_Float16)y1.w;
        } else {
            af[0] = (_Float16)0.f; af[1] = (_Float16)0.f;
            af[2] = (_Float16)0.f; af[3] = (_Float16)0.f;
            af[4] = (_Float16)0.f; af[5] = (_Float16)0.f;
            af[6] = (_Float16)0.f; af[7] = (_Float16)0.f;
        }

        // ---- gates via MFMA: [16x32] @ [32x128] in 8 tiles ----
        const float4v zero4 = {0.f, 0.f, 0.f, 0.f};
        float4v dz0 = __builtin_amdgcn_mfma_f32_16x16x32_f16(af, wzf0, zero4, 0, 0, 0);
        float4v dz1 = __builtin_amdgcn_mfma_f32_16x16x32_f16(af, wzf1, zero4, 0, 0, 0);
        float4v dz2 = __builtin_amdgcn_mfma_f32_16x16x32_f16(af, wzf2, zero4, 0, 0, 0);
        float4v dz3 = __builtin_amdgcn_mfma_f32_16x16x32_f16(af, wzf3, zero4, 0, 0, 0);
        float4v dh0 = __builtin_amdgcn_mfma_f32_16x16x32_f16(af, whf0, zero4, 0, 0, 0);
        float4v dh1 = __builtin_amdgcn_mfma_f32_16x16x32_f16(af, whf1, zero4, 0, 0, 0);
        float4v dh2 = __builtin_amdgcn_mfma_f32_16x16x32_f16(af, whf2, zero4, 0, 0, 0);
        float4v dh3 = __builtin_amdgcn_mfma_f32_16x16x32_f16(af, whf3, zero4, 0, 0, 0);

        // ---- epilogue: D row = kg*4+r = t, col = jt*16+c = o ----
        float q0, q1, q2, q3;
        EPI(q0, dz0, dh0, bz0, bh0)
        EPI(q1, dz1, dh1, bz1, bh1)
        EPI(q2, dz2, dh2, bz2, bh2)
        EPI(q3, dz3, dh3, bz3, bh3)
        const float accOwn = (kg == 0) ? q0 : (kg == 1) ? q1 : (kg == 2) ? q2 : q3;

        // ---- readout: butterfly-reduce relu(acc)*Wout over o(=lane) ----
        const float r = fmaxf(accOwn, 0.f);
        float v[TDIM];
#pragma unroll
        for (int j = 0; j < TDIM; j++) v[j] = r * wout_r[j];
#pragma unroll
        for (int m = 1; m < 64; m <<= 1) {
#pragma unroll
            for (int j = 0; j < TDIM; j++) v[j] += __shfl_xor(v[j], m, 64);
        }
        float vout = 0.f;
#pragma unroll
        for (int j = 0; j < TDIM; j++) vout = (lane == j) ? v[j] : vout;
        if (lane < TDIM)
            out[(rowB + (unsigned)n) * TDIM + lane] = vout + bo;
    }
}

// fp32 fallback (no fp16 workspace): consumes self-inclusive csr.
__global__ __launch_bounds__(384) void k_main_f(
    const float* __restrict__ X, const int* __restrict__ offsets,
    const int2* __restrict__ csr, const float* __restrict__ dis,
    const float* __restrict__ Wz, const float* __restrict__ bz,
    const float* __restrict__ Wh, const float* __restrict__ bh,
    const float* __restrict__ probs, const float* __restrict__ Wout,
    const float* __restrict__ bout, float* __restrict__ out, int N) {
    const int tid = threadIdx.x;
    const int lane = tid & 63;

    __shared__ float4 sY4[BDIM][96];
    __shared__ float sAcc[BDIM][ODIM];
    __shared__ float sWout[ODIM * TDIM];
    __shared__ float sBout[TDIM];

    for (int i = tid; i < ODIM * TDIM; i += 384) sWout[i] = Wout[i];
    if (tid < TDIM) sBout[tid] = bout[tid];

    const int o = tid & 63;
    const int w = tid >> 6;
    float wzr[FDIM], whr[FDIM];
#pragma unroll
    for (int f = 0; f < FDIM; f++) {
        wzr[f] = Wz[f * ODIM + o];
        whr[f] = Wh[f * ODIM + o];
    }
    const float bzo = bz[o], bho = bh[o];
    const int t0 = w, t1 = w + 6;
    const float p0 = probs[t0], p1 = probs[t1];

    const int b = tid / 96;
    const int q = tid - b * 96;
    const float4* __restrict__ Xq = (const float4*)X;
    const unsigned rowBase = (unsigned)b * (unsigned)N;

    for (int n = blockIdx.x; n < N; n += gridDim.x) {
        if (tid < BDIM * ODIM) ((float*)sAcc)[tid] = 0.f;

        const int beg = offsets[n], end = offsets[n + 1];
        float4 A0 = make_float4(0.f, 0.f, 0.f, 0.f);
        float4 A1 = A0, A2 = A0, A3 = A0;

        for (int ebase = beg; ebase < end; ebase += 64) {
            const int cnt2 = min(64, end - ebase);
            int esrc = 0;
            float enm = 0.f;
            if (ebase + lane < end) {
                const int2 e = csr[ebase + lane];
                esrc = e.x;
                enm = __int_as_float(e.y);
            }
            int j = 0;
            for (; j + 4 <= cnt2; j += 4) {
                const int s0 = __shfl(esrc, j + 0, 64), s1 = __shfl(esrc, j + 1, 64);
                const int s2 = __shfl(esrc, j + 2, 64), s3 = __shfl(esrc, j + 3, 64);
                const float m0 = __shfl(enm, j + 0, 64), m1 = __shfl(enm, j + 1, 64);
                const float m2 = __shfl(enm, j + 2, 64), m3 = __shfl(enm, j + 3, 64);
                const float4 u0 = Xq[(rowBase + s0) * 96u + q];
                const float4 u1 = Xq[(rowBase + s1) * 96u + q];
                const float4 u2 = Xq[(rowBase + s2) * 96u + q];
                const float4 u3 = Xq[(rowBase + s3) * 96u + q];
                A0.x += m0 * u0.x; A0.y += m0 * u0.y; A0.z += m0 * u0.z; A0.w += m0 * u0.w;
                A1.x += m1 * u1.x; A1.y += m1 * u1.y; A1.z += m1 * u1.z; A1.w += m1 * u1.w;
                A2.x += m2 * u2.x; A2.y += m2 * u2.y; A2.z += m2 * u2.z; A2.w += m2 * u2.w;
                A3.x += m3 * u3.x; A3.y += m3 * u3.y; A3.z += m3 * u3.z; A3.w += m3 * u3.w;
            }
            for (; j < cnt2; j++) {
                const int s = __shfl(esrc, j, 64);
                const float m = __shfl(enm, j, 64);
                const float4 u = Xq[(rowBase + s) * 96u + q];
                A0.x += m * u.x; A0.y += m * u.y; A0.z += m * u.z; A0.w += m * u.w;
            }
        }
        A0.x += (A1.x + A2.x) + A3.x;
        A0.y += (A1.y + A2.y) + A3.y;
        A0.z += (A1.z + A2.z) + A3.z;
        A0.w += (A1.w + A2.w) + A3.w;
        sY4[b][q] = A0;
        __syncthreads();

#pragma unroll
        for (int bb = 0; bb < BDIM; bb++) {
            const float* yb = (const float*)sY4[bb];
            float z0 = bzo, z1 = bzo, h0 = bho, h1 = bho;
#pragma unroll
            for (int f = 0; f < FDIM; f++) {
                float ya = yb[f * TDIM + t0];
                float yc = yb[f * TDIM + t1];
                z0 += ya * wzr[f]; h0 += ya * whr[f];
                z1 += yc * wzr[f]; h1 += yc * whr[f];
            }
            float contrib = p0 * (1.f - sigm(z0)) * tanhfast(h0)
                          + p1 * (1.f - sigm(z1)) * tanhfast(h1);
            atomicAdd(&sAcc[bb][o], contrib);
        }
        __syncthreads();

        if (tid < BDIM * TDIM) {
            int ob = tid / TDIM, jj = tid - ob * TDIM;
            float v = sBout[jj];
#pragma unroll
            for (int o2 = 0; o2 < ODIM; o2++) {
                v += fmaxf(sAcc[ob][o2], 0.f) * sWout[o2 * TDIM + jj];
            }
            out[(unsigned)(ob * N + n) * TDIM + jj] = v;
        }
        __syncthreads();
    }
}

extern "C" void kernel_launch(void* const* d_in, const int* in_sizes, int n_in,
                              void* d_out, int out_size, void* d_ws, size_t ws_size,
                              hipStream_t stream) {
    const float* X    = (const float*)d_in[0];
    const int*   ei   = (const int*)d_in[1];
    const float* Wg_z = (const float*)d_in[2];
    const float* bg_z = (const float*)d_in[3];
    const float* Wg_h = (const float*)d_in[6];
    const float* bg_h = (const float*)d_in[7];
    const float* Wl_z = (const float*)d_in[8];
    const float* bl_z = (const float*)d_in[9];
    const float* Wl_h = (const float*)d_in[12];
    const float* bl_h = (const float*)d_in[13];
    const float* att  = (const float*)d_in[14];
    const float* Wout = (const float*)d_in[15];
    const float* bout = (const float*)d_in[16];
    float* out = (float*)d_out;

    const int E = in_sizes[1] / 2;
    const int N = in_sizes[0] / (BDIM * FDIM * TDIM);
    const size_t xElems = (size_t)BDIM * N * FDIM * TDIM;
    const size_t xhBytes = xElems * 2;
    const size_t csrBytes = (size_t)(E + N) * 8;
    const size_t restBytes = (size_t)N * 4 * 4 + 64 + csrBytes + 20000;
    const bool useH = ws_size >= xhBytes + restBytes;

    char* wp = (char*)d_ws;
    uint2* Xh = nullptr;
    if (useH) { Xh = (uint2*)wp; wp += xhBytes; }
    int* counts   = (int*)wp;   wp += (size_t)N * 4;
    int* fill     = (int*)wp;   wp += (size_t)N * 4;
    int* offs     = (int*)wp;   wp += (size_t)(N + 4) * 4;
    float* dis    = (float*)wp; wp += (size_t)N * 4;
    int2* csr     = (int2*)wp;  wp += csrBytes;
    float* Wz     = (float*)wp; wp += FDIM * ODIM * 4;
    float* Wh     = (float*)wp; wp += FDIM * ODIM * 4;
    float* bz     = (float*)wp; wp += ODIM * 4;
    float* bh     = (float*)wp; wp += ODIM * 4;
    float* probs  = (float*)wp; wp += 16 * 4;

    hipMemsetAsync(counts, 0, (size_t)N * 4, stream);

    k_prep<<<1, 256, 0, stream>>>(Wg_z, bg_z, Wl_z, bl_z, Wg_h, bg_h, Wl_h, bl_h,
                                  att, Wz, bz, Wh, bh, probs);
    if (useH) {
        const int n4 = (int)(xElems / 4);
        k_cvt<<<2048, 256, 0, stream>>>((const float4*)X, Xh, n4);
    }
    k_count<<<(E + 255) / 256, 256, 0, stream>>>(ei + E, counts, E);
    k_scan<<<1, 1024, 0, stream>>>(counts, offs, dis, N);
    k_self<<<(N + 255) / 256, 256, 0, stream>>>(offs, dis, fill, csr, N);
    k_scatter<<<(E + 255) / 256, 256, 0, stream>>>(ei, ei + E, offs, fill, dis, csr, E);

    if (useH) {
        k_main_w<<<2048, 256, 0, stream>>>((const uint4*)Xh, offs, csr,
                                           Wz, bz, Wh, bh, probs, Wout, bout, out, N);
    } else {
        int nB = N < 2048 ? N : 2048;
        k_main_f<<<nB, 384, 0, stream>>>(X, offs, csr, dis, Wz, bz, Wh, bh,
                                         probs, Wout, bout, out, N);
    }
}

// Round 12
// 413.160 us; speedup vs baseline: 2.9449x; 1.0883x over previous
//
#include <hip/hip_runtime.h>
#include <hip/hip_bf16.h>
#include <hip/hip_fp16.h>

// TemporalGNN: GRU's H stays zero => R dead, timesteps independent.
// out[b,n,:] = relu( sum_t p_t*(1-Z_t)*Ht_t ) @ W_out + b_out
// R12 = R11 + (1) pk_fma_f16 gather accumulation (flush->f32 every 8 edges),
// (2) readout GEMV on MFMA (broadcast-row trick), (3) incremental n,b.

#define FDIM 32
#define TDIM 12
#define ODIM 64
#define BDIM 4

typedef _Float16 half8v __attribute__((ext_vector_type(8)));
typedef float float4v __attribute__((ext_vector_type(4)));

__global__ void k_count(const int* __restrict__ dst, int* __restrict__ counts, int E) {
    int e = blockIdx.x * 256 + threadIdx.x;
    if (e < E) atomicAdd(&counts[dst[e]], 1);
}

__global__ __launch_bounds__(1024) void k_scan(const int* __restrict__ counts,
                                               int* __restrict__ offsets,
                                               float* __restrict__ dis, int N) {
    __shared__ int wsum[16];
    __shared__ int sCarry;
    const int tid = threadIdx.x;
    const int lane = tid & 63;
    const int wv = tid >> 6;
    if (tid == 0) sCarry = 0;
    __syncthreads();
    for (int base = 0; base < N; base += 1024) {
        int i = base + tid;
        int v = (i < N) ? (counts[i] + 1) : 0;
        int s = v;
        for (int off = 1; off < 64; off <<= 1) {
            int t = __shfl_up(s, off, 64);
            if (lane >= off) s += t;
        }
        if (lane == 63) wsum[wv] = s;
        __syncthreads();
        if (wv == 0 && lane < 16) {
            int ws = wsum[lane];
            for (int off = 1; off < 16; off <<= 1) {
                int t = __shfl_up(ws, off, 64);
                if (lane >= off) ws += t;
            }
            wsum[lane] = ws;
        }
        __syncthreads();
        int carry = sCarry;
        int wpre = (wv > 0) ? wsum[wv - 1] : 0;
        if (i < N) {
            offsets[i] = carry + wpre + s - v;
            dis[i] = 1.0f / sqrtf((float)v);
        }
        __syncthreads();
        if (tid == 0) sCarry = carry + wsum[15];
        __syncthreads();
    }
    if (tid == 0) offsets[N] = sCarry;
}

__global__ void k_self(const int* __restrict__ offsets, const float* __restrict__ dis,
                       int* __restrict__ fill, int2* __restrict__ csr, int N) {
    int n = blockIdx.x * 256 + threadIdx.x;
    if (n < N) {
        float d = dis[n];
        csr[offsets[n]] = make_int2(n, __float_as_int(d * d));
        fill[n] = 1;
    }
}

__global__ void k_scatter(const int* __restrict__ src, const int* __restrict__ dst,
                          const int* __restrict__ offsets, int* __restrict__ fill,
                          const float* __restrict__ dis,
                          int2* __restrict__ csr, int E) {
    int e = blockIdx.x * 256 + threadIdx.x;
    if (e < E) {
        int s = src[e], d = dst[e];
        int pos = offsets[d] + atomicAdd(&fill[d], 1);
        csr[pos] = make_int2(s, __float_as_int(dis[s] * dis[d]));
    }
}

__global__ void k_prep(const float* __restrict__ Wg_z, const float* __restrict__ bg_z,
                       const float* __restrict__ Wl_z, const float* __restrict__ bl_z,
                       const float* __restrict__ Wg_h, const float* __restrict__ bg_h,
                       const float* __restrict__ Wl_h, const float* __restrict__ bl_h,
                       const float* __restrict__ att,
                       float* __restrict__ Wz, float* __restrict__ bz,
                       float* __restrict__ Wh, float* __restrict__ bh,
                       float* __restrict__ probs) {
    int tid = threadIdx.x;
    for (int i = tid; i < FDIM * ODIM; i += 256) {
        int f = i >> 6, o = i & 63;
        float az = 0.f, ah = 0.f;
        for (int k = 0; k < ODIM; k++) {
            az += Wg_z[f * ODIM + k] * Wl_z[k * ODIM + o];
            ah += Wg_h[f * ODIM + k] * Wl_h[k * ODIM + o];
        }
        Wz[i] = az;
        Wh[i] = ah;
    }
    if (tid < ODIM) {
        float az = bl_z[tid], ah = bl_h[tid];
        for (int k = 0; k < ODIM; k++) {
            az += bg_z[k] * Wl_z[k * ODIM + tid];
            ah += bg_h[k] * Wl_h[k * ODIM + tid];
        }
        bz[tid] = az;
        bh[tid] = ah;
    }
    if (tid == 0) {
        float m = -1e30f;
        for (int t = 0; t < TDIM; t++) m = fmaxf(m, att[t]);
        float e[TDIM], s = 0.f;
        for (int t = 0; t < TDIM; t++) { e[t] = expf(att[t] - m); s += e[t]; }
        for (int t = 0; t < TDIM; t++) probs[t] = e[t] / s;
    }
}

__global__ __launch_bounds__(256) void k_cvt(const float4* __restrict__ in,
                                             uint2* __restrict__ out, int n4) {
    int i = blockIdx.x * 256 + threadIdx.x;
    const int stride = gridDim.x * 256;
    for (; i < n4; i += stride) {
        const float4 v = in[i];
        __half2 h0 = __floats2half2_rn(v.x, v.y);
        __half2 h1 = __floats2half2_rn(v.z, v.w);
        uint2 u;
        u.x = *reinterpret_cast<unsigned*>(&h0);
        u.y = *reinterpret_cast<unsigned*>(&h1);
        out[i] = u;
    }
}

__device__ __forceinline__ float sigm(float x) { return 1.f / (1.f + __expf(-x)); }
__device__ __forceinline__ float tanhfast(float x) { return 1.f - 2.f / (1.f + __expf(2.f * x)); }

// fp16-packed accumulate: 4 hfma2 per edge into set s (0..3 half2 accs)
#define HPACC(mhI, v, hs0, hs1, hs2, hs3)                                      \
    {                                                                          \
        __half2 mh_ = *(__half2*)&(mhI);                                       \
        hs0 = __hfma2(mh_, *(__half2*)&(v).x, hs0);                            \
        hs1 = __hfma2(mh_, *(__half2*)&(v).y, hs1);                            \
        hs2 = __hfma2(mh_, *(__half2*)&(v).z, hs2);                            \
        hs3 = __hfma2(mh_, *(__half2*)&(v).w, hs3);                            \
    }

#define HFLUSH(hs0, hs1, hs2, hs3)                                             \
    {                                                                          \
        float2 t_;                                                             \
        t_ = __half22float2(hs0); a0 += t_.x; a1 += t_.y;                      \
        t_ = __half22float2(hs1); a2 += t_.x; a3 += t_.y;                      \
        t_ = __half22float2(hs2); a4 += t_.x; a5 += t_.y;                      \
        t_ = __half22float2(hs3); a6 += t_.x; a7 += t_.y;                      \
        hs0 = hzero; hs1 = hzero; hs2 = hzero; hs3 = hzero;                    \
    }

#define GLOADH(dst, mvar, slot)                                                \
    {                                                                          \
        int s_ = __shfl(esrc, (slot), 64);                                     \
        (mvar) = __shfl(hmi, (slot), 64);                                      \
        (dst) = Xh[(rowB + (unsigned)s_) * 48u + lanec];                       \
    }

#define LOADB(dst, Wsrc, jt)                                                   \
    {                                                                          \
        _Pragma("unroll") for (int r_ = 0; r_ < 8; r_++)                       \
            dst[r_] = (_Float16)Wsrc[(kg * 8 + r_) * ODIM + (jt) * 16 + c];    \
    }

#define EPI(qv, dzv, dhv, bzv, bhv)                                            \
    {                                                                          \
        float s_ = 0.f;                                                        \
        {  float zf_ = dzv[0] + bzv, hf_ = dhv[0] + bhv;                       \
           s_ += pr0 * (1.f - sigm(zf_)) * tanhfast(hf_); }                    \
        {  float zf_ = dzv[1] + bzv, hf_ = dhv[1] + bhv;                       \
           s_ += pr1 * (1.f - sigm(zf_)) * tanhfast(hf_); }                    \
        {  float zf_ = dzv[2] + bzv, hf_ = dhv[2] + bhv;                       \
           s_ += pr2 * (1.f - sigm(zf_)) * tanhfast(hf_); }                    \
        {  float zf_ = dzv[3] + bzv, hf_ = dhv[3] + bhv;                       \
           s_ += pr3 * (1.f - sigm(zf_)) * tanhfast(hf_); }                    \
        s_ += __shfl_xor(s_, 16, 64);                                          \
        s_ += __shfl_xor(s_, 32, 64);                                          \
        qv = s_;                                                               \
    }

// Wave-independent main kernel + MFMA gates + MFMA readout.
__global__ __launch_bounds__(256, 4) void k_main_w(
    const uint4* __restrict__ Xh, const int* __restrict__ offs,
    const int2* __restrict__ csr,
    const float* __restrict__ Wz, const float* __restrict__ bz,
    const float* __restrict__ Wh, const float* __restrict__ bh,
    const float* __restrict__ probs, const float* __restrict__ Wout,
    const float* __restrict__ bout, float* __restrict__ out, int N) {
    __shared__ float sY[4][16 * 36 + 4];   // [t][f] padded stride 36

    const int tid = threadIdx.x;
    const int wv = tid >> 6;
    const int lane = tid & 63;
    const int lanec = lane < 47 ? lane : 47;
    const int c = lane & 15;
    const int kg = lane >> 4;

    // persistent per-wave state
    half8v wzf0, wzf1, wzf2, wzf3, whf0, whf1, whf2, whf3;
    LOADB(wzf0, Wz, 0) LOADB(wzf1, Wz, 1) LOADB(wzf2, Wz, 2) LOADB(wzf3, Wz, 3)
    LOADB(whf0, Wh, 0) LOADB(whf1, Wh, 1) LOADB(whf2, Wh, 2) LOADB(whf3, Wh, 3)
    // readout B-frags: B[k=o][col=j<12] = Wout[o][j]
    half8v wo0, wo1;
#pragma unroll
    for (int r_ = 0; r_ < 8; r_++) {
        wo0[r_] = (_Float16)((c < TDIM) ? Wout[(kg * 8 + r_) * TDIM + c] : 0.f);
        wo1[r_] = (_Float16)((c < TDIM) ? Wout[(32 + kg * 8 + r_) * TDIM + c] : 0.f);
    }
    const float bz0 = bz[c], bz1 = bz[16 + c], bz2 = bz[32 + c], bz3 = bz[48 + c];
    const float bh0 = bh[c], bh1 = bh[16 + c], bh2 = bh[32 + c], bh3 = bh[48 + c];
    const float pr0 = (kg * 4 + 0 < TDIM) ? probs[kg * 4 + 0] : 0.f;
    const float pr1 = (kg * 4 + 1 < TDIM) ? probs[kg * 4 + 1] : 0.f;
    const float pr2 = (kg * 4 + 2 < TDIM) ? probs[kg * 4 + 2] : 0.f;
    const float pr3 = (kg * 4 + 3 < TDIM) ? probs[kg * 4 + 3] : 0.f;
    const float bo = (lane < TDIM) ? bout[lane] : 0.f;
    const __half2 hzero = __float2half2_rn(0.f);

    float* __restrict__ sy = sY[wv];
    const int strideT = gridDim.x * 4;
    const int totalTasks = N * BDIM;

    int task0 = blockIdx.x * 4 + wv;
    if (task0 >= totalTasks) return;
    int b = task0 / N;
    int n = task0 - b * N;

    while (true) {
        const unsigned rowB = (unsigned)b * (unsigned)N;
        const int beg = offs[n], end = offs[n + 1];

        // ---- gather: fp16 packed accumulate, flush to f32 every 8 edges ----
        float a0 = 0.f, a1 = 0.f, a2 = 0.f, a3 = 0.f,
              a4 = 0.f, a5 = 0.f, a6 = 0.f, a7 = 0.f;
        __half2 hA0 = hzero, hA1 = hzero, hA2 = hzero, hA3 = hzero;
        __half2 hB0 = hzero, hB1 = hzero, hB2 = hzero, hB3 = hzero;
        for (int ebase = beg; ebase < end; ebase += 64) {
            const int wcnt = min(64, end - ebase);
            int esrc = 0;
            int hmi = 0;
            if (ebase + lane < end) {
                const int2 e = csr[ebase + lane];
                esrc = e.x;
                const float m = __int_as_float(e.y);
                __half2 mh = __floats2half2_rn(m, m);
                hmi = *(int*)&mh;
            }
            int j = 0;
            for (; j + 8 <= wcnt; j += 8) {
                uint4 x0, x1, x2, x3, x4, x5, x6, x7;
                int m0, m1, m2, m3, m4, m5, m6, m7;
                GLOADH(x0, m0, j + 0); GLOADH(x1, m1, j + 1);
                GLOADH(x2, m2, j + 2); GLOADH(x3, m3, j + 3);
                GLOADH(x4, m4, j + 4); GLOADH(x5, m5, j + 5);
                GLOADH(x6, m6, j + 6); GLOADH(x7, m7, j + 7);
                HPACC(m0, x0, hA0, hA1, hA2, hA3);
                HPACC(m1, x1, hA0, hA1, hA2, hA3);
                HPACC(m2, x2, hA0, hA1, hA2, hA3);
                HPACC(m3, x3, hA0, hA1, hA2, hA3);
                HPACC(m4, x4, hB0, hB1, hB2, hB3);
                HPACC(m5, x5, hB0, hB1, hB2, hB3);
                HPACC(m6, x6, hB0, hB1, hB2, hB3);
                HPACC(m7, x7, hB0, hB1, hB2, hB3);
                HFLUSH(hA0, hA1, hA2, hA3);
                HFLUSH(hB0, hB1, hB2, hB3);
            }
            for (; j < wcnt; j++) {
                uint4 xv;
                int mv;
                GLOADH(xv, mv, j);
                HPACC(mv, xv, hA0, hA1, hA2, hA3);
            }
            HFLUSH(hA0, hA1, hA2, hA3);
        }

        // ---- deposit Y to LDS transposed [t][f] (stride 36) ----
        if (lane < 48) {
            int flat = lane * 8;               // = f*12 + t
            int f = flat / 12;
            int t = flat - f * 12;
#pragma unroll
            for (int k = 0; k < 8; k++) {
                float av = (k == 0) ? a0 : (k == 1) ? a1 : (k == 2) ? a2 :
                           (k == 3) ? a3 : (k == 4) ? a4 : (k == 5) ? a5 :
                           (k == 6) ? a6 : a7;
                sy[t * 36 + f] = av;
                t++;
                if (t == TDIM) { t = 0; f++; }
            }
        }

        // ---- A-frag: row=c (t), k=kg*8+j (f) ----
        half8v af;
        if (c < TDIM) {
            const float4* yp = (const float4*)&sy[c * 36 + kg * 8];
            const float4 y0 = yp[0];
            const float4 y1 = yp[1];
            af[0] = (_Float16)y0.x; af[1] = (_Float16)y0.y;
            af[2] = (_Float16)y0.z; af[3] = (_Float16)y0.w;
            af[4] = (_Float16)y1.x; af[5] = (_Float16)y1.y;
            af[6] = (_Float16)y1.z; af[7] = (_Float16)y1.w;
        } else {
            af[0] = (_Float16)0.f; af[1] = (_Float16)0.f;
            af[2] = (_Float16)0.f; af[3] = (_Float16)0.f;
            af[4] = (_Float16)0.f; af[5] = (_Float16)0.f;
            af[6] = (_Float16)0.f; af[7] = (_Float16)0.f;
        }

        // ---- gates via MFMA ----
        const float4v zero4 = {0.f, 0.f, 0.f, 0.f};
        float4v dz0 = __builtin_amdgcn_mfma_f32_16x16x32_f16(af, wzf0, zero4, 0, 0, 0);
        float4v dz1 = __builtin_amdgcn_mfma_f32_16x16x32_f16(af, wzf1, zero4, 0, 0, 0);
        float4v dz2 = __builtin_amdgcn_mfma_f32_16x16x32_f16(af, wzf2, zero4, 0, 0, 0);
        float4v dz3 = __builtin_amdgcn_mfma_f32_16x16x32_f16(af, wzf3, zero4, 0, 0, 0);
        float4v dh0 = __builtin_amdgcn_mfma_f32_16x16x32_f16(af, whf0, zero4, 0, 0, 0);
        float4v dh1 = __builtin_amdgcn_mfma_f32_16x16x32_f16(af, whf1, zero4, 0, 0, 0);
        float4v dh2 = __builtin_amdgcn_mfma_f32_16x16x32_f16(af, whf2, zero4, 0, 0, 0);
        float4v dh3 = __builtin_amdgcn_mfma_f32_16x16x32_f16(af, whf3, zero4, 0, 0, 0);

        // ---- epilogue: per-o weighted gate sum (acc at lane=o) ----
        float q0, q1, q2, q3;
        EPI(q0, dz0, dh0, bz0, bh0)
        EPI(q1, dz1, dh1, bz1, bh1)
        EPI(q2, dz2, dh2, bz2, bh2)
        EPI(q3, dz3, dh3, bz3, bh3)
        const float accOwn = (kg == 0) ? q0 : (kg == 1) ? q1 : (kg == 2) ? q2 : q3;

        // ---- readout GEMV on MFMA: broadcast relu(acc) to all A rows ----
        const float r = fmaxf(accOwn, 0.f);
        half8v ra0, ra1;
#pragma unroll
        for (int j = 0; j < 8; j++) {
            ra0[j] = (_Float16)__shfl(r, (kg << 3) + j, 64);
            ra1[j] = (_Float16)__shfl(r, 32 + (kg << 3) + j, 64);
        }
        float4v dro = __builtin_amdgcn_mfma_f32_16x16x32_f16(ra0, wo0, zero4, 0, 0, 0);
        dro = __builtin_amdgcn_mfma_f32_16x16x32_f16(ra1, wo1, dro, 0, 0, 0);
        // every D row equals out_j (identical A rows); col c = j
        if (lane < TDIM)
            out[(rowB + (unsigned)n) * TDIM + lane] = dro[0] + bo;

        // ---- advance task ----
        n += strideT;
        if (n >= N) { n -= N; b++; }
        if (b >= BDIM) break;
    }
}

// fp32 fallback (no fp16 workspace): consumes self-inclusive csr.
__global__ __launch_bounds__(384) void k_main_f(
    const float* __restrict__ X, const int* __restrict__ offsets,
    const int2* __restrict__ csr, const float* __restrict__ dis,
    const float* __restrict__ Wz, const float* __restrict__ bz,
    const float* __restrict__ Wh, const float* __restrict__ bh,
    const float* __restrict__ probs, const float* __restrict__ Wout,
    const float* __restrict__ bout, float* __restrict__ out, int N) {
    const int tid = threadIdx.x;
    const int lane = tid & 63;

    __shared__ float4 sY4[BDIM][96];
    __shared__ float sAcc[BDIM][ODIM];
    __shared__ float sWout[ODIM * TDIM];
    __shared__ float sBout[TDIM];

    for (int i = tid; i < ODIM * TDIM; i += 384) sWout[i] = Wout[i];
    if (tid < TDIM) sBout[tid] = bout[tid];

    const int o = tid & 63;
    const int w = tid >> 6;
    float wzr[FDIM], whr[FDIM];
#pragma unroll
    for (int f = 0; f < FDIM; f++) {
        wzr[f] = Wz[f * ODIM + o];
        whr[f] = Wh[f * ODIM + o];
    }
    const float bzo = bz[o], bho = bh[o];
    const int t0 = w, t1 = w + 6;
    const float p0 = probs[t0], p1 = probs[t1];

    const int b = tid / 96;
    const int q = tid - b * 96;
    const float4* __restrict__ Xq = (const float4*)X;
    const unsigned rowBase = (unsigned)b * (unsigned)N;

    for (int n = blockIdx.x; n < N; n += gridDim.x) {
        if (tid < BDIM * ODIM) ((float*)sAcc)[tid] = 0.f;

        const int beg = offsets[n], end = offsets[n + 1];
        float4 A0 = make_float4(0.f, 0.f, 0.f, 0.f);
        float4 A1 = A0, A2 = A0, A3 = A0;

        for (int ebase = beg; ebase < end; ebase += 64) {
            const int cnt2 = min(64, end - ebase);
            int esrc = 0;
            float enm = 0.f;
            if (ebase + lane < end) {
                const int2 e = csr[ebase + lane];
                esrc = e.x;
                enm = __int_as_float(e.y);
            }
            int j = 0;
            for (; j + 4 <= cnt2; j += 4) {
                const int s0 = __shfl(esrc, j + 0, 64), s1 = __shfl(esrc, j + 1, 64);
                const int s2 = __shfl(esrc, j + 2, 64), s3 = __shfl(esrc, j + 3, 64);
                const float m0 = __shfl(enm, j + 0, 64), m1 = __shfl(enm, j + 1, 64);
                const float m2 = __shfl(enm, j + 2, 64), m3 = __shfl(enm, j + 3, 64);
                const float4 u0 = Xq[(rowBase + s0) * 96u + q];
                const float4 u1 = Xq[(rowBase + s1) * 96u + q];
                const float4 u2 = Xq[(rowBase + s2) * 96u + q];
                const float4 u3 = Xq[(rowBase + s3) * 96u + q];
                A0.x += m0 * u0.x; A0.y += m0 * u0.y; A0.z += m0 * u0.z; A0.w += m0 * u0.w;
                A1.x += m1 * u1.x; A1.y += m1 * u1.y; A1.z += m1 * u1.z; A1.w += m1 * u1.w;
                A2.x += m2 * u2.x; A2.y += m2 * u2.y; A2.z += m2 * u2.z; A2.w += m2 * u2.w;
                A3.x += m3 * u3.x; A3.y += m3 * u3.y; A3.z += m3 * u3.z; A3.w += m3 * u3.w;
            }
            for (; j < cnt2; j++) {
                const int s = __shfl(esrc, j, 64);
                const float m = __shfl(enm, j, 64);
                const float4 u = Xq[(rowBase + s) * 96u + q];
                A0.x += m * u.x; A0.y += m * u.y; A0.z += m * u.z; A0.w += m * u.w;
            }
        }
        A0.x += (A1.x + A2.x) + A3.x;
        A0.y += (A1.y + A2.y) + A3.y;
        A0.z += (A1.z + A2.z) + A3.z;
        A0.w += (A1.w + A2.w) + A3.w;
        sY4[b][q] = A0;
        __syncthreads();

#pragma unroll
        for (int bb = 0; bb < BDIM; bb++) {
            const float* yb = (const float*)sY4[bb];
            float z0 = bzo, z1 = bzo, h0 = bho, h1 = bho;
#pragma unroll
            for (int f = 0; f < FDIM; f++) {
                float ya = yb[f * TDIM + t0];
                float yc = yb[f * TDIM + t1];
                z0 += ya * wzr[f]; h0 += ya * whr[f];
                z1 += yc * wzr[f]; h1 += yc * whr[f];
            }
            float contrib = p0 * (1.f - sigm(z0)) * tanhfast(h0)
                          + p1 * (1.f - sigm(z1)) * tanhfast(h1);
            atomicAdd(&sAcc[bb][o], contrib);
        }
        __syncthreads();

        if (tid < BDIM * TDIM) {
            int ob = tid / TDIM, jj = tid - ob * TDIM;
            float v = sBout[jj];
#pragma unroll
            for (int o2 = 0; o2 < ODIM; o2++) {
                v += fmaxf(sAcc[ob][o2], 0.f) * sWout[o2 * TDIM + jj];
            }
            out[(unsigned)(ob * N + n) * TDIM + jj] = v;
        }
        __syncthreads();
    }
}

extern "C" void kernel_launch(void* const* d_in, const int* in_sizes, int n_in,
                              void* d_out, int out_size, void* d_ws, size_t ws_size,
                              hipStream_t stream) {
    const float* X    = (const float*)d_in[0];
    const int*   ei   = (const int*)d_in[1];
    const float* Wg_z = (const float*)d_in[2];
    const float* bg_z = (const float*)d_in[3];
    const float* Wg_h = (const float*)d_in[6];
    const float* bg_h = (const float*)d_in[7];
    const float* Wl_z = (const float*)d_in[8];
    const float* bl_z = (const float*)d_in[9];
    const float* Wl_h = (const float*)d_in[12];
    const float* bl_h = (const float*)d_in[13];
    const float* att  = (const float*)d_in[14];
    const float* Wout = (const float*)d_in[15];
    const float* bout = (const float*)d_in[16];
    float* out = (float*)d_out;

    const int E = in_sizes[1] / 2;
    const int N = in_sizes[0] / (BDIM * FDIM * TDIM);
    const size_t xElems = (size_t)BDIM * N * FDIM * TDIM;
    const size_t xhBytes = xElems * 2;
    const size_t csrBytes = (size_t)(E + N) * 8;
    const size_t restBytes = (size_t)N * 4 * 4 + 64 + csrBytes + 20000;
    const bool useH = ws_size >= xhBytes + restBytes;

    char* wp = (char*)d_ws;
    uint2* Xh = nullptr;
    if (useH) { Xh = (uint2*)wp; wp += xhBytes; }
    int* counts   = (int*)wp;   wp += (size_t)N * 4;
    int* fill     = (int*)wp;   wp += (size_t)N * 4;
    int* offs     = (int*)wp;   wp += (size_t)(N + 4) * 4;
    float* dis    = (float*)wp; wp += (size_t)N * 4;
    int2* csr     = (int2*)wp;  wp += csrBytes;
    float* Wz     = (float*)wp; wp += FDIM * ODIM * 4;
    float* Wh     = (float*)wp; wp += FDIM * ODIM * 4;
    float* bz     = (float*)wp; wp += ODIM * 4;
    float* bh     = (float*)wp; wp += ODIM * 4;
    float* probs  = (float*)wp; wp += 16 * 4;

    hipMemsetAsync(counts, 0, (size_t)N * 4, stream);

    k_prep<<<1, 256, 0, stream>>>(Wg_z, bg_z, Wl_z, bl_z, Wg_h, bg_h, Wl_h, bl_h,
                                  att, Wz, bz, Wh, bh, probs);
    if (useH) {
        const int n4 = (int)(xElems / 4);
        k_cvt<<<2048, 256, 0, stream>>>((const float4*)X, Xh, n4);
    }
    k_count<<<(E + 255) / 256, 256, 0, stream>>>(ei + E, counts, E);
    k_scan<<<1, 1024, 0, stream>>>(counts, offs, dis, N);
    k_self<<<(N + 255) / 256, 256, 0, stream>>>(offs, dis, fill, csr, N);
    k_scatter<<<(E + 255) / 256, 256, 0, stream>>>(ei, ei + E, offs, fill, dis, csr, E);

    if (useH) {
        k_main_w<<<2048, 256, 0, stream>>>((const uint4*)Xh, offs, csr,
                                           Wz, bz, Wh, bh, probs, Wout, bout, out, N);
    } else {
        int nB = N < 2048 ? N : 2048;
        k_main_f<<<nB, 384, 0, stream>>>(X, offs, csr, dis, Wz, bz, Wh, bh,
                                         probs, Wout, bout, out, N);
    }
}

// Round 13
// 377.624 us; speedup vs baseline: 3.2220x; 1.0941x over previous
//
#include <hip/hip_runtime.h>
#include <hip/hip_bf16.h>
#include <hip/hip_fp16.h>

// TemporalGNN: GRU's H stays zero => R dead, timesteps independent.
// out[b,n,:] = relu( sum_t p_t*(1-Z_t)*Ht_t ) @ W_out + b_out
// R13 = R12 + (1) scalar-uniform CSR reads (readfirstlane bounds -> s_load +
// SALU addressing; zero per-edge VALU addr math, no shuffles), (2) norms
// pre-packed as half2 in csr by k_scatter/k_self, (3) fused-denominator
// gate epilogue: (1-sigm(z))*tanh(h) = u(v-1)/[(1+u)(1+v)], 2 exp + 1 raw rcp.

#define FDIM 32
#define TDIM 12
#define ODIM 64
#define BDIM 4

typedef _Float16 half8v __attribute__((ext_vector_type(8)));
typedef float float4v __attribute__((ext_vector_type(4)));

__global__ void k_count(const int* __restrict__ dst, int* __restrict__ counts, int E) {
    int e = blockIdx.x * 256 + threadIdx.x;
    if (e < E) atomicAdd(&counts[dst[e]], 1);
}

// exclusive scan of (counts[i]+1) (self-loop slot); dis = rsqrt(deg+1)
__global__ __launch_bounds__(1024) void k_scan(const int* __restrict__ counts,
                                               int* __restrict__ offsets,
                                               float* __restrict__ dis, int N) {
    __shared__ int wsum[16];
    __shared__ int sCarry;
    const int tid = threadIdx.x;
    const int lane = tid & 63;
    const int wv = tid >> 6;
    if (tid == 0) sCarry = 0;
    __syncthreads();
    for (int base = 0; base < N; base += 1024) {
        int i = base + tid;
        int v = (i < N) ? (counts[i] + 1) : 0;
        int s = v;
        for (int off = 1; off < 64; off <<= 1) {
            int t = __shfl_up(s, off, 64);
            if (lane >= off) s += t;
        }
        if (lane == 63) wsum[wv] = s;
        __syncthreads();
        if (wv == 0 && lane < 16) {
            int ws = wsum[lane];
            for (int off = 1; off < 16; off <<= 1) {
                int t = __shfl_up(ws, off, 64);
                if (lane >= off) ws += t;
            }
            wsum[lane] = ws;
        }
        __syncthreads();
        int carry = sCarry;
        int wpre = (wv > 0) ? wsum[wv - 1] : 0;
        if (i < N) {
            offsets[i] = carry + wpre + s - v;
            dis[i] = 1.0f / sqrtf((float)v);
        }
        __syncthreads();
        if (tid == 0) sCarry = carry + wsum[15];
        __syncthreads();
    }
    if (tid == 0) offsets[N] = sCarry;
}

// self-edge at slot 0 with packed half2 norm; fill starts at 1
__global__ void k_self(const int* __restrict__ offsets, const float* __restrict__ dis,
                       int* __restrict__ fill, int2* __restrict__ csr, int N) {
    int n = blockIdx.x * 256 + threadIdx.x;
    if (n < N) {
        float d = dis[n];
        float nm = d * d;
        __half2 mh = __floats2half2_rn(nm, nm);
        csr[offsets[n]] = make_int2(n, *(int*)&mh);
        fill[n] = 1;
    }
}

__global__ void k_scatter(const int* __restrict__ src, const int* __restrict__ dst,
                          const int* __restrict__ offsets, int* __restrict__ fill,
                          const float* __restrict__ dis,
                          int2* __restrict__ csr, int E) {
    int e = blockIdx.x * 256 + threadIdx.x;
    if (e < E) {
        int s = src[e], d = dst[e];
        int pos = offsets[d] + atomicAdd(&fill[d], 1);
        float nm = dis[s] * dis[d];
        __half2 mh = __floats2half2_rn(nm, nm);
        csr[pos] = make_int2(s, *(int*)&mh);
    }
}

__global__ void k_prep(const float* __restrict__ Wg_z, const float* __restrict__ bg_z,
                       const float* __restrict__ Wl_z, const float* __restrict__ bl_z,
                       const float* __restrict__ Wg_h, const float* __restrict__ bg_h,
                       const float* __restrict__ Wl_h, const float* __restrict__ bl_h,
                       const float* __restrict__ att,
                       float* __restrict__ Wz, float* __restrict__ bz,
                       float* __restrict__ Wh, float* __restrict__ bh,
                       float* __restrict__ probs) {
    int tid = threadIdx.x;
    for (int i = tid; i < FDIM * ODIM; i += 256) {
        int f = i >> 6, o = i & 63;
        float az = 0.f, ah = 0.f;
        for (int k = 0; k < ODIM; k++) {
            az += Wg_z[f * ODIM + k] * Wl_z[k * ODIM + o];
            ah += Wg_h[f * ODIM + k] * Wl_h[k * ODIM + o];
        }
        Wz[i] = az;
        Wh[i] = ah;
    }
    if (tid < ODIM) {
        float az = bl_z[tid], ah = bl_h[tid];
        for (int k = 0; k < ODIM; k++) {
            az += bg_z[k] * Wl_z[k * ODIM + tid];
            ah += bg_h[k] * Wl_h[k * ODIM + tid];
        }
        bz[tid] = az;
        bh[tid] = ah;
    }
    if (tid == 0) {
        float m = -1e30f;
        for (int t = 0; t < TDIM; t++) m = fmaxf(m, att[t]);
        float e[TDIM], s = 0.f;
        for (int t = 0; t < TDIM; t++) { e[t] = expf(att[t] - m); s += e[t]; }
        for (int t = 0; t < TDIM; t++) probs[t] = e[t] / s;
    }
}

__global__ __launch_bounds__(256) void k_cvt(const float4* __restrict__ in,
                                             uint2* __restrict__ out, int n4) {
    int i = blockIdx.x * 256 + threadIdx.x;
    const int stride = gridDim.x * 256;
    for (; i < n4; i += stride) {
        const float4 v = in[i];
        __half2 h0 = __floats2half2_rn(v.x, v.y);
        __half2 h1 = __floats2half2_rn(v.z, v.w);
        uint2 u;
        u.x = *reinterpret_cast<unsigned*>(&h0);
        u.y = *reinterpret_cast<unsigned*>(&h1);
        out[i] = u;
    }
}

__device__ __forceinline__ float sigm(float x) { return 1.f / (1.f + __expf(-x)); }
__device__ __forceinline__ float tanhfast(float x) { return 1.f - 2.f / (1.f + __expf(2.f * x)); }

// packed-fp16 accumulate; norm comes as int (half2 bits, SGPR-resident)
#define HPACC(mhI, v, hs0, hs1, hs2, hs3)                                      \
    {                                                                          \
        int mi_ = (mhI);                                                       \
        __half2 mh_ = *(__half2*)&mi_;                                         \
        hs0 = __hfma2(mh_, *(__half2*)&(v).x, hs0);                            \
        hs1 = __hfma2(mh_, *(__half2*)&(v).y, hs1);                            \
        hs2 = __hfma2(mh_, *(__half2*)&(v).z, hs2);                            \
        hs3 = __hfma2(mh_, *(__half2*)&(v).w, hs3);                            \
    }

#define HFLUSH(hs0, hs1, hs2, hs3)                                             \
    {                                                                          \
        float2 t_;                                                             \
        t_ = __half22float2(hs0); a0 += t_.x; a1 += t_.y;                      \
        t_ = __half22float2(hs1); a2 += t_.x; a3 += t_.y;                      \
        t_ = __half22float2(hs2); a4 += t_.x; a5 += t_.y;                      \
        t_ = __half22float2(hs3); a6 += t_.x; a7 += t_.y;                      \
        hs0 = hzero; hs1 = hzero; hs2 = hzero; hs3 = hzero;                    \
    }

#define LOADB(dst, Wsrc, jt)                                                   \
    {                                                                          \
        _Pragma("unroll") for (int r_ = 0; r_ < 8; r_++)                       \
            dst[r_] = (_Float16)Wsrc[(kg * 8 + r_) * ODIM + (jt) * 16 + c];    \
    }

// fused epilogue: (1-sigm(z))*tanh(h) = u*(v-1) / ((1+u)*(1+v)), u=e^-z, v=e^2h
#define EPI(qv, dzv, dhv, bzv, bhv)                                            \
    {                                                                          \
        float s_ = 0.f;                                                        \
        {  const float zf_ = dzv[0] + bzv, hf_ = dhv[0] + bhv;                 \
           const float u_ = __expf(-zf_), v_ = __expf(2.f * hf_);              \
           s_ += pr0 * u_ * (v_ - 1.f) *                                       \
                 __builtin_amdgcn_rcpf((1.f + u_) * (1.f + v_)); }             \
        {  const float zf_ = dzv[1] + bzv, hf_ = dhv[1] + bhv;                 \
           const float u_ = __expf(-zf_), v_ = __expf(2.f * hf_);              \
           s_ += pr1 * u_ * (v_ - 1.f) *                                       \
                 __builtin_amdgcn_rcpf((1.f + u_) * (1.f + v_)); }             \
        {  const float zf_ = dzv[2] + bzv, hf_ = dhv[2] + bhv;                 \
           const float u_ = __expf(-zf_), v_ = __expf(2.f * hf_);              \
           s_ += pr2 * u_ * (v_ - 1.f) *                                       \
                 __builtin_amdgcn_rcpf((1.f + u_) * (1.f + v_)); }             \
        {  const float zf_ = dzv[3] + bzv, hf_ = dhv[3] + bhv;                 \
           const float u_ = __expf(-zf_), v_ = __expf(2.f * hf_);              \
           s_ += pr3 * u_ * (v_ - 1.f) *                                       \
                 __builtin_amdgcn_rcpf((1.f + u_) * (1.f + v_)); }             \
        s_ += __shfl_xor(s_, 16, 64);                                          \
        s_ += __shfl_xor(s_, 32, 64);                                          \
        qv = s_;                                                               \
    }

// Wave-independent main kernel + MFMA gates + MFMA readout + scalar CSR.
__global__ __launch_bounds__(256, 4) void k_main_w(
    const uint4* __restrict__ Xh, const int* __restrict__ offs,
    const int2* __restrict__ csr,
    const float* __restrict__ Wz, const float* __restrict__ bz,
    const float* __restrict__ Wh, const float* __restrict__ bh,
    const float* __restrict__ probs, const float* __restrict__ Wout,
    const float* __restrict__ bout, float* __restrict__ out, int N) {
    __shared__ float sY[4][16 * 36 + 4];   // [t][f] padded stride 36

    const int tid = threadIdx.x;
    const int wv = tid >> 6;
    const int lane = tid & 63;
    const int lanec = lane < 47 ? lane : 47;
    const int c = lane & 15;
    const int kg = lane >> 4;

    // persistent per-wave state
    half8v wzf0, wzf1, wzf2, wzf3, whf0, whf1, whf2, whf3;
    LOADB(wzf0, Wz, 0) LOADB(wzf1, Wz, 1) LOADB(wzf2, Wz, 2) LOADB(wzf3, Wz, 3)
    LOADB(whf0, Wh, 0) LOADB(whf1, Wh, 1) LOADB(whf2, Wh, 2) LOADB(whf3, Wh, 3)
    half8v wo0, wo1;
#pragma unroll
    for (int r_ = 0; r_ < 8; r_++) {
        wo0[r_] = (_Float16)((c < TDIM) ? Wout[(kg * 8 + r_) * TDIM + c] : 0.f);
        wo1[r_] = (_Float16)((c < TDIM) ? Wout[(32 + kg * 8 + r_) * TDIM + c] : 0.f);
    }
    const float bz0 = bz[c], bz1 = bz[16 + c], bz2 = bz[32 + c], bz3 = bz[48 + c];
    const float bh0 = bh[c], bh1 = bh[16 + c], bh2 = bh[32 + c], bh3 = bh[48 + c];
    const float pr0 = (kg * 4 + 0 < TDIM) ? probs[kg * 4 + 0] : 0.f;
    const float pr1 = (kg * 4 + 1 < TDIM) ? probs[kg * 4 + 1] : 0.f;
    const float pr2 = (kg * 4 + 2 < TDIM) ? probs[kg * 4 + 2] : 0.f;
    const float pr3 = (kg * 4 + 3 < TDIM) ? probs[kg * 4 + 3] : 0.f;
    const float bo = (lane < TDIM) ? bout[lane] : 0.f;
    const __half2 hzero = __float2half2_rn(0.f);

    float* __restrict__ sy = sY[wv];
    const int strideT = gridDim.x * 4;
    const int totalTasks = N * BDIM;

    int task0 = blockIdx.x * 4 + wv;
    if (task0 >= totalTasks) return;
    int b = task0 / N;
    int n = task0 - b * N;

    while (true) {
        // scalar (SGPR) task state -> s_load csr + SALU addressing
        const int bs = __builtin_amdgcn_readfirstlane(b);
        const int ns = __builtin_amdgcn_readfirstlane(n);
        const unsigned rowB = (unsigned)bs * (unsigned)N;
        const int begS = __builtin_amdgcn_readfirstlane(offs[ns]);
        const int endS = __builtin_amdgcn_readfirstlane(offs[ns + 1]);

        // ---- gather: scalar edge stream, fp16 packed accumulate ----
        float a0 = 0.f, a1 = 0.f, a2 = 0.f, a3 = 0.f,
              a4 = 0.f, a5 = 0.f, a6 = 0.f, a7 = 0.f;
        __half2 hA0 = hzero, hA1 = hzero, hA2 = hzero, hA3 = hzero;
        __half2 hB0 = hzero, hB1 = hzero, hB2 = hzero, hB3 = hzero;
        int j = begS;
        for (; j + 8 <= endS; j += 8) {
            const int2 e0 = csr[j + 0], e1 = csr[j + 1], e2 = csr[j + 2], e3 = csr[j + 3];
            const int2 e4 = csr[j + 4], e5 = csr[j + 5], e6 = csr[j + 6], e7 = csr[j + 7];
            const uint4 x0 = Xh[(rowB + (unsigned)e0.x) * 48u + lanec];
            const uint4 x1 = Xh[(rowB + (unsigned)e1.x) * 48u + lanec];
            const uint4 x2 = Xh[(rowB + (unsigned)e2.x) * 48u + lanec];
            const uint4 x3 = Xh[(rowB + (unsigned)e3.x) * 48u + lanec];
            const uint4 x4 = Xh[(rowB + (unsigned)e4.x) * 48u + lanec];
            const uint4 x5 = Xh[(rowB + (unsigned)e5.x) * 48u + lanec];
            const uint4 x6 = Xh[(rowB + (unsigned)e6.x) * 48u + lanec];
            const uint4 x7 = Xh[(rowB + (unsigned)e7.x) * 48u + lanec];
            HPACC(e0.y, x0, hA0, hA1, hA2, hA3);
            HPACC(e1.y, x1, hA0, hA1, hA2, hA3);
            HPACC(e2.y, x2, hA0, hA1, hA2, hA3);
            HPACC(e3.y, x3, hA0, hA1, hA2, hA3);
            HPACC(e4.y, x4, hB0, hB1, hB2, hB3);
            HPACC(e5.y, x5, hB0, hB1, hB2, hB3);
            HPACC(e6.y, x6, hB0, hB1, hB2, hB3);
            HPACC(e7.y, x7, hB0, hB1, hB2, hB3);
            HFLUSH(hA0, hA1, hA2, hA3);
            HFLUSH(hB0, hB1, hB2, hB3);
        }
        for (; j < endS; ++j) {
            const int2 e = csr[j];
            const uint4 xv = Xh[(rowB + (unsigned)e.x) * 48u + lanec];
            HPACC(e.y, xv, hA0, hA1, hA2, hA3);
        }
        HFLUSH(hA0, hA1, hA2, hA3);

        // ---- deposit Y to LDS transposed [t][f] (stride 36) ----
        if (lane < 48) {
            int flat = lane * 8;               // = f*12 + t
            int f = flat / 12;
            int t = flat - f * 12;
#pragma unroll
            for (int k = 0; k < 8; k++) {
                float av = (k == 0) ? a0 : (k == 1) ? a1 : (k == 2) ? a2 :
                           (k == 3) ? a3 : (k == 4) ? a4 : (k == 5) ? a5 :
                           (k == 6) ? a6 : a7;
                sy[t * 36 + f] = av;
                t++;
                if (t == TDIM) { t = 0; f++; }
            }
        }

        // ---- A-frag: row=c (t), k=kg*8+j (f) ----
        half8v af;
        if (c < TDIM) {
            const float4* yp = (const float4*)&sy[c * 36 + kg * 8];
            const float4 y0 = yp[0];
            const float4 y1 = yp[1];
            af[0] = (_Float16)y0.x; af[1] = (_Float16)y0.y;
            af[2] = (_Float16)y0.z; af[3] = (_Float16)y0.w;
            af[4] = (_Float16)y1.x; af[5] = (_Float16)y1.y;
            af[6] = (_Float16)y1.z; af[7] = (_Float16)y1.w;
        } else {
            af[0] = (_Float16)0.f; af[1] = (_Float16)0.f;
            af[2] = (_Float16)0.f; af[3] = (_Float16)0.f;
            af[4] = (_Float16)0.f; af[5] = (_Float16)0.f;
            af[6] = (_Float16)0.f; af[7] = (_Float16)0.f;
        }

        // ---- gates via MFMA ----
        const float4v zero4 = {0.f, 0.f, 0.f, 0.f};
        float4v dz0 = __builtin_amdgcn_mfma_f32_16x16x32_f16(af, wzf0, zero4, 0, 0, 0);
        float4v dz1 = __builtin_amdgcn_mfma_f32_16x16x32_f16(af, wzf1, zero4, 0, 0, 0);
        float4v dz2 = __builtin_amdgcn_mfma_f32_16x16x32_f16(af, wzf2, zero4, 0, 0, 0);
        float4v dz3 = __builtin_amdgcn_mfma_f32_16x16x32_f16(af, wzf3, zero4, 0, 0, 0);
        float4v dh0 = __builtin_amdgcn_mfma_f32_16x16x32_f16(af, whf0, zero4, 0, 0, 0);
        float4v dh1 = __builtin_amdgcn_mfma_f32_16x16x32_f16(af, whf1, zero4, 0, 0, 0);
        float4v dh2 = __builtin_amdgcn_mfma_f32_16x16x32_f16(af, whf2, zero4, 0, 0, 0);
        float4v dh3 = __builtin_amdgcn_mfma_f32_16x16x32_f16(af, whf3, zero4, 0, 0, 0);

        // ---- epilogue: per-o weighted gate sum (acc at lane=o) ----
        float q0, q1, q2, q3;
        EPI(q0, dz0, dh0, bz0, bh0)
        EPI(q1, dz1, dh1, bz1, bh1)
        EPI(q2, dz2, dh2, bz2, bh2)
        EPI(q3, dz3, dh3, bz3, bh3)
        const float accOwn = (kg == 0) ? q0 : (kg == 1) ? q1 : (kg == 2) ? q2 : q3;

        // ---- readout GEMV on MFMA: broadcast relu(acc) to all A rows ----
        const float r = fmaxf(accOwn, 0.f);
        half8v ra0, ra1;
#pragma unroll
        for (int j2 = 0; j2 < 8; j2++) {
            ra0[j2] = (_Float16)__shfl(r, (kg << 3) + j2, 64);
            ra1[j2] = (_Float16)__shfl(r, 32 + (kg << 3) + j2, 64);
        }
        float4v dro = __builtin_amdgcn_mfma_f32_16x16x32_f16(ra0, wo0, zero4, 0, 0, 0);
        dro = __builtin_amdgcn_mfma_f32_16x16x32_f16(ra1, wo1, dro, 0, 0, 0);
        if (lane < TDIM)
            out[(rowB + (unsigned)n) * TDIM + lane] = dro[0] + bo;

        // ---- advance task ----
        n += strideT;
        if (n >= N) { n -= N; b++; }
        if (b >= BDIM) break;
    }
}

// fp32 fallback (no fp16 workspace): consumes self-inclusive csr (half2 norms).
__global__ __launch_bounds__(384) void k_main_f(
    const float* __restrict__ X, const int* __restrict__ offsets,
    const int2* __restrict__ csr, const float* __restrict__ dis,
    const float* __restrict__ Wz, const float* __restrict__ bz,
    const float* __restrict__ Wh, const float* __restrict__ bh,
    const float* __restrict__ probs, const float* __restrict__ Wout,
    const float* __restrict__ bout, float* __restrict__ out, int N) {
    const int tid = threadIdx.x;
    const int lane = tid & 63;

    __shared__ float4 sY4[BDIM][96];
    __shared__ float sAcc[BDIM][ODIM];
    __shared__ float sWout[ODIM * TDIM];
    __shared__ float sBout[TDIM];

    for (int i = tid; i < ODIM * TDIM; i += 384) sWout[i] = Wout[i];
    if (tid < TDIM) sBout[tid] = bout[tid];

    const int o = tid & 63;
    const int w = tid >> 6;
    float wzr[FDIM], whr[FDIM];
#pragma unroll
    for (int f = 0; f < FDIM; f++) {
        wzr[f] = Wz[f * ODIM + o];
        whr[f] = Wh[f * ODIM + o];
    }
    const float bzo = bz[o], bho = bh[o];
    const int t0 = w, t1 = w + 6;
    const float p0 = probs[t0], p1 = probs[t1];

    const int b = tid / 96;
    const int q = tid - b * 96;
    const float4* __restrict__ Xq = (const float4*)X;
    const unsigned rowBase = (unsigned)b * (unsigned)N;

    for (int n = blockIdx.x; n < N; n += gridDim.x) {
        if (tid < BDIM * ODIM) ((float*)sAcc)[tid] = 0.f;

        const int beg = offsets[n], end = offsets[n + 1];
        float4 A0 = make_float4(0.f, 0.f, 0.f, 0.f);
        float4 A1 = A0, A2 = A0, A3 = A0;

        for (int ebase = beg; ebase < end; ebase += 64) {
            const int cnt2 = min(64, end - ebase);
            int esrc = 0;
            float enm = 0.f;
            if (ebase + lane < end) {
                const int2 e = csr[ebase + lane];
                esrc = e.x;
                int ey = e.y;
                enm = __half22float2(*(__half2*)&ey).x;
            }
            int j = 0;
            for (; j + 4 <= cnt2; j += 4) {
                const int s0 = __shfl(esrc, j + 0, 64), s1 = __shfl(esrc, j + 1, 64);
                const int s2 = __shfl(esrc, j + 2, 64), s3 = __shfl(esrc, j + 3, 64);
                const float m0 = __shfl(enm, j + 0, 64), m1 = __shfl(enm, j + 1, 64);
                const float m2 = __shfl(enm, j + 2, 64), m3 = __shfl(enm, j + 3, 64);
                const float4 u0 = Xq[(rowBase + s0) * 96u + q];
                const float4 u1 = Xq[(rowBase + s1) * 96u + q];
                const float4 u2 = Xq[(rowBase + s2) * 96u + q];
                const float4 u3 = Xq[(rowBase + s3) * 96u + q];
                A0.x += m0 * u0.x; A0.y += m0 * u0.y; A0.z += m0 * u0.z; A0.w += m0 * u0.w;
                A1.x += m1 * u1.x; A1.y += m1 * u1.y; A1.z += m1 * u1.z; A1.w += m1 * u1.w;
                A2.x += m2 * u2.x; A2.y += m2 * u2.y; A2.z += m2 * u2.z; A2.w += m2 * u2.w;
                A3.x += m3 * u3.x; A3.y += m3 * u3.y; A3.z += m3 * u3.z; A3.w += m3 * u3.w;
            }
            for (; j < cnt2; j++) {
                const int s = __shfl(esrc, j, 64);
                const float m = __shfl(enm, j, 64);
                const float4 u = Xq[(rowBase + s) * 96u + q];
                A0.x += m * u.x; A0.y += m * u.y; A0.z += m * u.z; A0.w += m * u.w;
            }
        }
        A0.x += (A1.x + A2.x) + A3.x;
        A0.y += (A1.y + A2.y) + A3.y;
        A0.z += (A1.z + A2.z) + A3.z;
        A0.w += (A1.w + A2.w) + A3.w;
        sY4[b][q] = A0;
        __syncthreads();

#pragma unroll
        for (int bb = 0; bb < BDIM; bb++) {
            const float* yb = (const float*)sY4[bb];
            float z0 = bzo, z1 = bzo, h0 = bho, h1 = bho;
#pragma unroll
            for (int f = 0; f < FDIM; f++) {
                float ya = yb[f * TDIM + t0];
                float yc = yb[f * TDIM + t1];
                z0 += ya * wzr[f]; h0 += ya * whr[f];
                z1 += yc * wzr[f]; h1 += yc * whr[f];
            }
            float contrib = p0 * (1.f - sigm(z0)) * tanhfast(h0)
                          + p1 * (1.f - sigm(z1)) * tanhfast(h1);
            atomicAdd(&sAcc[bb][o], contrib);
        }
        __syncthreads();

        if (tid < BDIM * TDIM) {
            int ob = tid / TDIM, jj = tid - ob * TDIM;
            float v = sBout[jj];
#pragma unroll
            for (int o2 = 0; o2 < ODIM; o2++) {
                v += fmaxf(sAcc[ob][o2], 0.f) * sWout[o2 * TDIM + jj];
            }
            out[(unsigned)(ob * N + n) * TDIM + jj] = v;
        }
        __syncthreads();
    }
}

extern "C" void kernel_launch(void* const* d_in, const int* in_sizes, int n_in,
                              void* d_out, int out_size, void* d_ws, size_t ws_size,
                              hipStream_t stream) {
    const float* X    = (const float*)d_in[0];
    const int*   ei   = (const int*)d_in[1];
    const float* Wg_z = (const float*)d_in[2];
    const float* bg_z = (const float*)d_in[3];
    const float* Wg_h = (const float*)d_in[6];
    const float* bg_h = (const float*)d_in[7];
    const float* Wl_z = (const float*)d_in[8];
    const float* bl_z = (const float*)d_in[9];
    const float* Wl_h = (const float*)d_in[12];
    const float* bl_h = (const float*)d_in[13];
    const float* att  = (const float*)d_in[14];
    const float* Wout = (const float*)d_in[15];
    const float* bout = (const float*)d_in[16];
    float* out = (float*)d_out;

    const int E = in_sizes[1] / 2;
    const int N = in_sizes[0] / (BDIM * FDIM * TDIM);
    const size_t xElems = (size_t)BDIM * N * FDIM * TDIM;
    const size_t xhBytes = xElems * 2;
    const size_t csrBytes = (size_t)(E + N) * 8;
    const size_t restBytes = (size_t)N * 4 * 4 + 64 + csrBytes + 20000;
    const bool useH = ws_size >= xhBytes + restBytes;

    char* wp = (char*)d_ws;
    uint2* Xh = nullptr;
    if (useH) { Xh = (uint2*)wp; wp += xhBytes; }
    int* counts   = (int*)wp;   wp += (size_t)N * 4;
    int* fill     = (int*)wp;   wp += (size_t)N * 4;
    int* offs     = (int*)wp;   wp += (size_t)(N + 4) * 4;
    float* dis    = (float*)wp; wp += (size_t)N * 4;
    int2* csr     = (int2*)wp;  wp += csrBytes;
    float* Wz     = (float*)wp; wp += FDIM * ODIM * 4;
    float* Wh     = (float*)wp; wp += FDIM * ODIM * 4;
    float* bz     = (float*)wp; wp += ODIM * 4;
    float* bh     = (float*)wp; wp += ODIM * 4;
    float* probs  = (float*)wp; wp += 16 * 4;

    hipMemsetAsync(counts, 0, (size_t)N * 4, stream);

    k_prep<<<1, 256, 0, stream>>>(Wg_z, bg_z, Wl_z, bl_z, Wg_h, bg_h, Wl_h, bl_h,
                                  att, Wz, bz, Wh, bh, probs);
    if (useH) {
        const int n4 = (int)(xElems / 4);
        k_cvt<<<2048, 256, 0, stream>>>((const float4*)X, Xh, n4);
    }
    k_count<<<(E + 255) / 256, 256, 0, stream>>>(ei + E, counts, E);
    k_scan<<<1, 1024, 0, stream>>>(counts, offs, dis, N);
    k_self<<<(N + 255) / 256, 256, 0, stream>>>(offs, dis, fill, csr, N);
    k_scatter<<<(E + 255) / 256, 256, 0, stream>>>(ei, ei + E, offs, fill, dis, csr, E);

    if (useH) {
        k_main_w<<<2048, 256, 0, stream>>>((const uint4*)Xh, offs, csr,
                                           Wz, bz, Wh, bh, probs, Wout, bout, out, N);
    } else {
        int nB = N < 2048 ? N : 2048;
        k_main_f<<<nB, 384, 0, stream>>>(X, offs, csr, dis, Wz, bz, Wh, bh,
                                         probs, Wout, bout, out, N);
    }
}

// Round 14
// 371.620 us; speedup vs baseline: 3.2741x; 1.0162x over previous
//
#include <hip/hip_runtime.h>
#include <hip/hip_bf16.h>
#include <hip/hip_fp16.h>

// TemporalGNN: GRU's H stays zero => R dead, timesteps independent.
// out[b,n,:] = relu( sum_t p_t*(1-Z_t)*Ht_t ) @ W_out + b_out
// R14 = R13 k_main (unchanged) + setup-chain fusion:
//   kA = {cvt | count | prep} in one dispatch (block-range split),
//   k_scan also writes fill=1 and the csr self-edge (k_self eliminated).
//   5 launches total.

#define FDIM 32
#define TDIM 12
#define ODIM 64
#define BDIM 4

typedef _Float16 half8v __attribute__((ext_vector_type(8)));
typedef float float4v __attribute__((ext_vector_type(4)));

// ---- fused setup kernel A: [0,cvtB) cvt, [cvtB,cvtB+cntB) count, last prep ----
__global__ __launch_bounds__(256) void kA(
    const float4* __restrict__ Xin, uint2* __restrict__ Xh, int n4, int cvtB,
    const int* __restrict__ dstE, int* __restrict__ counts, int E, int cntB,
    const float* __restrict__ Wg_z, const float* __restrict__ bg_z,
    const float* __restrict__ Wl_z, const float* __restrict__ bl_z,
    const float* __restrict__ Wg_h, const float* __restrict__ bg_h,
    const float* __restrict__ Wl_h, const float* __restrict__ bl_h,
    const float* __restrict__ att,
    float* __restrict__ Wz, float* __restrict__ bz,
    float* __restrict__ Wh, float* __restrict__ bh,
    float* __restrict__ probs) {
    const int bid = blockIdx.x;
    const int tid = threadIdx.x;
    if (bid < cvtB) {
        int i = bid * 256 + tid;
        const int stride = cvtB * 256;
        for (; i < n4; i += stride) {
            const float4 v = Xin[i];
            __half2 h0 = __floats2half2_rn(v.x, v.y);
            __half2 h1 = __floats2half2_rn(v.z, v.w);
            uint2 u;
            u.x = *reinterpret_cast<unsigned*>(&h0);
            u.y = *reinterpret_cast<unsigned*>(&h1);
            Xh[i] = u;
        }
    } else if (bid < cvtB + cntB) {
        int e = (bid - cvtB) * 256 + tid;
        if (e < E) atomicAdd(&counts[dstE[e]], 1);
    } else {
        // prep: fold Wg@Wl_top, biases, softmax(att)
        for (int i = tid; i < FDIM * ODIM; i += 256) {
            int f = i >> 6, o = i & 63;
            float az = 0.f, ah = 0.f;
            for (int k = 0; k < ODIM; k++) {
                az += Wg_z[f * ODIM + k] * Wl_z[k * ODIM + o];
                ah += Wg_h[f * ODIM + k] * Wl_h[k * ODIM + o];
            }
            Wz[i] = az;
            Wh[i] = ah;
        }
        if (tid < ODIM) {
            float az = bl_z[tid], ah = bl_h[tid];
            for (int k = 0; k < ODIM; k++) {
                az += bg_z[k] * Wl_z[k * ODIM + tid];
                ah += bg_h[k] * Wl_h[k * ODIM + tid];
            }
            bz[tid] = az;
            bh[tid] = ah;
        }
        if (tid == 0) {
            float m = -1e30f;
            for (int t = 0; t < TDIM; t++) m = fmaxf(m, att[t]);
            float e[TDIM], s = 0.f;
            for (int t = 0; t < TDIM; t++) { e[t] = expf(att[t] - m); s += e[t]; }
            for (int t = 0; t < TDIM; t++) probs[t] = e[t] / s;
        }
    }
}

// exclusive scan of (counts[i]+1); also writes dis, fill=1, and csr self-edge.
__global__ __launch_bounds__(1024) void k_scan(const int* __restrict__ counts,
                                               int* __restrict__ offsets,
                                               float* __restrict__ dis,
                                               int* __restrict__ fill,
                                               int2* __restrict__ csr, int N) {
    __shared__ int wsum[16];
    __shared__ int sCarry;
    const int tid = threadIdx.x;
    const int lane = tid & 63;
    const int wv = tid >> 6;
    if (tid == 0) sCarry = 0;
    __syncthreads();
    for (int base = 0; base < N; base += 1024) {
        int i = base + tid;
        int v = (i < N) ? (counts[i] + 1) : 0;
        int s = v;
        for (int off = 1; off < 64; off <<= 1) {
            int t = __shfl_up(s, off, 64);
            if (lane >= off) s += t;
        }
        if (lane == 63) wsum[wv] = s;
        __syncthreads();
        if (wv == 0 && lane < 16) {
            int ws = wsum[lane];
            for (int off = 1; off < 16; off <<= 1) {
                int t = __shfl_up(ws, off, 64);
                if (lane >= off) ws += t;
            }
            wsum[lane] = ws;
        }
        __syncthreads();
        int carry = sCarry;
        int wpre = (wv > 0) ? wsum[wv - 1] : 0;
        if (i < N) {
            const int off0 = carry + wpre + s - v;
            offsets[i] = off0;
            const float d = 1.0f / sqrtf((float)v);
            dis[i] = d;
            fill[i] = 1;
            const float nm = d * d;
            __half2 mh = __floats2half2_rn(nm, nm);
            csr[off0] = make_int2(i, *(int*)&mh);   // self-edge at slot 0
        }
        __syncthreads();
        if (tid == 0) sCarry = carry + wsum[15];
        __syncthreads();
    }
    if (tid == 0) offsets[N] = sCarry;
}

__global__ void k_scatter(const int* __restrict__ src, const int* __restrict__ dst,
                          const int* __restrict__ offsets, int* __restrict__ fill,
                          const float* __restrict__ dis,
                          int2* __restrict__ csr, int E) {
    int e = blockIdx.x * 256 + threadIdx.x;
    if (e < E) {
        int s = src[e], d = dst[e];
        int pos = offsets[d] + atomicAdd(&fill[d], 1);
        float nm = dis[s] * dis[d];
        __half2 mh = __floats2half2_rn(nm, nm);
        csr[pos] = make_int2(s, *(int*)&mh);
    }
}

__device__ __forceinline__ float sigm(float x) { return 1.f / (1.f + __expf(-x)); }
__device__ __forceinline__ float tanhfast(float x) { return 1.f - 2.f / (1.f + __expf(2.f * x)); }

#define HPACC(mhI, v, hs0, hs1, hs2, hs3)                                      \
    {                                                                          \
        int mi_ = (mhI);                                                       \
        __half2 mh_ = *(__half2*)&mi_;                                         \
        hs0 = __hfma2(mh_, *(__half2*)&(v).x, hs0);                            \
        hs1 = __hfma2(mh_, *(__half2*)&(v).y, hs1);                            \
        hs2 = __hfma2(mh_, *(__half2*)&(v).z, hs2);                            \
        hs3 = __hfma2(mh_, *(__half2*)&(v).w, hs3);                            \
    }

#define HFLUSH(hs0, hs1, hs2, hs3)                                             \
    {                                                                          \
        float2 t_;                                                             \
        t_ = __half22float2(hs0); a0 += t_.x; a1 += t_.y;                      \
        t_ = __half22float2(hs1); a2 += t_.x; a3 += t_.y;                      \
        t_ = __half22float2(hs2); a4 += t_.x; a5 += t_.y;                      \
        t_ = __half22float2(hs3); a6 += t_.x; a7 += t_.y;                      \
        hs0 = hzero; hs1 = hzero; hs2 = hzero; hs3 = hzero;                    \
    }

#define LOADB(dst, Wsrc, jt)                                                   \
    {                                                                          \
        _Pragma("unroll") for (int r_ = 0; r_ < 8; r_++)                       \
            dst[r_] = (_Float16)Wsrc[(kg * 8 + r_) * ODIM + (jt) * 16 + c];    \
    }

// fused epilogue: (1-sigm(z))*tanh(h) = u*(v-1)/((1+u)(1+v)), u=e^-z, v=e^2h
#define EPI(qv, dzv, dhv, bzv, bhv)                                            \
    {                                                                          \
        float s_ = 0.f;                                                        \
        {  const float zf_ = dzv[0] + bzv, hf_ = dhv[0] + bhv;                 \
           const float u_ = __expf(-zf_), v_ = __expf(2.f * hf_);              \
           s_ += pr0 * u_ * (v_ - 1.f) *                                       \
                 __builtin_amdgcn_rcpf((1.f + u_) * (1.f + v_)); }             \
        {  const float zf_ = dzv[1] + bzv, hf_ = dhv[1] + bhv;                 \
           const float u_ = __expf(-zf_), v_ = __expf(2.f * hf_);              \
           s_ += pr1 * u_ * (v_ - 1.f) *                                       \
                 __builtin_amdgcn_rcpf((1.f + u_) * (1.f + v_)); }             \
        {  const float zf_ = dzv[2] + bzv, hf_ = dhv[2] + bhv;                 \
           const float u_ = __expf(-zf_), v_ = __expf(2.f * hf_);              \
           s_ += pr2 * u_ * (v_ - 1.f) *                                       \
                 __builtin_amdgcn_rcpf((1.f + u_) * (1.f + v_)); }             \
        {  const float zf_ = dzv[3] + bzv, hf_ = dhv[3] + bhv;                 \
           const float u_ = __expf(-zf_), v_ = __expf(2.f * hf_);              \
           s_ += pr3 * u_ * (v_ - 1.f) *                                       \
                 __builtin_amdgcn_rcpf((1.f + u_) * (1.f + v_)); }             \
        s_ += __shfl_xor(s_, 16, 64);                                          \
        s_ += __shfl_xor(s_, 32, 64);                                          \
        qv = s_;                                                               \
    }

// Wave-independent main kernel + MFMA gates + MFMA readout + scalar CSR.
__global__ __launch_bounds__(256, 4) void k_main_w(
    const uint4* __restrict__ Xh, const int* __restrict__ offs,
    const int2* __restrict__ csr,
    const float* __restrict__ Wz, const float* __restrict__ bz,
    const float* __restrict__ Wh, const float* __restrict__ bh,
    const float* __restrict__ probs, const float* __restrict__ Wout,
    const float* __restrict__ bout, float* __restrict__ out, int N) {
    __shared__ float sY[4][16 * 36 + 4];   // [t][f] padded stride 36

    const int tid = threadIdx.x;
    const int wv = tid >> 6;
    const int lane = tid & 63;
    const int lanec = lane < 47 ? lane : 47;
    const int c = lane & 15;
    const int kg = lane >> 4;

    half8v wzf0, wzf1, wzf2, wzf3, whf0, whf1, whf2, whf3;
    LOADB(wzf0, Wz, 0) LOADB(wzf1, Wz, 1) LOADB(wzf2, Wz, 2) LOADB(wzf3, Wz, 3)
    LOADB(whf0, Wh, 0) LOADB(whf1, Wh, 1) LOADB(whf2, Wh, 2) LOADB(whf3, Wh, 3)
    half8v wo0, wo1;
#pragma unroll
    for (int r_ = 0; r_ < 8; r_++) {
        wo0[r_] = (_Float16)((c < TDIM) ? Wout[(kg * 8 + r_) * TDIM + c] : 0.f);
        wo1[r_] = (_Float16)((c < TDIM) ? Wout[(32 + kg * 8 + r_) * TDIM + c] : 0.f);
    }
    const float bz0 = bz[c], bz1 = bz[16 + c], bz2 = bz[32 + c], bz3 = bz[48 + c];
    const float bh0 = bh[c], bh1 = bh[16 + c], bh2 = bh[32 + c], bh3 = bh[48 + c];
    const float pr0 = (kg * 4 + 0 < TDIM) ? probs[kg * 4 + 0] : 0.f;
    const float pr1 = (kg * 4 + 1 < TDIM) ? probs[kg * 4 + 1] : 0.f;
    const float pr2 = (kg * 4 + 2 < TDIM) ? probs[kg * 4 + 2] : 0.f;
    const float pr3 = (kg * 4 + 3 < TDIM) ? probs[kg * 4 + 3] : 0.f;
    const float bo = (lane < TDIM) ? bout[lane] : 0.f;
    const __half2 hzero = __float2half2_rn(0.f);

    float* __restrict__ sy = sY[wv];
    const int strideT = gridDim.x * 4;
    const int totalTasks = N * BDIM;

    int task0 = blockIdx.x * 4 + wv;
    if (task0 >= totalTasks) return;
    int b = task0 / N;
    int n = task0 - b * N;

    while (true) {
        const int bs = __builtin_amdgcn_readfirstlane(b);
        const int ns = __builtin_amdgcn_readfirstlane(n);
        const unsigned rowB = (unsigned)bs * (unsigned)N;
        const int begS = __builtin_amdgcn_readfirstlane(offs[ns]);
        const int endS = __builtin_amdgcn_readfirstlane(offs[ns + 1]);

        // ---- gather: scalar edge stream, fp16 packed accumulate ----
        float a0 = 0.f, a1 = 0.f, a2 = 0.f, a3 = 0.f,
              a4 = 0.f, a5 = 0.f, a6 = 0.f, a7 = 0.f;
        __half2 hA0 = hzero, hA1 = hzero, hA2 = hzero, hA3 = hzero;
        __half2 hB0 = hzero, hB1 = hzero, hB2 = hzero, hB3 = hzero;
        int j = begS;
        for (; j + 8 <= endS; j += 8) {
            const int2 e0 = csr[j + 0], e1 = csr[j + 1], e2 = csr[j + 2], e3 = csr[j + 3];
            const int2 e4 = csr[j + 4], e5 = csr[j + 5], e6 = csr[j + 6], e7 = csr[j + 7];
            const uint4 x0 = Xh[(rowB + (unsigned)e0.x) * 48u + lanec];
            const uint4 x1 = Xh[(rowB + (unsigned)e1.x) * 48u + lanec];
            const uint4 x2 = Xh[(rowB + (unsigned)e2.x) * 48u + lanec];
            const uint4 x3 = Xh[(rowB + (unsigned)e3.x) * 48u + lanec];
            const uint4 x4 = Xh[(rowB + (unsigned)e4.x) * 48u + lanec];
            const uint4 x5 = Xh[(rowB + (unsigned)e5.x) * 48u + lanec];
            const uint4 x6 = Xh[(rowB + (unsigned)e6.x) * 48u + lanec];
            const uint4 x7 = Xh[(rowB + (unsigned)e7.x) * 48u + lanec];
            HPACC(e0.y, x0, hA0, hA1, hA2, hA3);
            HPACC(e1.y, x1, hA0, hA1, hA2, hA3);
            HPACC(e2.y, x2, hA0, hA1, hA2, hA3);
            HPACC(e3.y, x3, hA0, hA1, hA2, hA3);
            HPACC(e4.y, x4, hB0, hB1, hB2, hB3);
            HPACC(e5.y, x5, hB0, hB1, hB2, hB3);
            HPACC(e6.y, x6, hB0, hB1, hB2, hB3);
            HPACC(e7.y, x7, hB0, hB1, hB2, hB3);
            HFLUSH(hA0, hA1, hA2, hA3);
            HFLUSH(hB0, hB1, hB2, hB3);
        }
        for (; j < endS; ++j) {
            const int2 e = csr[j];
            const uint4 xv = Xh[(rowB + (unsigned)e.x) * 48u + lanec];
            HPACC(e.y, xv, hA0, hA1, hA2, hA3);
        }
        HFLUSH(hA0, hA1, hA2, hA3);

        // ---- deposit Y to LDS transposed [t][f] (stride 36) ----
        if (lane < 48) {
            int flat = lane * 8;               // = f*12 + t
            int f = flat / 12;
            int t = flat - f * 12;
#pragma unroll
            for (int k = 0; k < 8; k++) {
                float av = (k == 0) ? a0 : (k == 1) ? a1 : (k == 2) ? a2 :
                           (k == 3) ? a3 : (k == 4) ? a4 : (k == 5) ? a5 :
                           (k == 6) ? a6 : a7;
                sy[t * 36 + f] = av;
                t++;
                if (t == TDIM) { t = 0; f++; }
            }
        }

        // ---- A-frag: row=c (t), k=kg*8+j (f) ----
        half8v af;
        if (c < TDIM) {
            const float4* yp = (const float4*)&sy[c * 36 + kg * 8];
            const float4 y0 = yp[0];
            const float4 y1 = yp[1];
            af[0] = (_Float16)y0.x; af[1] = (_Float16)y0.y;
            af[2] = (_Float16)y0.z; af[3] = (_Float16)y0.w;
            af[4] = (_Float16)y1.x; af[5] = (_Float16)y1.y;
            af[6] = (_Float16)y1.z; af[7] = (_Float16)y1.w;
        } else {
            af[0] = (_Float16)0.f; af[1] = (_Float16)0.f;
            af[2] = (_Float16)0.f; af[3] = (_Float16)0.f;
            af[4] = (_Float16)0.f; af[5] = (_Float16)0.f;
            af[6] = (_Float16)0.f; af[7] = (_Float16)0.f;
        }

        // ---- gates via MFMA ----
        const float4v zero4 = {0.f, 0.f, 0.f, 0.f};
        float4v dz0 = __builtin_amdgcn_mfma_f32_16x16x32_f16(af, wzf0, zero4, 0, 0, 0);
        float4v dz1 = __builtin_amdgcn_mfma_f32_16x16x32_f16(af, wzf1, zero4, 0, 0, 0);
        float4v dz2 = __builtin_amdgcn_mfma_f32_16x16x32_f16(af, wzf2, zero4, 0, 0, 0);
        float4v dz3 = __builtin_amdgcn_mfma_f32_16x16x32_f16(af, wzf3, zero4, 0, 0, 0);
        float4v dh0 = __builtin_amdgcn_mfma_f32_16x16x32_f16(af, whf0, zero4, 0, 0, 0);
        float4v dh1 = __builtin_amdgcn_mfma_f32_16x16x32_f16(af, whf1, zero4, 0, 0, 0);
        float4v dh2 = __builtin_amdgcn_mfma_f32_16x16x32_f16(af, whf2, zero4, 0, 0, 0);
        float4v dh3 = __builtin_amdgcn_mfma_f32_16x16x32_f16(af, whf3, zero4, 0, 0, 0);

        // ---- epilogue: per-o weighted gate sum ----
        float q0, q1, q2, q3;
        EPI(q0, dz0, dh0, bz0, bh0)
        EPI(q1, dz1, dh1, bz1, bh1)
        EPI(q2, dz2, dh2, bz2, bh2)
        EPI(q3, dz3, dh3, bz3, bh3)
        const float accOwn = (kg == 0) ? q0 : (kg == 1) ? q1 : (kg == 2) ? q2 : q3;

        // ---- readout GEMV on MFMA ----
        const float r = fmaxf(accOwn, 0.f);
        half8v ra0, ra1;
#pragma unroll
        for (int j2 = 0; j2 < 8; j2++) {
            ra0[j2] = (_Float16)__shfl(r, (kg << 3) + j2, 64);
            ra1[j2] = (_Float16)__shfl(r, 32 + (kg << 3) + j2, 64);
        }
        float4v dro = __builtin_amdgcn_mfma_f32_16x16x32_f16(ra0, wo0, zero4, 0, 0, 0);
        dro = __builtin_amdgcn_mfma_f32_16x16x32_f16(ra1, wo1, dro, 0, 0, 0);
        if (lane < TDIM)
            out[(rowB + (unsigned)n) * TDIM + lane] = dro[0] + bo;

        // ---- advance task ----
        n += strideT;
        if (n >= N) { n -= N; b++; }
        if (b >= BDIM) break;
    }
}

// fp32 fallback (no fp16 workspace): consumes self-inclusive csr (half2 norms).
__global__ __launch_bounds__(384) void k_main_f(
    const float* __restrict__ X, const int* __restrict__ offsets,
    const int2* __restrict__ csr, const float* __restrict__ dis,
    const float* __restrict__ Wz, const float* __restrict__ bz,
    const float* __restrict__ Wh, const float* __restrict__ bh,
    const float* __restrict__ probs, const float* __restrict__ Wout,
    const float* __restrict__ bout, float* __restrict__ out, int N) {
    const int tid = threadIdx.x;
    const int lane = tid & 63;

    __shared__ float4 sY4[BDIM][96];
    __shared__ float sAcc[BDIM][ODIM];
    __shared__ float sWout[ODIM * TDIM];
    __shared__ float sBout[TDIM];

    for (int i = tid; i < ODIM * TDIM; i += 384) sWout[i] = Wout[i];
    if (tid < TDIM) sBout[tid] = bout[tid];

    const int o = tid & 63;
    const int w = tid >> 6;
    float wzr[FDIM], whr[FDIM];
#pragma unroll
    for (int f = 0; f < FDIM; f++) {
        wzr[f] = Wz[f * ODIM + o];
        whr[f] = Wh[f * ODIM + o];
    }
    const float bzo = bz[o], bho = bh[o];
    const int t0 = w, t1 = w + 6;
    const float p0 = probs[t0], p1 = probs[t1];

    const int b = tid / 96;
    const int q = tid - b * 96;
    const float4* __restrict__ Xq = (const float4*)X;
    const unsigned rowBase = (unsigned)b * (unsigned)N;

    for (int n = blockIdx.x; n < N; n += gridDim.x) {
        if (tid < BDIM * ODIM) ((float*)sAcc)[tid] = 0.f;

        const int beg = offsets[n], end = offsets[n + 1];
        float4 A0 = make_float4(0.f, 0.f, 0.f, 0.f);
        float4 A1 = A0, A2 = A0, A3 = A0;

        for (int ebase = beg; ebase < end; ebase += 64) {
            const int cnt2 = min(64, end - ebase);
            int esrc = 0;
            float enm = 0.f;
            if (ebase + lane < end) {
                const int2 e = csr[ebase + lane];
                esrc = e.x;
                int ey = e.y;
                enm = __half22float2(*(__half2*)&ey).x;
            }
            int j = 0;
            for (; j + 4 <= cnt2; j += 4) {
                const int s0 = __shfl(esrc, j + 0, 64), s1 = __shfl(esrc, j + 1, 64);
                const int s2 = __shfl(esrc, j + 2, 64), s3 = __shfl(esrc, j + 3, 64);
                const float m0 = __shfl(enm, j + 0, 64), m1 = __shfl(enm, j + 1, 64);
                const float m2 = __shfl(enm, j + 2, 64), m3 = __shfl(enm, j + 3, 64);
                const float4 u0 = Xq[(rowBase + s0) * 96u + q];
                const float4 u1 = Xq[(rowBase + s1) * 96u + q];
                const float4 u2 = Xq[(rowBase + s2) * 96u + q];
                const float4 u3 = Xq[(rowBase + s3) * 96u + q];
                A0.x += m0 * u0.x; A0.y += m0 * u0.y; A0.z += m0 * u0.z; A0.w += m0 * u0.w;
                A1.x += m1 * u1.x; A1.y += m1 * u1.y; A1.z += m1 * u1.z; A1.w += m1 * u1.w;
                A2.x += m2 * u2.x; A2.y += m2 * u2.y; A2.z += m2 * u2.z; A2.w += m2 * u2.w;
                A3.x += m3 * u3.x; A3.y += m3 * u3.y; A3.z += m3 * u3.z; A3.w += m3 * u3.w;
            }
            for (; j < cnt2; j++) {
                const int s = __shfl(esrc, j, 64);
                const float m = __shfl(enm, j, 64);
                const float4 u = Xq[(rowBase + s) * 96u + q];
                A0.x += m * u.x; A0.y += m * u.y; A0.z += m * u.z; A0.w += m * u.w;
            }
        }
        A0.x += (A1.x + A2.x) + A3.x;
        A0.y += (A1.y + A2.y) + A3.y;
        A0.z += (A1.z + A2.z) + A3.z;
        A0.w += (A1.w + A2.w) + A3.w;
        sY4[b][q] = A0;
        __syncthreads();

#pragma unroll
        for (int bb = 0; bb < BDIM; bb++) {
            const float* yb = (const float*)sY4[bb];
            float z0 = bzo, z1 = bzo, h0 = bho, h1 = bho;
#pragma unroll
            for (int f = 0; f < FDIM; f++) {
                float ya = yb[f * TDIM + t0];
                float yc = yb[f * TDIM + t1];
                z0 += ya * wzr[f]; h0 += ya * whr[f];
                z1 += yc * wzr[f]; h1 += yc * whr[f];
            }
            float contrib = p0 * (1.f - sigm(z0)) * tanhfast(h0)
                          + p1 * (1.f - sigm(z1)) * tanhfast(h1);
            atomicAdd(&sAcc[bb][o], contrib);
        }
        __syncthreads();

        if (tid < BDIM * TDIM) {
            int ob = tid / TDIM, jj = tid - ob * TDIM;
            float v = sBout[jj];
#pragma unroll
            for (int o2 = 0; o2 < ODIM; o2++) {
                v += fmaxf(sAcc[ob][o2], 0.f) * sWout[o2 * TDIM + jj];
            }
            out[(unsigned)(ob * N + n) * TDIM + jj] = v;
        }
        __syncthreads();
    }
}

extern "C" void kernel_launch(void* const* d_in, const int* in_sizes, int n_in,
                              void* d_out, int out_size, void* d_ws, size_t ws_size,
                              hipStream_t stream) {
    const float* X    = (const float*)d_in[0];
    const int*   ei   = (const int*)d_in[1];
    const float* Wg_z = (const float*)d_in[2];
    const float* bg_z = (const float*)d_in[3];
    const float* Wg_h = (const float*)d_in[6];
    const float* bg_h = (const float*)d_in[7];
    const float* Wl_z = (const float*)d_in[8];
    const float* bl_z = (const float*)d_in[9];
    const float* Wl_h = (const float*)d_in[12];
    const float* bl_h = (const float*)d_in[13];
    const float* att  = (const float*)d_in[14];
    const float* Wout = (const float*)d_in[15];
    const float* bout = (const float*)d_in[16];
    float* out = (float*)d_out;

    const int E = in_sizes[1] / 2;
    const int N = in_sizes[0] / (BDIM * FDIM * TDIM);
    const size_t xElems = (size_t)BDIM * N * FDIM * TDIM;
    const size_t xhBytes = xElems * 2;
    const size_t csrBytes = (size_t)(E + N) * 8;
    const size_t restBytes = (size_t)N * 4 * 4 + 64 + csrBytes + 20000;
    const bool useH = ws_size >= xhBytes + restBytes;

    char* wp = (char*)d_ws;
    uint2* Xh = nullptr;
    if (useH) { Xh = (uint2*)wp; wp += xhBytes; }
    int* counts   = (int*)wp;   wp += (size_t)N * 4;
    int* fill     = (int*)wp;   wp += (size_t)N * 4;
    int* offs     = (int*)wp;   wp += (size_t)(N + 4) * 4;
    float* dis    = (float*)wp; wp += (size_t)N * 4;
    int2* csr     = (int2*)wp;  wp += csrBytes;
    float* Wz     = (float*)wp; wp += FDIM * ODIM * 4;
    float* Wh     = (float*)wp; wp += FDIM * ODIM * 4;
    float* bz     = (float*)wp; wp += ODIM * 4;
    float* bh     = (float*)wp; wp += ODIM * 4;
    float* probs  = (float*)wp; wp += 16 * 4;

    hipMemsetAsync(counts, 0, (size_t)N * 4, stream);

    const int cvtB = useH ? 2048 : 0;
    const int cntB = (E + 255) / 256;
    const int n4 = (int)(xElems / 4);
    kA<<<cvtB + cntB + 1, 256, 0, stream>>>(
        (const float4*)X, Xh, n4, cvtB,
        ei + E, counts, E, cntB,
        Wg_z, bg_z, Wl_z, bl_z, Wg_h, bg_h, Wl_h, bl_h, att,
        Wz, bz, Wh, bh, probs);
    k_scan<<<1, 1024, 0, stream>>>(counts, offs, dis, fill, csr, N);
    k_scatter<<<(E + 255) / 256, 256, 0, stream>>>(ei, ei + E, offs, fill, dis, csr, E);

    if (useH) {
        k_main_w<<<2048, 256, 0, stream>>>((const uint4*)Xh, offs, csr,
                                           Wz, bz, Wh, bh, probs, Wout, bout, out, N);
    } else {
        int nB = N < 2048 ? N : 2048;
        k_main_f<<<nB, 384, 0, stream>>>(X, offs, csr, dis, Wz, bz, Wh, bh,
                                         probs, Wout, bout, out, N);
    }
}

// Round 15
// 335.615 us; speedup vs baseline: 3.6253x; 1.1073x over previous
//
#include <hip/hip_runtime.h>
#include <hip/hip_bf16.h>
#include <hip/hip_fp16.h>

// TemporalGNN: GRU's H stays zero => R dead, timesteps independent.
// out[b,n,:] = relu( sum_t p_t*(1-Z_t)*Ht_t ) @ W_out + b_out
// R15 = R14 with the single-block scan replaced by a parallel 2-phase scan:
//   kB1: per-1024-tile reduce -> partials[30]
//   kB3: each block re-scans the 30 partials itself (no inter-block sync),
//        local wave scan, writes offsets/dis/fill/self-edges.
// k_main_w / kA / k_scatter unchanged (proven).

#define FDIM 32
#define TDIM 12
#define ODIM 64
#define BDIM 4
#define SCAN_TILE 1024

typedef _Float16 half8v __attribute__((ext_vector_type(8)));
typedef float float4v __attribute__((ext_vector_type(4)));

// ---- fused setup kernel A: [0,cvtB) cvt, [cvtB,cvtB+cntB) count, last prep ----
__global__ __launch_bounds__(256) void kA(
    const float4* __restrict__ Xin, uint2* __restrict__ Xh, int n4, int cvtB,
    const int* __restrict__ dstE, int* __restrict__ counts, int E, int cntB,
    const float* __restrict__ Wg_z, const float* __restrict__ bg_z,
    const float* __restrict__ Wl_z, const float* __restrict__ bl_z,
    const float* __restrict__ Wg_h, const float* __restrict__ bg_h,
    const float* __restrict__ Wl_h, const float* __restrict__ bl_h,
    const float* __restrict__ att,
    float* __restrict__ Wz, float* __restrict__ bz,
    float* __restrict__ Wh, float* __restrict__ bh,
    float* __restrict__ probs) {
    const int bid = blockIdx.x;
    const int tid = threadIdx.x;
    if (bid < cvtB) {
        int i = bid * 256 + tid;
        const int stride = cvtB * 256;
        for (; i < n4; i += stride) {
            const float4 v = Xin[i];
            __half2 h0 = __floats2half2_rn(v.x, v.y);
            __half2 h1 = __floats2half2_rn(v.z, v.w);
            uint2 u;
            u.x = *reinterpret_cast<unsigned*>(&h0);
            u.y = *reinterpret_cast<unsigned*>(&h1);
            Xh[i] = u;
        }
    } else if (bid < cvtB + cntB) {
        int e = (bid - cvtB) * 256 + tid;
        if (e < E) atomicAdd(&counts[dstE[e]], 1);
    } else {
        for (int i = tid; i < FDIM * ODIM; i += 256) {
            int f = i >> 6, o = i & 63;
            float az = 0.f, ah = 0.f;
            for (int k = 0; k < ODIM; k++) {
                az += Wg_z[f * ODIM + k] * Wl_z[k * ODIM + o];
                ah += Wg_h[f * ODIM + k] * Wl_h[k * ODIM + o];
            }
            Wz[i] = az;
            Wh[i] = ah;
        }
        if (tid < ODIM) {
            float az = bl_z[tid], ah = bl_h[tid];
            for (int k = 0; k < ODIM; k++) {
                az += bg_z[k] * Wl_z[k * ODIM + tid];
                ah += bg_h[k] * Wl_h[k * ODIM + tid];
            }
            bz[tid] = az;
            bh[tid] = ah;
        }
        if (tid == 0) {
            float m = -1e30f;
            for (int t = 0; t < TDIM; t++) m = fmaxf(m, att[t]);
            float e[TDIM], s = 0.f;
            for (int t = 0; t < TDIM; t++) { e[t] = expf(att[t] - m); s += e[t]; }
            for (int t = 0; t < TDIM; t++) probs[t] = e[t] / s;
        }
    }
}

// ---- scan phase 1: per-tile reduce of (counts[i]+1) ----
__global__ __launch_bounds__(256) void kB1(const int* __restrict__ counts, int N,
                                           int* __restrict__ partials) {
    __shared__ int wsum[4];
    const int tid = threadIdx.x;
    const int blk = blockIdx.x;
    const int i0 = blk * SCAN_TILE + tid * 4;
    int s = 0;
    s += (i0 + 0 < N) ? counts[i0 + 0] + 1 : 0;
    s += (i0 + 1 < N) ? counts[i0 + 1] + 1 : 0;
    s += (i0 + 2 < N) ? counts[i0 + 2] + 1 : 0;
    s += (i0 + 3 < N) ? counts[i0 + 3] + 1 : 0;
    for (int off = 1; off < 64; off <<= 1) s += __shfl_xor(s, off, 64);
    if ((tid & 63) == 0) wsum[tid >> 6] = s;
    __syncthreads();
    if (tid == 0) partials[blk] = wsum[0] + wsum[1] + wsum[2] + wsum[3];
}

// ---- scan phase 2: apply. Each block scans the small partials array itself. ----
__global__ __launch_bounds__(256) void kB3(const int* __restrict__ counts, int N,
                                           const int* __restrict__ partials,
                                           int* __restrict__ offsets,
                                           float* __restrict__ dis,
                                           int* __restrict__ fill,
                                           int2* __restrict__ csr, int E) {
    __shared__ int sBase;
    __shared__ int wsum[4];
    const int tid = threadIdx.x;
    const int blk = blockIdx.x;
    const int lane = tid & 63;
    const int wv = tid >> 6;

    if (tid == 0) {
        int acc = 0;
        for (int j = 0; j < blk; j++) acc += partials[j];   // <=30 L2-hot reads
        sBase = acc;
    }

    const int i0 = blk * SCAN_TILE + tid * 4;
    const int e0 = (i0 + 0 < N) ? counts[i0 + 0] + 1 : 0;
    const int e1 = (i0 + 1 < N) ? counts[i0 + 1] + 1 : 0;
    const int e2 = (i0 + 2 < N) ? counts[i0 + 2] + 1 : 0;
    const int e3 = (i0 + 3 < N) ? counts[i0 + 3] + 1 : 0;
    const int s = e0 + e1 + e2 + e3;
    int inc = s;
    for (int off = 1; off < 64; off <<= 1) {
        int t = __shfl_up(inc, off, 64);
        if (lane >= off) inc += t;
    }
    if (lane == 63) wsum[wv] = inc;
    __syncthreads();
    int wbase = 0;
    for (int j = 0; j < wv; j++) wbase += wsum[j];
    int base = sBase + wbase + inc - s;   // exclusive offset of element i0

    const int ee[4] = {e0, e1, e2, e3};
#pragma unroll
    for (int k = 0; k < 4; k++) {
        const int i = i0 + k;
        if (i < N) {
            offsets[i] = base;
            const float d = 1.0f / sqrtf((float)ee[k]);
            dis[i] = d;
            fill[i] = 1;
            const float nm = d * d;
            __half2 mh = __floats2half2_rn(nm, nm);
            csr[base] = make_int2(i, *(int*)&mh);   // self-edge at slot 0
            base += ee[k];
        }
    }
    if (blk == 0 && tid == 0) offsets[N] = E + N;   // total = sum(counts+1)
}

__global__ void k_scatter(const int* __restrict__ src, const int* __restrict__ dst,
                          const int* __restrict__ offsets, int* __restrict__ fill,
                          const float* __restrict__ dis,
                          int2* __restrict__ csr, int E) {
    int e = blockIdx.x * 256 + threadIdx.x;
    if (e < E) {
        int s = src[e], d = dst[e];
        int pos = offsets[d] + atomicAdd(&fill[d], 1);
        float nm = dis[s] * dis[d];
        __half2 mh = __floats2half2_rn(nm, nm);
        csr[pos] = make_int2(s, *(int*)&mh);
    }
}

__device__ __forceinline__ float sigm(float x) { return 1.f / (1.f + __expf(-x)); }
__device__ __forceinline__ float tanhfast(float x) { return 1.f - 2.f / (1.f + __expf(2.f * x)); }

#define HPACC(mhI, v, hs0, hs1, hs2, hs3)                                      \
    {                                                                          \
        int mi_ = (mhI);                                                       \
        __half2 mh_ = *(__half2*)&mi_;                                         \
        hs0 = __hfma2(mh_, *(__half2*)&(v).x, hs0);                            \
        hs1 = __hfma2(mh_, *(__half2*)&(v).y, hs1);                            \
        hs2 = __hfma2(mh_, *(__half2*)&(v).z, hs2);                            \
        hs3 = __hfma2(mh_, *(__half2*)&(v).w, hs3);                            \
    }

#define HFLUSH(hs0, hs1, hs2, hs3)                                             \
    {                                                                          \
        float2 t_;                                                             \
        t_ = __half22float2(hs0); a0 += t_.x; a1 += t_.y;                      \
        t_ = __half22float2(hs1); a2 += t_.x; a3 += t_.y;                      \
        t_ = __half22float2(hs2); a4 += t_.x; a5 += t_.y;                      \
        t_ = __half22float2(hs3); a6 += t_.x; a7 += t_.y;                      \
        hs0 = hzero; hs1 = hzero; hs2 = hzero; hs3 = hzero;                    \
    }

#define LOADB(dst, Wsrc, jt)                                                   \
    {                                                                          \
        _Pragma("unroll") for (int r_ = 0; r_ < 8; r_++)                       \
            dst[r_] = (_Float16)Wsrc[(kg * 8 + r_) * ODIM + (jt) * 16 + c];    \
    }

#define EPI(qv, dzv, dhv, bzv, bhv)                                            \
    {                                                                          \
        float s_ = 0.f;                                                        \
        {  const float zf_ = dzv[0] + bzv, hf_ = dhv[0] + bhv;                 \
           const float u_ = __expf(-zf_), v_ = __expf(2.f * hf_);              \
           s_ += pr0 * u_ * (v_ - 1.f) *                                       \
                 __builtin_amdgcn_rcpf((1.f + u_) * (1.f + v_)); }             \
        {  const float zf_ = dzv[1] + bzv, hf_ = dhv[1] + bhv;                 \
           const float u_ = __expf(-zf_), v_ = __expf(2.f * hf_);              \
           s_ += pr1 * u_ * (v_ - 1.f) *                                       \
                 __builtin_amdgcn_rcpf((1.f + u_) * (1.f + v_)); }             \
        {  const float zf_ = dzv[2] + bzv, hf_ = dhv[2] + bhv;                 \
           const float u_ = __expf(-zf_), v_ = __expf(2.f * hf_);              \
           s_ += pr2 * u_ * (v_ - 1.f) *                                       \
                 __builtin_amdgcn_rcpf((1.f + u_) * (1.f + v_)); }             \
        {  const float zf_ = dzv[3] + bzv, hf_ = dhv[3] + bhv;                 \
           const float u_ = __expf(-zf_), v_ = __expf(2.f * hf_);              \
           s_ += pr3 * u_ * (v_ - 1.f) *                                       \
                 __builtin_amdgcn_rcpf((1.f + u_) * (1.f + v_)); }             \
        s_ += __shfl_xor(s_, 16, 64);                                          \
        s_ += __shfl_xor(s_, 32, 64);                                          \
        qv = s_;                                                               \
    }

// Wave-independent main kernel + MFMA gates + MFMA readout + scalar CSR.
__global__ __launch_bounds__(256, 4) void k_main_w(
    const uint4* __restrict__ Xh, const int* __restrict__ offs,
    const int2* __restrict__ csr,
    const float* __restrict__ Wz, const float* __restrict__ bz,
    const float* __restrict__ Wh, const float* __restrict__ bh,
    const float* __restrict__ probs, const float* __restrict__ Wout,
    const float* __restrict__ bout, float* __restrict__ out, int N) {
    __shared__ float sY[4][16 * 36 + 4];   // [t][f] padded stride 36

    const int tid = threadIdx.x;
    const int wv = tid >> 6;
    const int lane = tid & 63;
    const int lanec = lane < 47 ? lane : 47;
    const int c = lane & 15;
    const int kg = lane >> 4;

    half8v wzf0, wzf1, wzf2, wzf3, whf0, whf1, whf2, whf3;
    LOADB(wzf0, Wz, 0) LOADB(wzf1, Wz, 1) LOADB(wzf2, Wz, 2) LOADB(wzf3, Wz, 3)
    LOADB(whf0, Wh, 0) LOADB(whf1, Wh, 1) LOADB(whf2, Wh, 2) LOADB(whf3, Wh, 3)
    half8v wo0, wo1;
#pragma unroll
    for (int r_ = 0; r_ < 8; r_++) {
        wo0[r_] = (_Float16)((c < TDIM) ? Wout[(kg * 8 + r_) * TDIM + c] : 0.f);
        wo1[r_] = (_Float16)((c < TDIM) ? Wout[(32 + kg * 8 + r_) * TDIM + c] : 0.f);
    }
    const float bz0 = bz[c], bz1 = bz[16 + c], bz2 = bz[32 + c], bz3 = bz[48 + c];
    const float bh0 = bh[c], bh1 = bh[16 + c], bh2 = bh[32 + c], bh3 = bh[48 + c];
    const float pr0 = (kg * 4 + 0 < TDIM) ? probs[kg * 4 + 0] : 0.f;
    const float pr1 = (kg * 4 + 1 < TDIM) ? probs[kg * 4 + 1] : 0.f;
    const float pr2 = (kg * 4 + 2 < TDIM) ? probs[kg * 4 + 2] : 0.f;
    const float pr3 = (kg * 4 + 3 < TDIM) ? probs[kg * 4 + 3] : 0.f;
    const float bo = (lane < TDIM) ? bout[lane] : 0.f;
    const __half2 hzero = __float2half2_rn(0.f);

    float* __restrict__ sy = sY[wv];
    const int strideT = gridDim.x * 4;
    const int totalTasks = N * BDIM;

    int task0 = blockIdx.x * 4 + wv;
    if (task0 >= totalTasks) return;
    int b = task0 / N;
    int n = task0 - b * N;

    while (true) {
        const int bs = __builtin_amdgcn_readfirstlane(b);
        const int ns = __builtin_amdgcn_readfirstlane(n);
        const unsigned rowB = (unsigned)bs * (unsigned)N;
        const int begS = __builtin_amdgcn_readfirstlane(offs[ns]);
        const int endS = __builtin_amdgcn_readfirstlane(offs[ns + 1]);

        // ---- gather: scalar edge stream, fp16 packed accumulate ----
        float a0 = 0.f, a1 = 0.f, a2 = 0.f, a3 = 0.f,
              a4 = 0.f, a5 = 0.f, a6 = 0.f, a7 = 0.f;
        __half2 hA0 = hzero, hA1 = hzero, hA2 = hzero, hA3 = hzero;
        __half2 hB0 = hzero, hB1 = hzero, hB2 = hzero, hB3 = hzero;
        int j = begS;
        for (; j + 8 <= endS; j += 8) {
            const int2 e0 = csr[j + 0], e1 = csr[j + 1], e2 = csr[j + 2], e3 = csr[j + 3];
            const int2 e4 = csr[j + 4], e5 = csr[j + 5], e6 = csr[j + 6], e7 = csr[j + 7];
            const uint4 x0 = Xh[(rowB + (unsigned)e0.x) * 48u + lanec];
            const uint4 x1 = Xh[(rowB + (unsigned)e1.x) * 48u + lanec];
            const uint4 x2 = Xh[(rowB + (unsigned)e2.x) * 48u + lanec];
            const uint4 x3 = Xh[(rowB + (unsigned)e3.x) * 48u + lanec];
            const uint4 x4 = Xh[(rowB + (unsigned)e4.x) * 48u + lanec];
            const uint4 x5 = Xh[(rowB + (unsigned)e5.x) * 48u + lanec];
            const uint4 x6 = Xh[(rowB + (unsigned)e6.x) * 48u + lanec];
            const uint4 x7 = Xh[(rowB + (unsigned)e7.x) * 48u + lanec];
            HPACC(e0.y, x0, hA0, hA1, hA2, hA3);
            HPACC(e1.y, x1, hA0, hA1, hA2, hA3);
            HPACC(e2.y, x2, hA0, hA1, hA2, hA3);
            HPACC(e3.y, x3, hA0, hA1, hA2, hA3);
            HPACC(e4.y, x4, hB0, hB1, hB2, hB3);
            HPACC(e5.y, x5, hB0, hB1, hB2, hB3);
            HPACC(e6.y, x6, hB0, hB1, hB2, hB3);
            HPACC(e7.y, x7, hB0, hB1, hB2, hB3);
            HFLUSH(hA0, hA1, hA2, hA3);
            HFLUSH(hB0, hB1, hB2, hB3);
        }
        for (; j < endS; ++j) {
            const int2 e = csr[j];
            const uint4 xv = Xh[(rowB + (unsigned)e.x) * 48u + lanec];
            HPACC(e.y, xv, hA0, hA1, hA2, hA3);
        }
        HFLUSH(hA0, hA1, hA2, hA3);

        // ---- deposit Y to LDS transposed [t][f] (stride 36) ----
        if (lane < 48) {
            int flat = lane * 8;               // = f*12 + t
            int f = flat / 12;
            int t = flat - f * 12;
#pragma unroll
            for (int k = 0; k < 8; k++) {
                float av = (k == 0) ? a0 : (k == 1) ? a1 : (k == 2) ? a2 :
                           (k == 3) ? a3 : (k == 4) ? a4 : (k == 5) ? a5 :
                           (k == 6) ? a6 : a7;
                sy[t * 36 + f] = av;
                t++;
                if (t == TDIM) { t = 0; f++; }
            }
        }

        // ---- A-frag: row=c (t), k=kg*8+j (f) ----
        half8v af;
        if (c < TDIM) {
            const float4* yp = (const float4*)&sy[c * 36 + kg * 8];
            const float4 y0 = yp[0];
            const float4 y1 = yp[1];
            af[0] = (_Float16)y0.x; af[1] = (_Float16)y0.y;
            af[2] = (_Float16)y0.z; af[3] = (_Float16)y0.w;
            af[4] = (_Float16)y1.x; af[5] = (_Float16)y1.y;
            af[6] = (_Float16)y1.z; af[7] = (_Float16)y1.w;
        } else {
            af[0] = (_Float16)0.f; af[1] = (_Float16)0.f;
            af[2] = (_Float16)0.f; af[3] = (_Float16)0.f;
            af[4] = (_Float16)0.f; af[5] = (_Float16)0.f;
            af[6] = (_Float16)0.f; af[7] = (_Float16)0.f;
        }

        // ---- gates via MFMA ----
        const float4v zero4 = {0.f, 0.f, 0.f, 0.f};
        float4v dz0 = __builtin_amdgcn_mfma_f32_16x16x32_f16(af, wzf0, zero4, 0, 0, 0);
        float4v dz1 = __builtin_amdgcn_mfma_f32_16x16x32_f16(af, wzf1, zero4, 0, 0, 0);
        float4v dz2 = __builtin_amdgcn_mfma_f32_16x16x32_f16(af, wzf2, zero4, 0, 0, 0);
        float4v dz3 = __builtin_amdgcn_mfma_f32_16x16x32_f16(af, wzf3, zero4, 0, 0, 0);
        float4v dh0 = __builtin_amdgcn_mfma_f32_16x16x32_f16(af, whf0, zero4, 0, 0, 0);
        float4v dh1 = __builtin_amdgcn_mfma_f32_16x16x32_f16(af, whf1, zero4, 0, 0, 0);
        float4v dh2 = __builtin_amdgcn_mfma_f32_16x16x32_f16(af, whf2, zero4, 0, 0, 0);
        float4v dh3 = __builtin_amdgcn_mfma_f32_16x16x32_f16(af, whf3, zero4, 0, 0, 0);

        // ---- epilogue: per-o weighted gate sum ----
        float q0, q1, q2, q3;
        EPI(q0, dz0, dh0, bz0, bh0)
        EPI(q1, dz1, dh1, bz1, bh1)
        EPI(q2, dz2, dh2, bz2, bh2)
        EPI(q3, dz3, dh3, bz3, bh3)
        const float accOwn = (kg == 0) ? q0 : (kg == 1) ? q1 : (kg == 2) ? q2 : q3;

        // ---- readout GEMV on MFMA ----
        const float r = fmaxf(accOwn, 0.f);
        half8v ra0, ra1;
#pragma unroll
        for (int j2 = 0; j2 < 8; j2++) {
            ra0[j2] = (_Float16)__shfl(r, (kg << 3) + j2, 64);
            ra1[j2] = (_Float16)__shfl(r, 32 + (kg << 3) + j2, 64);
        }
        float4v dro = __builtin_amdgcn_mfma_f32_16x16x32_f16(ra0, wo0, zero4, 0, 0, 0);
        dro = __builtin_amdgcn_mfma_f32_16x16x32_f16(ra1, wo1, dro, 0, 0, 0);
        if (lane < TDIM)
            out[(rowB + (unsigned)n) * TDIM + lane] = dro[0] + bo;

        // ---- advance task ----
        n += strideT;
        if (n >= N) { n -= N; b++; }
        if (b >= BDIM) break;
    }
}

// fp32 fallback (no fp16 workspace): consumes self-inclusive csr (half2 norms).
__global__ __launch_bounds__(384) void k_main_f(
    const float* __restrict__ X, const int* __restrict__ offsets,
    const int2* __restrict__ csr, const float* __restrict__ dis,
    const float* __restrict__ Wz, const float* __restrict__ bz,
    const float* __restrict__ Wh, const float* __restrict__ bh,
    const float* __restrict__ probs, const float* __restrict__ Wout,
    const float* __restrict__ bout, float* __restrict__ out, int N) {
    const int tid = threadIdx.x;
    const int lane = tid & 63;

    __shared__ float4 sY4[BDIM][96];
    __shared__ float sAcc[BDIM][ODIM];
    __shared__ float sWout[ODIM * TDIM];
    __shared__ float sBout[TDIM];

    for (int i = tid; i < ODIM * TDIM; i += 384) sWout[i] = Wout[i];
    if (tid < TDIM) sBout[tid] = bout[tid];

    const int o = tid & 63;
    const int w = tid >> 6;
    float wzr[FDIM], whr[FDIM];
#pragma unroll
    for (int f = 0; f < FDIM; f++) {
        wzr[f] = Wz[f * ODIM + o];
        whr[f] = Wh[f * ODIM + o];
    }
    const float bzo = bz[o], bho = bh[o];
    const int t0 = w, t1 = w + 6;
    const float p0 = probs[t0], p1 = probs[t1];

    const int b = tid / 96;
    const int q = tid - b * 96;
    const float4* __restrict__ Xq = (const float4*)X;
    const unsigned rowBase = (unsigned)b * (unsigned)N;

    for (int n = blockIdx.x; n < N; n += gridDim.x) {
        if (tid < BDIM * ODIM) ((float*)sAcc)[tid] = 0.f;

        const int beg = offsets[n], end = offsets[n + 1];
        float4 A0 = make_float4(0.f, 0.f, 0.f, 0.f);
        float4 A1 = A0, A2 = A0, A3 = A0;

        for (int ebase = beg; ebase < end; ebase += 64) {
            const int cnt2 = min(64, end - ebase);
            int esrc = 0;
            float enm = 0.f;
            if (ebase + lane < end) {
                const int2 e = csr[ebase + lane];
                esrc = e.x;
                int ey = e.y;
                enm = __half22float2(*(__half2*)&ey).x;
            }
            int j = 0;
            for (; j + 4 <= cnt2; j += 4) {
                const int s0 = __shfl(esrc, j + 0, 64), s1 = __shfl(esrc, j + 1, 64);
                const int s2 = __shfl(esrc, j + 2, 64), s3 = __shfl(esrc, j + 3, 64);
                const float m0 = __shfl(enm, j + 0, 64), m1 = __shfl(enm, j + 1, 64);
                const float m2 = __shfl(enm, j + 2, 64), m3 = __shfl(enm, j + 3, 64);
                const float4 u0 = Xq[(rowBase + s0) * 96u + q];
                const float4 u1 = Xq[(rowBase + s1) * 96u + q];
                const float4 u2 = Xq[(rowBase + s2) * 96u + q];
                const float4 u3 = Xq[(rowBase + s3) * 96u + q];
                A0.x += m0 * u0.x; A0.y += m0 * u0.y; A0.z += m0 * u0.z; A0.w += m0 * u0.w;
                A1.x += m1 * u1.x; A1.y += m1 * u1.y; A1.z += m1 * u1.z; A1.w += m1 * u1.w;
                A2.x += m2 * u2.x; A2.y += m2 * u2.y; A2.z += m2 * u2.z; A2.w += m2 * u2.w;
                A3.x += m3 * u3.x; A3.y += m3 * u3.y; A3.z += m3 * u3.z; A3.w += m3 * u3.w;
            }
            for (; j < cnt2; j++) {
                const int s = __shfl(esrc, j, 64);
                const float m = __shfl(enm, j, 64);
                const float4 u = Xq[(rowBase + s) * 96u + q];
                A0.x += m * u.x; A0.y += m * u.y; A0.z += m * u.z; A0.w += m * u.w;
            }
        }
        A0.x += (A1.x + A2.x) + A3.x;
        A0.y += (A1.y + A2.y) + A3.y;
        A0.z += (A1.z + A2.z) + A3.z;
        A0.w += (A1.w + A2.w) + A3.w;
        sY4[b][q] = A0;
        __syncthreads();

#pragma unroll
        for (int bb = 0; bb < BDIM; bb++) {
            const float* yb = (const float*)sY4[bb];
            float z0 = bzo, z1 = bzo, h0 = bho, h1 = bho;
#pragma unroll
            for (int f = 0; f < FDIM; f++) {
                float ya = yb[f * TDIM + t0];
                float yc = yb[f * TDIM + t1];
                z0 += ya * wzr[f]; h0 += ya * whr[f];
                z1 += yc * wzr[f]; h1 += yc * whr[f];
            }
            float contrib = p0 * (1.f - sigm(z0)) * tanhfast(h0)
                          + p1 * (1.f - sigm(z1)) * tanhfast(h1);
            atomicAdd(&sAcc[bb][o], contrib);
        }
        __syncthreads();

        if (tid < BDIM * TDIM) {
            int ob = tid / TDIM, jj = tid - ob * TDIM;
            float v = sBout[jj];
#pragma unroll
            for (int o2 = 0; o2 < ODIM; o2++) {
                v += fmaxf(sAcc[ob][o2], 0.f) * sWout[o2 * TDIM + jj];
            }
            out[(unsigned)(ob * N + n) * TDIM + jj] = v;
        }
        __syncthreads();
    }
}

extern "C" void kernel_launch(void* const* d_in, const int* in_sizes, int n_in,
                              void* d_out, int out_size, void* d_ws, size_t ws_size,
                              hipStream_t stream) {
    const float* X    = (const float*)d_in[0];
    const int*   ei   = (const int*)d_in[1];
    const float* Wg_z = (const float*)d_in[2];
    const float* bg_z = (const float*)d_in[3];
    const float* Wg_h = (const float*)d_in[6];
    const float* bg_h = (const float*)d_in[7];
    const float* Wl_z = (const float*)d_in[8];
    const float* bl_z = (const float*)d_in[9];
    const float* Wl_h = (const float*)d_in[12];
    const float* bl_h = (const float*)d_in[13];
    const float* att  = (const float*)d_in[14];
    const float* Wout = (const float*)d_in[15];
    const float* bout = (const float*)d_in[16];
    float* out = (float*)d_out;

    const int E = in_sizes[1] / 2;
    const int N = in_sizes[0] / (BDIM * FDIM * TDIM);
    const size_t xElems = (size_t)BDIM * N * FDIM * TDIM;
    const size_t xhBytes = xElems * 2;
    const size_t csrBytes = (size_t)(E + N) * 8;
    const size_t restBytes = (size_t)N * 4 * 4 + 4096 + csrBytes + 20000;
    const bool useH = ws_size >= xhBytes + restBytes;
    const int nScanBlk = (N + SCAN_TILE - 1) / SCAN_TILE;

    char* wp = (char*)d_ws;
    uint2* Xh = nullptr;
    if (useH) { Xh = (uint2*)wp; wp += xhBytes; }
    int* counts   = (int*)wp;   wp += (size_t)N * 4;
    int* fill     = (int*)wp;   wp += (size_t)N * 4;
    int* offs     = (int*)wp;   wp += (size_t)(N + 4) * 4;
    float* dis    = (float*)wp; wp += (size_t)N * 4;
    int* partials = (int*)wp;   wp += (size_t)(nScanBlk + 4) * 4;
    int2* csr     = (int2*)wp;  wp += csrBytes;
    float* Wz     = (float*)wp; wp += FDIM * ODIM * 4;
    float* Wh     = (float*)wp; wp += FDIM * ODIM * 4;
    float* bz     = (float*)wp; wp += ODIM * 4;
    float* bh     = (float*)wp; wp += ODIM * 4;
    float* probs  = (float*)wp; wp += 16 * 4;

    hipMemsetAsync(counts, 0, (size_t)N * 4, stream);

    const int cvtB = useH ? 2048 : 0;
    const int cntB = (E + 255) / 256;
    const int n4 = (int)(xElems / 4);
    kA<<<cvtB + cntB + 1, 256, 0, stream>>>(
        (const float4*)X, Xh, n4, cvtB,
        ei + E, counts, E, cntB,
        Wg_z, bg_z, Wl_z, bl_z, Wg_h, bg_h, Wl_h, bl_h, att,
        Wz, bz, Wh, bh, probs);
    kB1<<<nScanBlk, 256, 0, stream>>>(counts, N, partials);
    kB3<<<nScanBlk, 256, 0, stream>>>(counts, N, partials, offs, dis, fill, csr, E);
    k_scatter<<<(E + 255) / 256, 256, 0, stream>>>(ei, ei + E, offs, fill, dis, csr, E);

    if (useH) {
        k_main_w<<<2048, 256, 0, stream>>>((const uint4*)Xh, offs, csr,
                                           Wz, bz, Wh, bh, probs, Wout, bout, out, N);
    } else {
        int nB = N < 2048 ? N : 2048;
        k_main_f<<<nB, 384, 0, stream>>>(X, offs, csr, dis, Wz, bz, Wh, bh,
                                         probs, Wout, bout, out, N);
    }
}